// Round 2
// baseline (388.604 us; speedup 1.0000x reference)
//
#include <hip/hip_runtime.h>
#include <hip/hip_bf16.h>

#define B_  4
#define S_  1024
#define DM_ 1024
#define H_  16
#define DK_ 64

typedef unsigned short u16;
typedef __attribute__((ext_vector_type(8))) short bf16x8;
typedef __attribute__((ext_vector_type(4))) float f32x4;

__device__ __forceinline__ float bf2f(u16 u) {
    union { unsigned int i; float f; } c;
    c.i = ((unsigned int)u) << 16;
    return c.f;
}
__device__ __forceinline__ u16 f2bf(float f) {
    union { float f; unsigned int i; } c;
    c.f = f;
    unsigned int x = c.i;
    unsigned int lsb = (x >> 16) & 1u;
    x += 0x7fffu + lsb;          // round-to-nearest-even
    return (u16)(x >> 16);
}
__device__ __forceinline__ u16 f2bf_fast(float f) {
    __hip_bfloat16 h = __float2bfloat16(f);   // HW cvt, RNE
    return *reinterpret_cast<u16*>(&h);
}

// async global->LDS, 16B per lane; LDS dest = wave-uniform base + lane*16
__device__ __forceinline__ void async_ld16(const u16* g, u16* l) {
    __builtin_amdgcn_global_load_lds(
        (const __attribute__((address_space(1))) unsigned int*)(const void*)g,
        (__attribute__((address_space(3))) unsigned int*)(void*)l, 16, 0, 0);
}

// ---------------------------------------------------------------------------
// Runtime dtype detection (one wave). flag=1: inputs are fp32.
// ---------------------------------------------------------------------------
__global__ void detect_kernel(const u16* __restrict__ q, int* __restrict__ flag) {
    int lane = threadIdx.x & 63;
    int cnt = 0;
#pragma unroll
    for (int i = 0; i < 4; ++i) {
        u16 u = q[2 * (lane * 4 + i)];
        int e = (u >> 7) & 0xFF;
        cnt += (e >= 100 && e <= 140) ? 1 : 0;
    }
#pragma unroll
    for (int off = 1; off < 64; off <<= 1) cnt += __shfl_xor(cnt, off, 64);
    if (lane == 0) *flag = (cnt < 128) ? 1 : 0;
}

// ---------------------------------------------------------------------------
// Fused prep: blocks [0,512) scan mask -> per-(b,k64-tile) any-zero flags
// (tflags pre-zeroed via hipMemsetAsync; dirty -> atomicOr 1). Blocks >= 512
// do packed fp32->bf16 conversion (early-out when inputs already bf16).
// ---------------------------------------------------------------------------
#define NSEG 12
struct CvtArgs {
    const void* src[NSEG];
    void*       dst[NSEG];
    unsigned    off[NSEG + 1];
};

__global__ __launch_bounds__(256) void prep_kernel(
    CvtArgs a, unsigned total, const int* __restrict__ flag,
    const int* __restrict__ mask, int* __restrict__ tflags)
{
    const int tid = threadIdx.x;
    if (blockIdx.x < 512) {
        const int bx = blockIdx.x;
        const int kt = bx & 15, b = (bx >> 4) & 3, z = bx >> 6;
        int ok = 1;
#pragma unroll
        for (int i = tid; i < 128 * 16; i += 256) {
            int row = z * 128 + (i >> 4), seg = i & 15;
            int4 m = *(const int4*)&mask[((size_t)b * S_ + row) * S_ + kt * 64 + seg * 4];
            ok &= (m.x != 0) & (m.y != 0) & (m.z != 0) & (m.w != 0);
        }
        if (!ok) atomicOr(&tflags[b * 16 + kt], 1);
        return;
    }
    if (!*flag) return;   // bf16 inputs: GEMMs read originals directly
    unsigned v = (blockIdx.x - 512) * 256 + tid;
    if (v >= total) return;
    int s = 0;
    while (s < NSEG - 1 && v >= a.off[s + 1]) ++s;
    unsigned local = v - a.off[s];
    u16* dp = (u16*)a.dst[s] + (size_t)local * 8;
    const float* sp = (const float*)a.src[s] + (size_t)local * 8;
    float4 x = *(const float4*)sp, y = *(const float4*)(sp + 4);
    u16 t[8] = {f2bf(x.x), f2bf(x.y), f2bf(x.z), f2bf(x.w),
                f2bf(y.x), f2bf(y.y), f2bf(y.z), f2bf(y.w)};
    *(uint4*)dp = *(uint4*)t;
}

// ---------------------------------------------------------------------------
// Per-head transpose: Kp (b,s,h,d) -> KpT[((b*H+h)*DK + d)*S + s].
// ---------------------------------------------------------------------------
__global__ __launch_bounds__(256) void transpose_kernel(
    const u16* __restrict__ kp, u16* __restrict__ kpt)
{
    __shared__ u16 T[64][65];
    const int s0 = blockIdx.x * 64, h = blockIdx.y, b = blockIdx.z;
    const int tid = threadIdx.x;
    const size_t base = (size_t)b * S_ * DM_ + (size_t)h * DK_;
    for (int c = tid; c < 512; c += 256) {
        int row = c >> 3, cc = (c & 7) * 8;
        union { uint4 v; u16 u[8]; } x;
        x.v = *(const uint4*)&kp[base + (size_t)(s0 + row) * DM_ + cc];
#pragma unroll
        for (int j = 0; j < 8; ++j) T[row][cc + j] = x.u[j];
    }
    __syncthreads();
    const size_t baseT = (size_t)(b * H_ + h) * DK_ * S_;
    for (int c = tid; c < 512; c += 256) {
        int d = c >> 3, ss = (c & 7) * 8;
        u16 t[8];
#pragma unroll
        for (int j = 0; j < 8; ++j) t[j] = T[ss + j][d];
        *(uint4*)&kpt[baseT + (size_t)d * S_ + s0 + ss] = *(uint4*)t;
    }
}

// ---------------------------------------------------------------------------
// QKV projection + fused per-head refinements. 128x128 tile, BK=64, async
// global->LDS staging, XOR column-group swizzle (m97 structure). After the
// K-loop each wave's 64x64 quadrant is ONE head's complete column block for
// 64 rows, so the row-local 64x64 refinements run entirely in the epilogue:
// C-layout acc -> per-wave LDS region (A-layout swizzled) -> MFMA with
// weight B-frags read straight from global (L2-hot, shared across heads).
// z=0 (Q): emits q1b (Wql->Wel chain) + q2r. z=1 (K): Kp + krb. z=2: vrb.
// ---------------------------------------------------------------------------
struct QKVArgs {
    const u16* A0[3]; const u16* A1[3];
    const u16* W0[3]; const u16* W1[3];
    const void* bias[3];
    const u16* R10[3]; const u16* R11[3];   // Wql, Wkl, Wvl
    const void* rb1[3];                      // bql, bkl, bvl
    const u16* R20; const u16* R21; const void* rb2;   // Wel, bel
    const u16* R30; const u16* R31; const void* rb3;   // Wq2, bq2
    u16 *Kp, *q1b, *q2r, *krb, *vrb;
};

__global__ __launch_bounds__(256, 3) void qkv_fused_kernel(
    QKVArgs a, const int* __restrict__ flag)
{
    __shared__ __align__(16) u16 smem[16384];   // 32 KB: As+Ws; epilogue 4x8KB/wave
    u16 (*As)[64] = (u16(*)[64])smem;
    u16 (*Ws)[64] = (u16(*)[64])(smem + 8192);

    const int z = blockIdx.z;
    const int f = *flag;
    const u16* __restrict__ A = f ? a.A1[z] : a.A0[z];
    const u16* __restrict__ W = f ? a.W1[z] : a.W0[z];
    const void* biasp = a.bias[z];

    const int m0   = blockIdx.y * 128;
    const int n0   = blockIdx.x * 128;
    const int tid  = threadIdx.x;
    const int w    = tid >> 6;
    const int lane = tid & 63;
    const int l16  = lane & 15;
    const int quad = lane >> 4;
    const int wr   = (w >> 1) * 64;
    const int wc   = (w & 1) * 64;

    const int srow = lane >> 3;
    const int sgrp = (lane & 7) ^ srow;

    f32x4 acc[4][4];
#pragma unroll
    for (int rt = 0; rt < 4; ++rt)
#pragma unroll
        for (int ct = 0; ct < 4; ++ct) acc[rt][ct] = (f32x4){0.f, 0.f, 0.f, 0.f};

    for (int k0 = 0; k0 < DM_; k0 += 64) {
#pragma unroll
        for (int s = 0; s < 4; ++s) {
            int seg = w * 4 + s;
            async_ld16(&A[(size_t)(m0 + seg * 8 + srow) * DM_ + k0 + sgrp * 8],
                       &As[seg * 8][0]);
            async_ld16(&W[(size_t)(n0 + seg * 8 + srow) * DM_ + k0 + sgrp * 8],
                       &Ws[seg * 8][0]);
        }
        __syncthreads();
#pragma unroll
        for (int kk = 0; kk < 2; ++kk) {
            const int p = (kk * 4 + quad) ^ (l16 & 7);
            bf16x8 av[4], bv[4];
#pragma unroll
            for (int rt = 0; rt < 4; ++rt)
                av[rt] = *(const bf16x8*)&As[wr + rt * 16 + l16][p * 8];
#pragma unroll
            for (int ct = 0; ct < 4; ++ct)
                bv[ct] = *(const bf16x8*)&Ws[wc + ct * 16 + l16][p * 8];
#pragma unroll
            for (int rt = 0; rt < 4; ++rt)
#pragma unroll
                for (int ct = 0; ct < 4; ++ct)
                    acc[rt][ct] = __builtin_amdgcn_mfma_f32_16x16x32_bf16(
                        av[rt], bv[ct], acc[rt][ct], 0, 0, 0);
        }
        __syncthreads();   // trailing barrier: all waves done reading As/Ws
    }

    // ---- fused refinement epilogue (per-wave private LDS region) ----
    const int hcol = n0 + wc;                       // = head * 64
    u16 (*Es)[64] = (u16(*)[64])(smem + w * 4096);

    // projected tile (+bias, bf16) -> Es in A-layout swizzle; z==1 also -> Kp
#pragma unroll
    for (int ct = 0; ct < 4; ++ct) {
        int col = hcol + ct * 16 + l16;
        float bv = f ? ((const float*)biasp)[col] : bf2f(((const u16*)biasp)[col]);
#pragma unroll
        for (int rt = 0; rt < 4; ++rt)
#pragma unroll
            for (int r = 0; r < 4; ++r) {
                int ml = rt * 16 + quad * 4 + r;
                int cl = ct * 16 + l16;
                u16 bb = f2bf(acc[rt][ct][r] + bv);
                if (z == 1) a.Kp[(size_t)(m0 + wr + ml) * DM_ + col] = bb;
                Es[ml][((((cl >> 3) ^ (ml & 7)) << 3) | (cl & 7))] = bb;
            }
    }

    // A-frags of the projected tile (same-wave DS in-order; no barrier needed)
    bf16x8 af[4][2];
#pragma unroll
    for (int rt = 0; rt < 4; ++rt)
#pragma unroll
        for (int kk = 0; kk < 2; ++kk)
            af[rt][kk] = *(const bf16x8*)
                &Es[rt * 16 + l16][(((kk * 4 + quad) ^ (l16 & 7)) << 3)];

    // stage-1 weight B-frags from global (64x64, L2-hot)
    const u16* R1 = f ? a.R11[z] : a.R10[z];
    bf16x8 wb[2][4];
#pragma unroll
    for (int kk = 0; kk < 2; ++kk)
#pragma unroll
        for (int ct = 0; ct < 4; ++ct)
            wb[kk][ct] = *(const bf16x8*)
                &R1[(size_t)(ct * 16 + l16) * 64 + kk * 32 + quad * 8];

    f32x4 r1[4][4];
#pragma unroll
    for (int rt = 0; rt < 4; ++rt)
#pragma unroll
        for (int ct = 0; ct < 4; ++ct) r1[rt][ct] = (f32x4){0.f, 0.f, 0.f, 0.f};
#pragma unroll
    for (int kk = 0; kk < 2; ++kk)
#pragma unroll
        for (int rt = 0; rt < 4; ++rt)
#pragma unroll
            for (int ct = 0; ct < 4; ++ct)
                r1[rt][ct] = __builtin_amdgcn_mfma_f32_16x16x32_bf16(
                    af[rt][kk], wb[kk][ct], r1[rt][ct], 0, 0, 0);

    if (z != 0) {
        // single-stage: krb (z==1) or vrb (z==2) = relu(r1 + rb1)
        const void* rb = a.rb1[z];
        u16* out = (z == 1) ? a.krb : a.vrb;
#pragma unroll
        for (int ct = 0; ct < 4; ++ct) {
            int cl = ct * 16 + l16;
            float bv = f ? ((const float*)rb)[cl] : bf2f(((const u16*)rb)[cl]);
#pragma unroll
            for (int rt = 0; rt < 4; ++rt)
#pragma unroll
                for (int r = 0; r < 4; ++r) {
                    float v = r1[rt][ct][r] + bv;
                    v = v > 0.f ? v : 0.f;
                    out[(size_t)(m0 + wr + rt * 16 + quad * 4 + r) * DM_ + hcol + cl]
                        = f2bf(v);
                }
        }
    } else {
        // q1a = relu(r1 + bql) -> Es (round-trip for stage 2)
        {
            const void* rb = a.rb1[0];
#pragma unroll
            for (int ct = 0; ct < 4; ++ct) {
                int cl = ct * 16 + l16;
                float bv = f ? ((const float*)rb)[cl] : bf2f(((const u16*)rb)[cl]);
#pragma unroll
                for (int rt = 0; rt < 4; ++rt)
#pragma unroll
                    for (int r = 0; r < 4; ++r) {
                        float v = r1[rt][ct][r] + bv;
                        v = v > 0.f ? v : 0.f;
                        int ml = rt * 16 + quad * 4 + r;
                        Es[ml][((((cl >> 3) ^ (ml & 7)) << 3) | (cl & 7))] = f2bf(v);
                    }
            }
        }
        // q2r = relu(proj @ Wq2^T + bq2)  (reuses af while Es writes land)
        {
            const u16* R3 = f ? a.R31 : a.R30;
#pragma unroll
            for (int kk = 0; kk < 2; ++kk)
#pragma unroll
                for (int ct = 0; ct < 4; ++ct)
                    wb[kk][ct] = *(const bf16x8*)
                        &R3[(size_t)(ct * 16 + l16) * 64 + kk * 32 + quad * 8];
            f32x4 r3[4][4];
#pragma unroll
            for (int rt = 0; rt < 4; ++rt)
#pragma unroll
                for (int ct = 0; ct < 4; ++ct) r3[rt][ct] = (f32x4){0.f, 0.f, 0.f, 0.f};
#pragma unroll
            for (int kk = 0; kk < 2; ++kk)
#pragma unroll
                for (int rt = 0; rt < 4; ++rt)
#pragma unroll
                    for (int ct = 0; ct < 4; ++ct)
                        r3[rt][ct] = __builtin_amdgcn_mfma_f32_16x16x32_bf16(
                            af[rt][kk], wb[kk][ct], r3[rt][ct], 0, 0, 0);
            const void* rb = a.rb3;
#pragma unroll
            for (int ct = 0; ct < 4; ++ct) {
                int cl = ct * 16 + l16;
                float bv = f ? ((const float*)rb)[cl] : bf2f(((const u16*)rb)[cl]);
#pragma unroll
                for (int rt = 0; rt < 4; ++rt)
#pragma unroll
                    for (int r = 0; r < 4; ++r) {
                        float v = r3[rt][ct][r] + bv;
                        v = v > 0.f ? v : 0.f;
                        a.q2r[(size_t)(m0 + wr + rt * 16 + quad * 4 + r) * DM_
                              + hcol + cl] = f2bf(v);
                    }
            }
        }
        // q1b = relu(q1a @ Wel^T + bel)
        {
#pragma unroll
            for (int rt = 0; rt < 4; ++rt)
#pragma unroll
                for (int kk = 0; kk < 2; ++kk)
                    af[rt][kk] = *(const bf16x8*)
                        &Es[rt * 16 + l16][(((kk * 4 + quad) ^ (l16 & 7)) << 3)];
            const u16* R2 = f ? a.R21 : a.R20;
#pragma unroll
            for (int kk = 0; kk < 2; ++kk)
#pragma unroll
                for (int ct = 0; ct < 4; ++ct)
                    wb[kk][ct] = *(const bf16x8*)
                        &R2[(size_t)(ct * 16 + l16) * 64 + kk * 32 + quad * 8];
            f32x4 r2[4][4];
#pragma unroll
            for (int rt = 0; rt < 4; ++rt)
#pragma unroll
                for (int ct = 0; ct < 4; ++ct) r2[rt][ct] = (f32x4){0.f, 0.f, 0.f, 0.f};
#pragma unroll
            for (int kk = 0; kk < 2; ++kk)
#pragma unroll
                for (int rt = 0; rt < 4; ++rt)
#pragma unroll
                    for (int ct = 0; ct < 4; ++ct)
                        r2[rt][ct] = __builtin_amdgcn_mfma_f32_16x16x32_bf16(
                            af[rt][kk], wb[kk][ct], r2[rt][ct], 0, 0, 0);
            const void* rb = a.rb2;
#pragma unroll
            for (int ct = 0; ct < 4; ++ct) {
                int cl = ct * 16 + l16;
                float bv = f ? ((const float*)rb)[cl] : bf2f(((const u16*)rb)[cl]);
#pragma unroll
                for (int rt = 0; rt < 4; ++rt)
#pragma unroll
                    for (int r = 0; r < 4; ++r) {
                        float v = r2[rt][ct][r] + bv;
                        v = v > 0.f ? v : 0.f;
                        a.q1b[(size_t)(m0 + wr + rt * 16 + quad * 4 + r) * DM_
                              + hcol + cl] = f2bf(v);
                    }
            }
        }
    }
}

// ---------------------------------------------------------------------------
// Output-projection GEMM (m97 structure), dtype-dynamic bias/out.
// ---------------------------------------------------------------------------
__global__ __launch_bounds__(256, 3) void gemm_async_kernel(
    const u16* __restrict__ Ain, const u16* __restrict__ W0,
    const u16* __restrict__ W1, const void* __restrict__ biasp,
    void* __restrict__ Cp, const int* __restrict__ flag)
{
    __shared__ __align__(16) u16 As[128][64];
    __shared__ __align__(16) u16 Ws[128][64];

    const int f = *flag;
    const u16* __restrict__ W = f ? W1 : W0;

    const int m0   = blockIdx.y * 128;
    const int n0   = blockIdx.x * 128;
    const int tid  = threadIdx.x;
    const int w    = tid >> 6;
    const int lane = tid & 63;
    const int l16  = lane & 15;
    const int quad = lane >> 4;
    const int wr   = (w >> 1) * 64;
    const int wc   = (w & 1) * 64;

    const int srow = lane >> 3;
    const int sgrp = (lane & 7) ^ srow;

    f32x4 acc[4][4];
#pragma unroll
    for (int rt = 0; rt < 4; ++rt)
#pragma unroll
        for (int ct = 0; ct < 4; ++ct) acc[rt][ct] = (f32x4){0.f, 0.f, 0.f, 0.f};

    for (int k0 = 0; k0 < DM_; k0 += 64) {
#pragma unroll
        for (int s = 0; s < 4; ++s) {
            int seg = w * 4 + s;
            async_ld16(&Ain[(size_t)(m0 + seg * 8 + srow) * DM_ + k0 + sgrp * 8],
                       &As[seg * 8][0]);
            async_ld16(&W[(size_t)(n0 + seg * 8 + srow) * DM_ + k0 + sgrp * 8],
                       &Ws[seg * 8][0]);
        }
        __syncthreads();
#pragma unroll
        for (int kk = 0; kk < 2; ++kk) {
            const int p = (kk * 4 + quad) ^ (l16 & 7);
            bf16x8 av[4], bv[4];
#pragma unroll
            for (int rt = 0; rt < 4; ++rt)
                av[rt] = *(const bf16x8*)&As[wr + rt * 16 + l16][p * 8];
#pragma unroll
            for (int ct = 0; ct < 4; ++ct)
                bv[ct] = *(const bf16x8*)&Ws[wc + ct * 16 + l16][p * 8];
#pragma unroll
            for (int rt = 0; rt < 4; ++rt)
#pragma unroll
                for (int ct = 0; ct < 4; ++ct)
                    acc[rt][ct] = __builtin_amdgcn_mfma_f32_16x16x32_bf16(
                        av[rt], bv[ct], acc[rt][ct], 0, 0, 0);
        }
        __syncthreads();
    }

#pragma unroll
    for (int ct = 0; ct < 4; ++ct) {
        int col = n0 + wc + ct * 16 + l16;
        float bv = f ? ((const float*)biasp)[col] : bf2f(((const u16*)biasp)[col]);
#pragma unroll
        for (int rt = 0; rt < 4; ++rt)
#pragma unroll
            for (int r = 0; r < 4; ++r) {
                int row = m0 + wr + rt * 16 + quad * 4 + r;
                float v = acc[rt][ct][r] + bv;
                size_t idx = (size_t)row * DM_ + col;
                if (f) ((float*)Cp)[idx] = v;
                else   ((u16*)Cp)[idx]   = f2bf(v);
            }
    }
}

// ---------------------------------------------------------------------------
// Fused attention, R11: NO K/V/KpT LDS staging. R1's counters showed the
// panels are fully L2-resident (FETCH 20 MB, HBM 5%), so staging was pure
// overhead (guide m169: dropping L2-fit V-staging was +26%). B-operand
// fragments are gathered straight from global: each bf16x8 load touches 16
// rows x one 64B-aligned line, all L2/L1-hot. This removes every barrier
// from the main loop (only remaining LDS is the per-wave pts transpose
// buffer), shrinks LDS 73.7->18.4 KB, and lifts occupancy to 3 waves/SIMD
// via __launch_bounds__(256,3). XCD swizzle (T1) + setprio (T5) kept.
// ---------------------------------------------------------------------------
__global__ __launch_bounds__(256, 3) void attn_kernel(
    const u16* __restrict__ q1, const u16* __restrict__ q2,
    const u16* __restrict__ kr, const u16* __restrict__ vr,
    const u16* __restrict__ kpt, const int* __restrict__ mask,
    const int* __restrict__ tflags, u16* __restrict__ om)
{
    __shared__ __align__(16) u16 pts[4][32][72];   // per-wave P~ staging (only LDS)

    // bijective XCD swizzle: hw XCD = bid%8; XCD x gets orig ids x*64..x*64+63
    // = (b,h) pairs 8x..8x+7 complete (8 q-tiles each) -> panels L2-resident.
    const int bid  = blockIdx.x;                  // 0..511 flat
    const int orig = (bid & 7) * 64 + (bid >> 3);
    const int qt = orig & 7;
    const int h  = (orig >> 3) & 15;
    const int b  = orig >> 7;

    const int q0   = qt * 128;
    const int tid  = threadIdx.x;
    const int w    = tid >> 6;
    const int lane = tid & 63;
    const int l16  = lane & 15;
    const int quad = lane >> 4;

    const size_t base  = (size_t)b * S_ * DM_ + (size_t)h * DK_;
    const size_t baseT = (size_t)(b * H_ + h) * DK_ * S_;

    // per-lane base pointers for B-side gathers (row = ct*16+l16, col chunk = quad)
    const u16* __restrict__ krL = kr  + base  + (size_t)l16 * DM_ + quad * 8;
    const u16* __restrict__ vrL = vr  + base  + (size_t)l16 * DM_ + quad * 8;
    const u16* __restrict__ ktL = kpt + baseT + (size_t)l16 * S_  + quad * 8;

    bf16x8 a1[2][2], a2[2][2];
#pragma unroll
    for (int rt = 0; rt < 2; ++rt) {
        const int qrow = q0 + w * 32 + rt * 16 + l16;
#pragma unroll
        for (int kk = 0; kk < 2; ++kk) {
            a1[rt][kk] = *(const bf16x8*)&q1[base + (size_t)qrow * DM_ + kk * 32 + quad * 8];
            a2[rt][kk] = *(const bf16x8*)&q2[base + (size_t)qrow * DM_ + kk * 32 + quad * 8];
        }
    }

    float m_run[2][4], l_run[2][4];
    f32x4 oacc[2][4];
#pragma unroll
    for (int rt = 0; rt < 2; ++rt)
#pragma unroll
        for (int r = 0; r < 4; ++r) { m_run[rt][r] = -1e30f; l_run[rt][r] = 0.f; }
#pragma unroll
    for (int rt = 0; rt < 2; ++rt)
#pragma unroll
        for (int ct = 0; ct < 4; ++ct) oacc[rt][ct] = (f32x4){0.f, 0.f, 0.f, 0.f};

    for (int kt = 0; kt < S_ / 64; ++kt) {
        const int k0 = kt * 64;
        const int tf = tflags[b * 16 + kt];

        f32x4 s1[2][4], s2[2][4];
#pragma unroll
        for (int rt = 0; rt < 2; ++rt)
#pragma unroll
            for (int ct = 0; ct < 4; ++ct) {
                s1[rt][ct] = (f32x4){0.f, 0.f, 0.f, 0.f};
                s2[rt][ct] = (f32x4){0.f, 0.f, 0.f, 0.f};
            }
        __builtin_amdgcn_s_setprio(1);
#pragma unroll
        for (int kk = 0; kk < 2; ++kk) {
            bf16x8 b1[4], b2[4];
#pragma unroll
            for (int ct = 0; ct < 4; ++ct) {
                b1[ct] = *(const bf16x8*)&krL[(size_t)(k0 + ct * 16) * DM_ + kk * 32];
                b2[ct] = *(const bf16x8*)&vrL[(size_t)(k0 + ct * 16) * DM_ + kk * 32];
            }
#pragma unroll
            for (int rt = 0; rt < 2; ++rt)
#pragma unroll
                for (int ct = 0; ct < 4; ++ct) {
                    s1[rt][ct] = __builtin_amdgcn_mfma_f32_16x16x32_bf16(
                        a1[rt][kk], b1[ct], s1[rt][ct], 0, 0, 0);
                    s2[rt][ct] = __builtin_amdgcn_mfma_f32_16x16x32_bf16(
                        a2[rt][kk], b2[ct], s2[rt][ct], 0, 0, 0);
                }
        }
        __builtin_amdgcn_s_setprio(0);

        if (tf) {
#pragma unroll
            for (int rt = 0; rt < 2; ++rt)
#pragma unroll
                for (int ct = 0; ct < 4; ++ct)
#pragma unroll
                    for (int r = 0; r < 4; ++r) {
                        int qrow = q0 + w * 32 + rt * 16 + quad * 4 + r;
                        int kc   = k0 + ct * 16 + l16;
                        if (mask[((size_t)b * S_ + qrow) * S_ + kc] == 0)
                            s1[rt][ct][r] = -1e9f;
                    }
        }

        float tmax[2][4];
#pragma unroll
        for (int rt = 0; rt < 2; ++rt)
#pragma unroll
            for (int r = 0; r < 4; ++r) tmax[rt][r] = -1e30f;
#pragma unroll
        for (int rt = 0; rt < 2; ++rt)
#pragma unroll
            for (int ct = 0; ct < 4; ++ct)
#pragma unroll
                for (int r = 0; r < 4; ++r)
                    tmax[rt][r] = fmaxf(tmax[rt][r], s1[rt][ct][r]);
#pragma unroll
        for (int off = 1; off < 16; off <<= 1)
#pragma unroll
            for (int rt = 0; rt < 2; ++rt)
#pragma unroll
                for (int r = 0; r < 4; ++r)
                    tmax[rt][r] = fmaxf(tmax[rt][r], __shfl_xor(tmax[rt][r], off, 64));

        float alpha[2][4], newm[2][4];
#pragma unroll
        for (int rt = 0; rt < 2; ++rt)
#pragma unroll
            for (int r = 0; r < 4; ++r) {
                newm[rt][r]  = fmaxf(m_run[rt][r], tmax[rt][r]);
                alpha[rt][r] = __expf(m_run[rt][r] - newm[rt][r]);
                m_run[rt][r] = newm[rt][r];
            }

        float psum[2][4] = {};
#pragma unroll
        for (int rt = 0; rt < 2; ++rt)
#pragma unroll
            for (int ct = 0; ct < 4; ++ct)
#pragma unroll
                for (int r = 0; r < 4; ++r) {
                    float p = __expf(s1[rt][ct][r] - newm[rt][r]);
                    psum[rt][r] += p;
                    pts[w][rt * 16 + quad * 4 + r][ct * 16 + l16] =
                        f2bf_fast(p * s2[rt][ct][r]);
                }
#pragma unroll
        for (int off = 1; off < 16; off <<= 1)
#pragma unroll
            for (int rt = 0; rt < 2; ++rt)
#pragma unroll
                for (int r = 0; r < 4; ++r)
                    psum[rt][r] += __shfl_xor(psum[rt][r], off, 64);
#pragma unroll
        for (int rt = 0; rt < 2; ++rt)
#pragma unroll
            for (int r = 0; r < 4; ++r)
                l_run[rt][r] = l_run[rt][r] * alpha[rt][r] + psum[rt][r];
#pragma unroll
        for (int rt = 0; rt < 2; ++rt)
#pragma unroll
            for (int ct = 0; ct < 4; ++ct)
#pragma unroll
                for (int r = 0; r < 4; ++r) oacc[rt][ct][r] *= alpha[rt][r];

        {
            __builtin_amdgcn_s_setprio(1);
            bf16x8 bb[2][4];
#pragma unroll
            for (int kk = 0; kk < 2; ++kk)
#pragma unroll
                for (int ct = 0; ct < 4; ++ct)
                    bb[kk][ct] = *(const bf16x8*)&ktL[(size_t)(ct * 16) * S_ + k0 + kk * 32];
#pragma unroll
            for (int rt = 0; rt < 2; ++rt)
#pragma unroll
                for (int kk = 0; kk < 2; ++kk) {
                    // per-wave DS in-order: reads see this wave's pts writes
                    bf16x8 a = *(const bf16x8*)&pts[w][rt * 16 + l16][kk * 32 + quad * 8];
#pragma unroll
                    for (int ct = 0; ct < 4; ++ct)
                        oacc[rt][ct] = __builtin_amdgcn_mfma_f32_16x16x32_bf16(
                            a, bb[kk][ct], oacc[rt][ct], 0, 0, 0);
                }
            __builtin_amdgcn_s_setprio(0);
        }
    }

#pragma unroll
    for (int rt = 0; rt < 2; ++rt)
#pragma unroll
        for (int ct = 0; ct < 4; ++ct)
#pragma unroll
            for (int r = 0; r < 4; ++r) {
                int row = q0 + w * 32 + rt * 16 + quad * 4 + r;
                int col = ct * 16 + l16;
                float v = oacc[rt][ct][r] / l_run[rt][r];
                om[base + (size_t)row * DM_ + col] = f2bf_fast(v);
            }
}

// ---------------------------------------------------------------------------
extern "C" void kernel_launch(void* const* d_in, const int* in_sizes, int n_in,
                              void* d_out, int out_size, void* d_ws, size_t ws_size,
                              hipStream_t stream)
{
    const void* query = d_in[0];
    const void* key   = d_in[1];
    const void* value = d_in[2];
    const int*  mask  = (const int*)d_in[3];
    const void* Wq  = d_in[4];  const void* bq  = d_in[5];
    const void* Wk  = d_in[6];  const void* bk  = d_in[7];
    const void* Wv  = d_in[8];  const void* bv  = d_in[9];
    const void* Wo  = d_in[10]; const void* bo  = d_in[11];
    const void* Wkl = d_in[12]; const void* bkl = d_in[13];
    const void* Wql = d_in[14]; const void* bql = d_in[15];
    const void* Wq2 = d_in[16]; const void* bq2 = d_in[17];
    const void* Wvl = d_in[18]; const void* bvl = d_in[19];
    const void* Wel = d_in[20]; const void* bel = d_in[21];

    int* flag   = (int*)d_ws;
    int* tflags = (int*)d_ws + 4;                     // 64 ints
    u16* ws     = (u16*)((char*)d_ws + 512);
    const size_t BUF = (size_t)(B_ * S_) * DM_;       // 4M elems = 8 MB bf16
    u16* Kp  = ws + 0 * BUF;
    u16* krb = ws + 1 * BUF;
    u16* q1b = ws + 2 * BUF;
    u16* q2r = ws + 3 * BUF;
    u16* vrb = ws + 4 * BUF;
    u16* Om  = ws + 5 * BUF;
    u16* KpT = ws + 6 * BUF;
    u16* Qc  = ws + 7 * BUF;
    u16* Kc  = ws + 8 * BUF;
    u16* Vc  = ws + 9 * BUF;
    u16* Wbig = ws + 10 * BUF;
    u16* Wqc = Wbig + 0 * (size_t)(DM_ * DM_);
    u16* Wkc = Wbig + 1 * (size_t)(DM_ * DM_);
    u16* Wvc = Wbig + 2 * (size_t)(DM_ * DM_);
    u16* Woc = Wbig + 3 * (size_t)(DM_ * DM_);
    u16* Wsm = Wbig + 4 * (size_t)(DM_ * DM_);
    u16* Wklc = Wsm + 0 * (DK_ * DK_);
    u16* Wqlc = Wsm + 1 * (DK_ * DK_);
    u16* Welc = Wsm + 2 * (DK_ * DK_);
    u16* Wq2c = Wsm + 3 * (DK_ * DK_);
    u16* Wvlc = Wsm + 4 * (DK_ * DK_);

    const int M = B_ * S_;
    dim3 blk(256);

    detect_kernel<<<1, 64, 0, stream>>>((const u16*)query, flag);

    // fused mask-flag scan + dtype conversion
    hipMemsetAsync(tflags, 0, 64 * sizeof(int), stream);
    CvtArgs ca;
    const unsigned VIN = (unsigned)(BUF / 8);
    const unsigned VWB = (unsigned)(DM_ * DM_ / 8);
    const unsigned VWS = (unsigned)(DK_ * DK_ / 8);
    const void* srcs[NSEG] = {query, key, value, Wq, Wk, Wv, Wo, Wkl, Wql, Wel, Wq2, Wvl};
    void* dsts[NSEG] = {Qc, Kc, Vc, Wqc, Wkc, Wvc, Woc, Wklc, Wqlc, Welc, Wq2c, Wvlc};
    unsigned vcn[NSEG] = {VIN, VIN, VIN, VWB, VWB, VWB, VWB, VWS, VWS, VWS, VWS, VWS};
    unsigned off = 0;
    for (int i = 0; i < NSEG; ++i) { ca.src[i] = srcs[i]; ca.dst[i] = dsts[i]; ca.off[i] = off; off += vcn[i]; }
    ca.off[NSEG] = off;
    prep_kernel<<<dim3(512 + (off + 255) / 256), blk, 0, stream>>>(ca, off, flag, mask, tflags);

    // Q/K/V projections + fused per-head refinements (768 blocks)
    QKVArgs qa = {};
    qa.A0[0] = (const u16*)query; qa.A1[0] = Qc;
    qa.A0[1] = (const u16*)key;   qa.A1[1] = Kc;
    qa.A0[2] = (const u16*)value; qa.A1[2] = Vc;
    qa.W0[0] = (const u16*)Wq; qa.W1[0] = Wqc;
    qa.W0[1] = (const u16*)Wk; qa.W1[1] = Wkc;
    qa.W0[2] = (const u16*)Wv; qa.W1[2] = Wvc;
    qa.bias[0] = bq; qa.bias[1] = bk; qa.bias[2] = bv;
    qa.R10[0] = (const u16*)Wql; qa.R11[0] = Wqlc; qa.rb1[0] = bql;
    qa.R10[1] = (const u16*)Wkl; qa.R11[1] = Wklc; qa.rb1[1] = bkl;
    qa.R10[2] = (const u16*)Wvl; qa.R11[2] = Wvlc; qa.rb1[2] = bvl;
    qa.R20 = (const u16*)Wel; qa.R21 = Welc; qa.rb2 = bel;
    qa.R30 = (const u16*)Wq2; qa.R31 = Wq2c; qa.rb3 = bq2;
    qa.Kp = Kp; qa.q1b = q1b; qa.q2r = q2r; qa.krb = krb; qa.vrb = vrb;
    dim3 gBig(DM_ / 128, M / 128, 3);
    qkv_fused_kernel<<<gBig, blk, 0, stream>>>(qa, flag);

    // Kp -> per-head transposed copy
    dim3 gT(S_ / 64, H_, B_);
    transpose_kernel<<<gT, blk, 0, stream>>>(Kp, KpT);

    // fused attention -> merged (B,S,DM) layout (128 q-rows per block,
    // flat grid + XCD swizzle: one (b,h) pair's 8 q-blocks per XCD)
    attn_kernel<<<dim3(512), blk, 0, stream>>>(q1b, q2r, krb, vrb, KpT, mask, tflags, Om);

    // output projection -> d_out
    dim3 gO(DM_ / 128, M / 128);
    gemm_async_kernel<<<gO, blk, 0, stream>>>(Om, (const u16*)Wo, Woc, bo, d_out, flag);
}

// Round 3
// 332.440 us; speedup vs baseline: 1.1689x; 1.1689x over previous
//
#include <hip/hip_runtime.h>
#include <hip/hip_bf16.h>

#define B_  4
#define S_  1024
#define DM_ 1024
#define H_  16
#define DK_ 64

typedef unsigned short u16;
typedef __attribute__((ext_vector_type(8))) short bf16x8;
typedef __attribute__((ext_vector_type(4))) float f32x4;

__device__ __forceinline__ float bf2f(u16 u) {
    union { unsigned int i; float f; } c;
    c.i = ((unsigned int)u) << 16;
    return c.f;
}
__device__ __forceinline__ u16 f2bf(float f) {
    union { float f; unsigned int i; } c;
    c.f = f;
    unsigned int x = c.i;
    unsigned int lsb = (x >> 16) & 1u;
    x += 0x7fffu + lsb;          // round-to-nearest-even
    return (u16)(x >> 16);
}
__device__ __forceinline__ u16 f2bf_fast(float f) {
    __hip_bfloat16 h = __float2bfloat16(f);   // HW cvt, RNE
    return *reinterpret_cast<u16*>(&h);
}

// async global->LDS, 16B per lane; LDS dest = wave-uniform base + lane*16
__device__ __forceinline__ void async_ld16(const u16* g, u16* l) {
    __builtin_amdgcn_global_load_lds(
        (const __attribute__((address_space(1))) unsigned int*)(const void*)g,
        (__attribute__((address_space(3))) unsigned int*)(void*)l, 16, 0, 0);
}

// ---------------------------------------------------------------------------
// Runtime dtype detection (one wave). flag=1: inputs are fp32.
// ---------------------------------------------------------------------------
__global__ void detect_kernel(const u16* __restrict__ q, int* __restrict__ flag) {
    int lane = threadIdx.x & 63;
    int cnt = 0;
#pragma unroll
    for (int i = 0; i < 4; ++i) {
        u16 u = q[2 * (lane * 4 + i)];
        int e = (u >> 7) & 0xFF;
        cnt += (e >= 100 && e <= 140) ? 1 : 0;
    }
#pragma unroll
    for (int off = 1; off < 64; off <<= 1) cnt += __shfl_xor(cnt, off, 64);
    if (lane == 0) *flag = (cnt < 128) ? 1 : 0;
}

// ---------------------------------------------------------------------------
// Fused prep: blocks [0,512) scan mask -> per-(b,k64-tile) any-zero flags
// (tflags pre-zeroed via hipMemsetAsync; dirty -> atomicOr 1). Blocks >= 512
// do packed fp32->bf16 conversion (early-out when inputs already bf16).
// ---------------------------------------------------------------------------
#define NSEG 12
struct CvtArgs {
    const void* src[NSEG];
    void*       dst[NSEG];
    unsigned    off[NSEG + 1];
};

__global__ __launch_bounds__(256) void prep_kernel(
    CvtArgs a, unsigned total, const int* __restrict__ flag,
    const int* __restrict__ mask, int* __restrict__ tflags)
{
    const int tid = threadIdx.x;
    if (blockIdx.x < 512) {
        const int bx = blockIdx.x;
        const int kt = bx & 15, b = (bx >> 4) & 3, z = bx >> 6;
        int ok = 1;
#pragma unroll
        for (int i = tid; i < 128 * 16; i += 256) {
            int row = z * 128 + (i >> 4), seg = i & 15;
            int4 m = *(const int4*)&mask[((size_t)b * S_ + row) * S_ + kt * 64 + seg * 4];
            ok &= (m.x != 0) & (m.y != 0) & (m.z != 0) & (m.w != 0);
        }
        if (!ok) atomicOr(&tflags[b * 16 + kt], 1);
        return;
    }
    if (!*flag) return;   // bf16 inputs: GEMMs read originals directly
    unsigned v = (blockIdx.x - 512) * 256 + tid;
    if (v >= total) return;
    int s = 0;
    while (s < NSEG - 1 && v >= a.off[s + 1]) ++s;
    unsigned local = v - a.off[s];
    u16* dp = (u16*)a.dst[s] + (size_t)local * 8;
    const float* sp = (const float*)a.src[s] + (size_t)local * 8;
    float4 x = *(const float4*)sp, y = *(const float4*)(sp + 4);
    u16 t[8] = {f2bf(x.x), f2bf(x.y), f2bf(x.z), f2bf(x.w),
                f2bf(y.x), f2bf(y.y), f2bf(y.z), f2bf(y.w)};
    *(uint4*)dp = *(uint4*)t;
}

// ---------------------------------------------------------------------------
// Per-head transpose: Kp (b,s,h,d) -> KpT[((b*H+h)*DK + d)*S + s].
// ---------------------------------------------------------------------------
__global__ __launch_bounds__(256) void transpose_kernel(
    const u16* __restrict__ kp, u16* __restrict__ kpt)
{
    __shared__ u16 T[64][65];
    const int s0 = blockIdx.x * 64, h = blockIdx.y, b = blockIdx.z;
    const int tid = threadIdx.x;
    const size_t base = (size_t)b * S_ * DM_ + (size_t)h * DK_;
    for (int c = tid; c < 512; c += 256) {
        int row = c >> 3, cc = (c & 7) * 8;
        union { uint4 v; u16 u[8]; } x;
        x.v = *(const uint4*)&kp[base + (size_t)(s0 + row) * DM_ + cc];
#pragma unroll
        for (int j = 0; j < 8; ++j) T[row][cc + j] = x.u[j];
    }
    __syncthreads();
    const size_t baseT = (size_t)(b * H_ + h) * DK_ * S_;
    for (int c = tid; c < 512; c += 256) {
        int d = c >> 3, ss = (c & 7) * 8;
        u16 t[8];
#pragma unroll
        for (int j = 0; j < 8; ++j) t[j] = T[ss + j][d];
        *(uint4*)&kpt[baseT + (size_t)d * S_ + s0 + ss] = *(uint4*)t;
    }
}

// ---------------------------------------------------------------------------
// QKV projection + fused per-head refinements. 128x128 tile, BK=64, async
// global->LDS staging, XOR column-group swizzle (m97 structure). After the
// K-loop each wave's 64x64 quadrant is ONE head's complete column block for
// 64 rows, so the row-local 64x64 refinements run entirely in the epilogue:
// C-layout acc -> per-wave LDS region (A-layout swizzled) -> MFMA with
// weight B-frags read straight from global (L2-hot, shared across heads).
// z=0 (Q): emits q1b (Wql->Wel chain) + q2r. z=1 (K): Kp + krb. z=2: vrb.
// ---------------------------------------------------------------------------
struct QKVArgs {
    const u16* A0[3]; const u16* A1[3];
    const u16* W0[3]; const u16* W1[3];
    const void* bias[3];
    const u16* R10[3]; const u16* R11[3];   // Wql, Wkl, Wvl
    const void* rb1[3];                      // bql, bkl, bvl
    const u16* R20; const u16* R21; const void* rb2;   // Wel, bel
    const u16* R30; const u16* R31; const void* rb3;   // Wq2, bq2
    u16 *Kp, *q1b, *q2r, *krb, *vrb;
};

__global__ __launch_bounds__(256, 3) void qkv_fused_kernel(
    QKVArgs a, const int* __restrict__ flag)
{
    __shared__ __align__(16) u16 smem[16384];   // 32 KB: As+Ws; epilogue 4x8KB/wave
    u16 (*As)[64] = (u16(*)[64])smem;
    u16 (*Ws)[64] = (u16(*)[64])(smem + 8192);

    const int z = blockIdx.z;
    const int f = *flag;
    const u16* __restrict__ A = f ? a.A1[z] : a.A0[z];
    const u16* __restrict__ W = f ? a.W1[z] : a.W0[z];
    const void* biasp = a.bias[z];

    const int m0   = blockIdx.y * 128;
    const int n0   = blockIdx.x * 128;
    const int tid  = threadIdx.x;
    const int w    = tid >> 6;
    const int lane = tid & 63;
    const int l16  = lane & 15;
    const int quad = lane >> 4;
    const int wr   = (w >> 1) * 64;
    const int wc   = (w & 1) * 64;

    const int srow = lane >> 3;
    const int sgrp = (lane & 7) ^ srow;

    f32x4 acc[4][4];
#pragma unroll
    for (int rt = 0; rt < 4; ++rt)
#pragma unroll
        for (int ct = 0; ct < 4; ++ct) acc[rt][ct] = (f32x4){0.f, 0.f, 0.f, 0.f};

    for (int k0 = 0; k0 < DM_; k0 += 64) {
#pragma unroll
        for (int s = 0; s < 4; ++s) {
            int seg = w * 4 + s;
            async_ld16(&A[(size_t)(m0 + seg * 8 + srow) * DM_ + k0 + sgrp * 8],
                       &As[seg * 8][0]);
            async_ld16(&W[(size_t)(n0 + seg * 8 + srow) * DM_ + k0 + sgrp * 8],
                       &Ws[seg * 8][0]);
        }
        __syncthreads();
#pragma unroll
        for (int kk = 0; kk < 2; ++kk) {
            const int p = (kk * 4 + quad) ^ (l16 & 7);
            bf16x8 av[4], bv[4];
#pragma unroll
            for (int rt = 0; rt < 4; ++rt)
                av[rt] = *(const bf16x8*)&As[wr + rt * 16 + l16][p * 8];
#pragma unroll
            for (int ct = 0; ct < 4; ++ct)
                bv[ct] = *(const bf16x8*)&Ws[wc + ct * 16 + l16][p * 8];
#pragma unroll
            for (int rt = 0; rt < 4; ++rt)
#pragma unroll
                for (int ct = 0; ct < 4; ++ct)
                    acc[rt][ct] = __builtin_amdgcn_mfma_f32_16x16x32_bf16(
                        av[rt], bv[ct], acc[rt][ct], 0, 0, 0);
        }
        __syncthreads();   // trailing barrier: all waves done reading As/Ws
    }

    // ---- fused refinement epilogue (per-wave private LDS region) ----
    const int hcol = n0 + wc;                       // = head * 64
    u16 (*Es)[64] = (u16(*)[64])(smem + w * 4096);

    // projected tile (+bias, bf16) -> Es in A-layout swizzle; z==1 also -> Kp
#pragma unroll
    for (int ct = 0; ct < 4; ++ct) {
        int col = hcol + ct * 16 + l16;
        float bv = f ? ((const float*)biasp)[col] : bf2f(((const u16*)biasp)[col]);
#pragma unroll
        for (int rt = 0; rt < 4; ++rt)
#pragma unroll
            for (int r = 0; r < 4; ++r) {
                int ml = rt * 16 + quad * 4 + r;
                int cl = ct * 16 + l16;
                u16 bb = f2bf(acc[rt][ct][r] + bv);
                if (z == 1) a.Kp[(size_t)(m0 + wr + ml) * DM_ + col] = bb;
                Es[ml][((((cl >> 3) ^ (ml & 7)) << 3) | (cl & 7))] = bb;
            }
    }

    // A-frags of the projected tile (same-wave DS in-order; no barrier needed)
    bf16x8 af[4][2];
#pragma unroll
    for (int rt = 0; rt < 4; ++rt)
#pragma unroll
        for (int kk = 0; kk < 2; ++kk)
            af[rt][kk] = *(const bf16x8*)
                &Es[rt * 16 + l16][(((kk * 4 + quad) ^ (l16 & 7)) << 3)];

    // stage-1 weight B-frags from global (64x64, L2-hot)
    const u16* R1 = f ? a.R11[z] : a.R10[z];
    bf16x8 wb[2][4];
#pragma unroll
    for (int kk = 0; kk < 2; ++kk)
#pragma unroll
        for (int ct = 0; ct < 4; ++ct)
            wb[kk][ct] = *(const bf16x8*)
                &R1[(size_t)(ct * 16 + l16) * 64 + kk * 32 + quad * 8];

    f32x4 r1[4][4];
#pragma unroll
    for (int rt = 0; rt < 4; ++rt)
#pragma unroll
        for (int ct = 0; ct < 4; ++ct) r1[rt][ct] = (f32x4){0.f, 0.f, 0.f, 0.f};
#pragma unroll
    for (int kk = 0; kk < 2; ++kk)
#pragma unroll
        for (int rt = 0; rt < 4; ++rt)
#pragma unroll
            for (int ct = 0; ct < 4; ++ct)
                r1[rt][ct] = __builtin_amdgcn_mfma_f32_16x16x32_bf16(
                    af[rt][kk], wb[kk][ct], r1[rt][ct], 0, 0, 0);

    if (z != 0) {
        // single-stage: krb (z==1) or vrb (z==2) = relu(r1 + rb1)
        const void* rb = a.rb1[z];
        u16* out = (z == 1) ? a.krb : a.vrb;
#pragma unroll
        for (int ct = 0; ct < 4; ++ct) {
            int cl = ct * 16 + l16;
            float bv = f ? ((const float*)rb)[cl] : bf2f(((const u16*)rb)[cl]);
#pragma unroll
            for (int rt = 0; rt < 4; ++rt)
#pragma unroll
                for (int r = 0; r < 4; ++r) {
                    float v = r1[rt][ct][r] + bv;
                    v = v > 0.f ? v : 0.f;
                    out[(size_t)(m0 + wr + rt * 16 + quad * 4 + r) * DM_ + hcol + cl]
                        = f2bf(v);
                }
        }
    } else {
        // q1a = relu(r1 + bql) -> Es (round-trip for stage 2)
        {
            const void* rb = a.rb1[0];
#pragma unroll
            for (int ct = 0; ct < 4; ++ct) {
                int cl = ct * 16 + l16;
                float bv = f ? ((const float*)rb)[cl] : bf2f(((const u16*)rb)[cl]);
#pragma unroll
                for (int rt = 0; rt < 4; ++rt)
#pragma unroll
                    for (int r = 0; r < 4; ++r) {
                        float v = r1[rt][ct][r] + bv;
                        v = v > 0.f ? v : 0.f;
                        int ml = rt * 16 + quad * 4 + r;
                        Es[ml][((((cl >> 3) ^ (ml & 7)) << 3) | (cl & 7))] = f2bf(v);
                    }
            }
        }
        // q2r = relu(proj @ Wq2^T + bq2)  (reuses af while Es writes land)
        {
            const u16* R3 = f ? a.R31 : a.R30;
#pragma unroll
            for (int kk = 0; kk < 2; ++kk)
#pragma unroll
                for (int ct = 0; ct < 4; ++ct)
                    wb[kk][ct] = *(const bf16x8*)
                        &R3[(size_t)(ct * 16 + l16) * 64 + kk * 32 + quad * 8];
            f32x4 r3[4][4];
#pragma unroll
            for (int rt = 0; rt < 4; ++rt)
#pragma unroll
                for (int ct = 0; ct < 4; ++ct) r3[rt][ct] = (f32x4){0.f, 0.f, 0.f, 0.f};
#pragma unroll
            for (int kk = 0; kk < 2; ++kk)
#pragma unroll
                for (int rt = 0; rt < 4; ++rt)
#pragma unroll
                    for (int ct = 0; ct < 4; ++ct)
                        r3[rt][ct] = __builtin_amdgcn_mfma_f32_16x16x32_bf16(
                            af[rt][kk], wb[kk][ct], r3[rt][ct], 0, 0, 0);
            const void* rb = a.rb3;
#pragma unroll
            for (int ct = 0; ct < 4; ++ct) {
                int cl = ct * 16 + l16;
                float bv = f ? ((const float*)rb)[cl] : bf2f(((const u16*)rb)[cl]);
#pragma unroll
                for (int rt = 0; rt < 4; ++rt)
#pragma unroll
                    for (int r = 0; r < 4; ++r) {
                        float v = r3[rt][ct][r] + bv;
                        v = v > 0.f ? v : 0.f;
                        a.q2r[(size_t)(m0 + wr + rt * 16 + quad * 4 + r) * DM_
                              + hcol + cl] = f2bf(v);
                    }
            }
        }
        // q1b = relu(q1a @ Wel^T + bel)
        {
#pragma unroll
            for (int rt = 0; rt < 4; ++rt)
#pragma unroll
                for (int kk = 0; kk < 2; ++kk)
                    af[rt][kk] = *(const bf16x8*)
                        &Es[rt * 16 + l16][(((kk * 4 + quad) ^ (l16 & 7)) << 3)];
            const u16* R2 = f ? a.R21 : a.R20;
#pragma unroll
            for (int kk = 0; kk < 2; ++kk)
#pragma unroll
                for (int ct = 0; ct < 4; ++ct)
                    wb[kk][ct] = *(const bf16x8*)
                        &R2[(size_t)(ct * 16 + l16) * 64 + kk * 32 + quad * 8];
            f32x4 r2[4][4];
#pragma unroll
            for (int rt = 0; rt < 4; ++rt)
#pragma unroll
                for (int ct = 0; ct < 4; ++ct) r2[rt][ct] = (f32x4){0.f, 0.f, 0.f, 0.f};
#pragma unroll
            for (int kk = 0; kk < 2; ++kk)
#pragma unroll
                for (int rt = 0; rt < 4; ++rt)
#pragma unroll
                    for (int ct = 0; ct < 4; ++ct)
                        r2[rt][ct] = __builtin_amdgcn_mfma_f32_16x16x32_bf16(
                            af[rt][kk], wb[kk][ct], r2[rt][ct], 0, 0, 0);
            const void* rb = a.rb2;
#pragma unroll
            for (int ct = 0; ct < 4; ++ct) {
                int cl = ct * 16 + l16;
                float bv = f ? ((const float*)rb)[cl] : bf2f(((const u16*)rb)[cl]);
#pragma unroll
                for (int rt = 0; rt < 4; ++rt)
#pragma unroll
                    for (int r = 0; r < 4; ++r) {
                        float v = r2[rt][ct][r] + bv;
                        v = v > 0.f ? v : 0.f;
                        a.q1b[(size_t)(m0 + wr + rt * 16 + quad * 4 + r) * DM_
                              + hcol + cl] = f2bf(v);
                    }
            }
        }
    }
}

// ---------------------------------------------------------------------------
// Output-projection GEMM (m97 structure), dtype-dynamic bias/out.
// ---------------------------------------------------------------------------
__global__ __launch_bounds__(256, 3) void gemm_async_kernel(
    const u16* __restrict__ Ain, const u16* __restrict__ W0,
    const u16* __restrict__ W1, const void* __restrict__ biasp,
    void* __restrict__ Cp, const int* __restrict__ flag)
{
    __shared__ __align__(16) u16 As[128][64];
    __shared__ __align__(16) u16 Ws[128][64];

    const int f = *flag;
    const u16* __restrict__ W = f ? W1 : W0;

    const int m0   = blockIdx.y * 128;
    const int n0   = blockIdx.x * 128;
    const int tid  = threadIdx.x;
    const int w    = tid >> 6;
    const int lane = tid & 63;
    const int l16  = lane & 15;
    const int quad = lane >> 4;
    const int wr   = (w >> 1) * 64;
    const int wc   = (w & 1) * 64;

    const int srow = lane >> 3;
    const int sgrp = (lane & 7) ^ srow;

    f32x4 acc[4][4];
#pragma unroll
    for (int rt = 0; rt < 4; ++rt)
#pragma unroll
        for (int ct = 0; ct < 4; ++ct) acc[rt][ct] = (f32x4){0.f, 0.f, 0.f, 0.f};

    for (int k0 = 0; k0 < DM_; k0 += 64) {
#pragma unroll
        for (int s = 0; s < 4; ++s) {
            int seg = w * 4 + s;
            async_ld16(&Ain[(size_t)(m0 + seg * 8 + srow) * DM_ + k0 + sgrp * 8],
                       &As[seg * 8][0]);
            async_ld16(&W[(size_t)(n0 + seg * 8 + srow) * DM_ + k0 + sgrp * 8],
                       &Ws[seg * 8][0]);
        }
        __syncthreads();
#pragma unroll
        for (int kk = 0; kk < 2; ++kk) {
            const int p = (kk * 4 + quad) ^ (l16 & 7);
            bf16x8 av[4], bv[4];
#pragma unroll
            for (int rt = 0; rt < 4; ++rt)
                av[rt] = *(const bf16x8*)&As[wr + rt * 16 + l16][p * 8];
#pragma unroll
            for (int ct = 0; ct < 4; ++ct)
                bv[ct] = *(const bf16x8*)&Ws[wc + ct * 16 + l16][p * 8];
#pragma unroll
            for (int rt = 0; rt < 4; ++rt)
#pragma unroll
                for (int ct = 0; ct < 4; ++ct)
                    acc[rt][ct] = __builtin_amdgcn_mfma_f32_16x16x32_bf16(
                        av[rt], bv[ct], acc[rt][ct], 0, 0, 0);
        }
        __syncthreads();
    }

#pragma unroll
    for (int ct = 0; ct < 4; ++ct) {
        int col = n0 + wc + ct * 16 + l16;
        float bv = f ? ((const float*)biasp)[col] : bf2f(((const u16*)biasp)[col]);
#pragma unroll
        for (int rt = 0; rt < 4; ++rt)
#pragma unroll
            for (int r = 0; r < 4; ++r) {
                int row = m0 + wr + rt * 16 + quad * 4 + r;
                float v = acc[rt][ct][r] + bv;
                size_t idx = (size_t)row * DM_ + col;
                if (f) ((float*)Cp)[idx] = v;
                else   ((u16*)Cp)[idx]   = f2bf(v);
            }
    }
}

// ---------------------------------------------------------------------------
// Fused attention, R12: R2's no-staging structure with the spill fixed.
// R2's launch_bounds(256,3) capped VGPR at 84 -> ~100 regs spilled to
// scratch (WRITE_SIZE 8->105 MB = the regression). Restore (256,2) (R1's
// bound, which held a LARGER live set in 128 VGPRs spill-free). Keeps:
// no K/V/KpT LDS staging (panels are L2-resident per R1 counters: FETCH
// 20 MB, HBM 5%), barrier-free main loop, 18.4 KB LDS (pts only), XCD
// swizzle (T1), setprio (T5).
// ---------------------------------------------------------------------------
__global__ __launch_bounds__(256, 2) void attn_kernel(
    const u16* __restrict__ q1, const u16* __restrict__ q2,
    const u16* __restrict__ kr, const u16* __restrict__ vr,
    const u16* __restrict__ kpt, const int* __restrict__ mask,
    const int* __restrict__ tflags, u16* __restrict__ om)
{
    __shared__ __align__(16) u16 pts[4][32][72];   // per-wave P~ staging (only LDS)

    // bijective XCD swizzle: hw XCD = bid%8; XCD x gets orig ids x*64..x*64+63
    // = (b,h) pairs 8x..8x+7 complete (8 q-tiles each) -> panels L2-resident.
    const int bid  = blockIdx.x;                  // 0..511 flat
    const int orig = (bid & 7) * 64 + (bid >> 3);
    const int qt = orig & 7;
    const int h  = (orig >> 3) & 15;
    const int b  = orig >> 7;

    const int q0   = qt * 128;
    const int tid  = threadIdx.x;
    const int w    = tid >> 6;
    const int lane = tid & 63;
    const int l16  = lane & 15;
    const int quad = lane >> 4;

    const size_t base  = (size_t)b * S_ * DM_ + (size_t)h * DK_;
    const size_t baseT = (size_t)(b * H_ + h) * DK_ * S_;

    // per-lane base pointers for B-side gathers (row = ct*16+l16, col chunk = quad)
    const u16* __restrict__ krL = kr  + base  + (size_t)l16 * DM_ + quad * 8;
    const u16* __restrict__ vrL = vr  + base  + (size_t)l16 * DM_ + quad * 8;
    const u16* __restrict__ ktL = kpt + baseT + (size_t)l16 * S_  + quad * 8;

    bf16x8 a1[2][2], a2[2][2];
#pragma unroll
    for (int rt = 0; rt < 2; ++rt) {
        const int qrow = q0 + w * 32 + rt * 16 + l16;
#pragma unroll
        for (int kk = 0; kk < 2; ++kk) {
            a1[rt][kk] = *(const bf16x8*)&q1[base + (size_t)qrow * DM_ + kk * 32 + quad * 8];
            a2[rt][kk] = *(const bf16x8*)&q2[base + (size_t)qrow * DM_ + kk * 32 + quad * 8];
        }
    }

    float m_run[2][4], l_run[2][4];
    f32x4 oacc[2][4];
#pragma unroll
    for (int rt = 0; rt < 2; ++rt)
#pragma unroll
        for (int r = 0; r < 4; ++r) { m_run[rt][r] = -1e30f; l_run[rt][r] = 0.f; }
#pragma unroll
    for (int rt = 0; rt < 2; ++rt)
#pragma unroll
        for (int ct = 0; ct < 4; ++ct) oacc[rt][ct] = (f32x4){0.f, 0.f, 0.f, 0.f};

    for (int kt = 0; kt < S_ / 64; ++kt) {
        const int k0 = kt * 64;
        const int tf = tflags[b * 16 + kt];

        f32x4 s1[2][4], s2[2][4];
#pragma unroll
        for (int rt = 0; rt < 2; ++rt)
#pragma unroll
            for (int ct = 0; ct < 4; ++ct) {
                s1[rt][ct] = (f32x4){0.f, 0.f, 0.f, 0.f};
                s2[rt][ct] = (f32x4){0.f, 0.f, 0.f, 0.f};
            }
        __builtin_amdgcn_s_setprio(1);
#pragma unroll
        for (int kk = 0; kk < 2; ++kk) {
            bf16x8 b1[4], b2[4];
#pragma unroll
            for (int ct = 0; ct < 4; ++ct) {
                b1[ct] = *(const bf16x8*)&krL[(size_t)(k0 + ct * 16) * DM_ + kk * 32];
                b2[ct] = *(const bf16x8*)&vrL[(size_t)(k0 + ct * 16) * DM_ + kk * 32];
            }
#pragma unroll
            for (int rt = 0; rt < 2; ++rt)
#pragma unroll
                for (int ct = 0; ct < 4; ++ct) {
                    s1[rt][ct] = __builtin_amdgcn_mfma_f32_16x16x32_bf16(
                        a1[rt][kk], b1[ct], s1[rt][ct], 0, 0, 0);
                    s2[rt][ct] = __builtin_amdgcn_mfma_f32_16x16x32_bf16(
                        a2[rt][kk], b2[ct], s2[rt][ct], 0, 0, 0);
                }
        }
        __builtin_amdgcn_s_setprio(0);

        if (tf) {
#pragma unroll
            for (int rt = 0; rt < 2; ++rt)
#pragma unroll
                for (int ct = 0; ct < 4; ++ct)
#pragma unroll
                    for (int r = 0; r < 4; ++r) {
                        int qrow = q0 + w * 32 + rt * 16 + quad * 4 + r;
                        int kc   = k0 + ct * 16 + l16;
                        if (mask[((size_t)b * S_ + qrow) * S_ + kc] == 0)
                            s1[rt][ct][r] = -1e9f;
                    }
        }

        float tmax[2][4];
#pragma unroll
        for (int rt = 0; rt < 2; ++rt)
#pragma unroll
            for (int r = 0; r < 4; ++r) tmax[rt][r] = -1e30f;
#pragma unroll
        for (int rt = 0; rt < 2; ++rt)
#pragma unroll
            for (int ct = 0; ct < 4; ++ct)
#pragma unroll
                for (int r = 0; r < 4; ++r)
                    tmax[rt][r] = fmaxf(tmax[rt][r], s1[rt][ct][r]);
#pragma unroll
        for (int off = 1; off < 16; off <<= 1)
#pragma unroll
            for (int rt = 0; rt < 2; ++rt)
#pragma unroll
                for (int r = 0; r < 4; ++r)
                    tmax[rt][r] = fmaxf(tmax[rt][r], __shfl_xor(tmax[rt][r], off, 64));

        float alpha[2][4], newm[2][4];
#pragma unroll
        for (int rt = 0; rt < 2; ++rt)
#pragma unroll
            for (int r = 0; r < 4; ++r) {
                newm[rt][r]  = fmaxf(m_run[rt][r], tmax[rt][r]);
                alpha[rt][r] = __expf(m_run[rt][r] - newm[rt][r]);
                m_run[rt][r] = newm[rt][r];
            }

        float psum[2][4] = {};
#pragma unroll
        for (int rt = 0; rt < 2; ++rt)
#pragma unroll
            for (int ct = 0; ct < 4; ++ct)
#pragma unroll
                for (int r = 0; r < 4; ++r) {
                    float p = __expf(s1[rt][ct][r] - newm[rt][r]);
                    psum[rt][r] += p;
                    pts[w][rt * 16 + quad * 4 + r][ct * 16 + l16] =
                        f2bf_fast(p * s2[rt][ct][r]);
                }
#pragma unroll
        for (int off = 1; off < 16; off <<= 1)
#pragma unroll
            for (int rt = 0; rt < 2; ++rt)
#pragma unroll
                for (int r = 0; r < 4; ++r)
                    psum[rt][r] += __shfl_xor(psum[rt][r], off, 64);
#pragma unroll
        for (int rt = 0; rt < 2; ++rt)
#pragma unroll
            for (int r = 0; r < 4; ++r)
                l_run[rt][r] = l_run[rt][r] * alpha[rt][r] + psum[rt][r];
#pragma unroll
        for (int rt = 0; rt < 2; ++rt)
#pragma unroll
            for (int ct = 0; ct < 4; ++ct)
#pragma unroll
                for (int r = 0; r < 4; ++r) oacc[rt][ct][r] *= alpha[rt][r];

        {
            __builtin_amdgcn_s_setprio(1);
            bf16x8 bb[2][4];
#pragma unroll
            for (int kk = 0; kk < 2; ++kk)
#pragma unroll
                for (int ct = 0; ct < 4; ++ct)
                    bb[kk][ct] = *(const bf16x8*)&ktL[(size_t)(ct * 16) * S_ + k0 + kk * 32];
#pragma unroll
            for (int rt = 0; rt < 2; ++rt)
#pragma unroll
                for (int kk = 0; kk < 2; ++kk) {
                    // per-wave DS in-order: reads see this wave's pts writes
                    bf16x8 a = *(const bf16x8*)&pts[w][rt * 16 + l16][kk * 32 + quad * 8];
#pragma unroll
                    for (int ct = 0; ct < 4; ++ct)
                        oacc[rt][ct] = __builtin_amdgcn_mfma_f32_16x16x32_bf16(
                            a, bb[kk][ct], oacc[rt][ct], 0, 0, 0);
                }
            __builtin_amdgcn_s_setprio(0);
        }
    }

#pragma unroll
    for (int rt = 0; rt < 2; ++rt)
#pragma unroll
        for (int ct = 0; ct < 4; ++ct)
#pragma unroll
            for (int r = 0; r < 4; ++r) {
                int row = q0 + w * 32 + rt * 16 + quad * 4 + r;
                int col = ct * 16 + l16;
                float v = oacc[rt][ct][r] / l_run[rt][r];
                om[base + (size_t)row * DM_ + col] = f2bf_fast(v);
            }
}

// ---------------------------------------------------------------------------
extern "C" void kernel_launch(void* const* d_in, const int* in_sizes, int n_in,
                              void* d_out, int out_size, void* d_ws, size_t ws_size,
                              hipStream_t stream)
{
    const void* query = d_in[0];
    const void* key   = d_in[1];
    const void* value = d_in[2];
    const int*  mask  = (const int*)d_in[3];
    const void* Wq  = d_in[4];  const void* bq  = d_in[5];
    const void* Wk  = d_in[6];  const void* bk  = d_in[7];
    const void* Wv  = d_in[8];  const void* bv  = d_in[9];
    const void* Wo  = d_in[10]; const void* bo  = d_in[11];
    const void* Wkl = d_in[12]; const void* bkl = d_in[13];
    const void* Wql = d_in[14]; const void* bql = d_in[15];
    const void* Wq2 = d_in[16]; const void* bq2 = d_in[17];
    const void* Wvl = d_in[18]; const void* bvl = d_in[19];
    const void* Wel = d_in[20]; const void* bel = d_in[21];

    int* flag   = (int*)d_ws;
    int* tflags = (int*)d_ws + 4;                     // 64 ints
    u16* ws     = (u16*)((char*)d_ws + 512);
    const size_t BUF = (size_t)(B_ * S_) * DM_;       // 4M elems = 8 MB bf16
    u16* Kp  = ws + 0 * BUF;
    u16* krb = ws + 1 * BUF;
    u16* q1b = ws + 2 * BUF;
    u16* q2r = ws + 3 * BUF;
    u16* vrb = ws + 4 * BUF;
    u16* Om  = ws + 5 * BUF;
    u16* KpT = ws + 6 * BUF;
    u16* Qc  = ws + 7 * BUF;
    u16* Kc  = ws + 8 * BUF;
    u16* Vc  = ws + 9 * BUF;
    u16* Wbig = ws + 10 * BUF;
    u16* Wqc = Wbig + 0 * (size_t)(DM_ * DM_);
    u16* Wkc = Wbig + 1 * (size_t)(DM_ * DM_);
    u16* Wvc = Wbig + 2 * (size_t)(DM_ * DM_);
    u16* Woc = Wbig + 3 * (size_t)(DM_ * DM_);
    u16* Wsm = Wbig + 4 * (size_t)(DM_ * DM_);
    u16* Wklc = Wsm + 0 * (DK_ * DK_);
    u16* Wqlc = Wsm + 1 * (DK_ * DK_);
    u16* Welc = Wsm + 2 * (DK_ * DK_);
    u16* Wq2c = Wsm + 3 * (DK_ * DK_);
    u16* Wvlc = Wsm + 4 * (DK_ * DK_);

    const int M = B_ * S_;
    dim3 blk(256);

    detect_kernel<<<1, 64, 0, stream>>>((const u16*)query, flag);

    // fused mask-flag scan + dtype conversion
    hipMemsetAsync(tflags, 0, 64 * sizeof(int), stream);
    CvtArgs ca;
    const unsigned VIN = (unsigned)(BUF / 8);
    const unsigned VWB = (unsigned)(DM_ * DM_ / 8);
    const unsigned VWS = (unsigned)(DK_ * DK_ / 8);
    const void* srcs[NSEG] = {query, key, value, Wq, Wk, Wv, Wo, Wkl, Wql, Wel, Wq2, Wvl};
    void* dsts[NSEG] = {Qc, Kc, Vc, Wqc, Wkc, Wvc, Woc, Wklc, Wqlc, Welc, Wq2c, Wvlc};
    unsigned vcn[NSEG] = {VIN, VIN, VIN, VWB, VWB, VWB, VWB, VWS, VWS, VWS, VWS, VWS};
    unsigned off = 0;
    for (int i = 0; i < NSEG; ++i) { ca.src[i] = srcs[i]; ca.dst[i] = dsts[i]; ca.off[i] = off; off += vcn[i]; }
    ca.off[NSEG] = off;
    prep_kernel<<<dim3(512 + (off + 255) / 256), blk, 0, stream>>>(ca, off, flag, mask, tflags);

    // Q/K/V projections + fused per-head refinements (768 blocks)
    QKVArgs qa = {};
    qa.A0[0] = (const u16*)query; qa.A1[0] = Qc;
    qa.A0[1] = (const u16*)key;   qa.A1[1] = Kc;
    qa.A0[2] = (const u16*)value; qa.A1[2] = Vc;
    qa.W0[0] = (const u16*)Wq; qa.W1[0] = Wqc;
    qa.W0[1] = (const u16*)Wk; qa.W1[1] = Wkc;
    qa.W0[2] = (const u16*)Wv; qa.W1[2] = Wvc;
    qa.bias[0] = bq; qa.bias[1] = bk; qa.bias[2] = bv;
    qa.R10[0] = (const u16*)Wql; qa.R11[0] = Wqlc; qa.rb1[0] = bql;
    qa.R10[1] = (const u16*)Wkl; qa.R11[1] = Wklc; qa.rb1[1] = bkl;
    qa.R10[2] = (const u16*)Wvl; qa.R11[2] = Wvlc; qa.rb1[2] = bvl;
    qa.R20 = (const u16*)Wel; qa.R21 = Welc; qa.rb2 = bel;
    qa.R30 = (const u16*)Wq2; qa.R31 = Wq2c; qa.rb3 = bq2;
    qa.Kp = Kp; qa.q1b = q1b; qa.q2r = q2r; qa.krb = krb; qa.vrb = vrb;
    dim3 gBig(DM_ / 128, M / 128, 3);
    qkv_fused_kernel<<<gBig, blk, 0, stream>>>(qa, flag);

    // Kp -> per-head transposed copy
    dim3 gT(S_ / 64, H_, B_);
    transpose_kernel<<<gT, blk, 0, stream>>>(Kp, KpT);

    // fused attention -> merged (B,S,DM) layout (128 q-rows per block,
    // flat grid + XCD swizzle: one (b,h) pair's 8 q-blocks per XCD)
    attn_kernel<<<dim3(512), blk, 0, stream>>>(q1b, q2r, krb, vrb, KpT, mask, tflags, Om);

    // output projection -> d_out
    dim3 gO(DM_ / 128, M / 128);
    gemm_async_kernel<<<gO, blk, 0, stream>>>(Om, (const u16*)Wo, Woc, bo, d_out, flag);
}

// Round 4
// 309.891 us; speedup vs baseline: 1.2540x; 1.0728x over previous
//
#include <hip/hip_runtime.h>
#include <hip/hip_bf16.h>

#define B_  4
#define S_  1024
#define DM_ 1024
#define H_  16
#define DK_ 64

typedef unsigned short u16;
typedef __attribute__((ext_vector_type(8))) short bf16x8;
typedef __attribute__((ext_vector_type(4))) float f32x4;

__device__ __forceinline__ float bf2f(u16 u) {
    union { unsigned int i; float f; } c;
    c.i = ((unsigned int)u) << 16;
    return c.f;
}
__device__ __forceinline__ u16 f2bf(float f) {
    union { float f; unsigned int i; } c;
    c.f = f;
    unsigned int x = c.i;
    unsigned int lsb = (x >> 16) & 1u;
    x += 0x7fffu + lsb;          // round-to-nearest-even
    return (u16)(x >> 16);
}
__device__ __forceinline__ u16 f2bf_fast(float f) {
    __hip_bfloat16 h = __float2bfloat16(f);   // HW cvt, RNE
    return *reinterpret_cast<u16*>(&h);
}

// async global->LDS, 16B per lane; LDS dest = wave-uniform base + lane*16
__device__ __forceinline__ void async_ld16(const u16* g, u16* l) {
    __builtin_amdgcn_global_load_lds(
        (const __attribute__((address_space(1))) unsigned int*)(const void*)g,
        (__attribute__((address_space(3))) unsigned int*)(void*)l, 16, 0, 0);
}

// ---------------------------------------------------------------------------
// Runtime dtype detection (one wave). flag=1: inputs are fp32.
// ---------------------------------------------------------------------------
__global__ void detect_kernel(const u16* __restrict__ q, int* __restrict__ flag) {
    int lane = threadIdx.x & 63;
    int cnt = 0;
#pragma unroll
    for (int i = 0; i < 4; ++i) {
        u16 u = q[2 * (lane * 4 + i)];
        int e = (u >> 7) & 0xFF;
        cnt += (e >= 100 && e <= 140) ? 1 : 0;
    }
#pragma unroll
    for (int off = 1; off < 64; off <<= 1) cnt += __shfl_xor(cnt, off, 64);
    if (lane == 0) *flag = (cnt < 128) ? 1 : 0;
}

// ---------------------------------------------------------------------------
// Fused prep: blocks [0,512) scan mask -> per-(b,k64-tile) any-zero flags
// (tflags pre-zeroed via hipMemsetAsync; dirty -> atomicOr 1). Blocks >= 512
// do packed fp32->bf16 conversion (early-out when inputs already bf16).
// ---------------------------------------------------------------------------
#define NSEG 12
struct CvtArgs {
    const void* src[NSEG];
    void*       dst[NSEG];
    unsigned    off[NSEG + 1];
};

__global__ __launch_bounds__(256) void prep_kernel(
    CvtArgs a, unsigned total, const int* __restrict__ flag,
    const int* __restrict__ mask, int* __restrict__ tflags)
{
    const int tid = threadIdx.x;
    if (blockIdx.x < 512) {
        const int bx = blockIdx.x;
        const int kt = bx & 15, b = (bx >> 4) & 3, z = bx >> 6;
        int ok = 1;
#pragma unroll
        for (int i = tid; i < 128 * 16; i += 256) {
            int row = z * 128 + (i >> 4), seg = i & 15;
            int4 m = *(const int4*)&mask[((size_t)b * S_ + row) * S_ + kt * 64 + seg * 4];
            ok &= (m.x != 0) & (m.y != 0) & (m.z != 0) & (m.w != 0);
        }
        if (!ok) atomicOr(&tflags[b * 16 + kt], 1);
        return;
    }
    if (!*flag) return;   // bf16 inputs: GEMMs read originals directly
    unsigned v = (blockIdx.x - 512) * 256 + tid;
    if (v >= total) return;
    int s = 0;
    while (s < NSEG - 1 && v >= a.off[s + 1]) ++s;
    unsigned local = v - a.off[s];
    u16* dp = (u16*)a.dst[s] + (size_t)local * 8;
    const float* sp = (const float*)a.src[s] + (size_t)local * 8;
    float4 x = *(const float4*)sp, y = *(const float4*)(sp + 4);
    u16 t[8] = {f2bf(x.x), f2bf(x.y), f2bf(x.z), f2bf(x.w),
                f2bf(y.x), f2bf(y.y), f2bf(y.z), f2bf(y.w)};
    *(uint4*)dp = *(uint4*)t;
}

// ---------------------------------------------------------------------------
// Per-head transpose: Kp (b,s,h,d) -> KpT[((b*H+h)*DK + d)*S + s].
// ---------------------------------------------------------------------------
__global__ __launch_bounds__(256) void transpose_kernel(
    const u16* __restrict__ kp, u16* __restrict__ kpt)
{
    __shared__ u16 T[64][65];
    const int s0 = blockIdx.x * 64, h = blockIdx.y, b = blockIdx.z;
    const int tid = threadIdx.x;
    const size_t base = (size_t)b * S_ * DM_ + (size_t)h * DK_;
    for (int c = tid; c < 512; c += 256) {
        int row = c >> 3, cc = (c & 7) * 8;
        union { uint4 v; u16 u[8]; } x;
        x.v = *(const uint4*)&kp[base + (size_t)(s0 + row) * DM_ + cc];
#pragma unroll
        for (int j = 0; j < 8; ++j) T[row][cc + j] = x.u[j];
    }
    __syncthreads();
    const size_t baseT = (size_t)(b * H_ + h) * DK_ * S_;
    for (int c = tid; c < 512; c += 256) {
        int d = c >> 3, ss = (c & 7) * 8;
        u16 t[8];
#pragma unroll
        for (int j = 0; j < 8; ++j) t[j] = T[ss + j][d];
        *(uint4*)&kpt[baseT + (size_t)d * S_ + s0 + ss] = *(uint4*)t;
    }
}

// ---------------------------------------------------------------------------
// QKV projection + fused per-head refinements. 128x128 tile, BK=64, async
// global->LDS staging, XOR column-group swizzle (m97 structure). After the
// K-loop each wave's 64x64 quadrant is ONE head's complete column block for
// 64 rows, so the row-local 64x64 refinements run entirely in the epilogue:
// C-layout acc -> per-wave LDS region (A-layout swizzled) -> MFMA with
// weight B-frags read straight from global (L2-hot, shared across heads).
// z=0 (Q): emits q1b (Wql->Wel chain) + q2r. z=1 (K): Kp + krb. z=2: vrb.
// ---------------------------------------------------------------------------
struct QKVArgs {
    const u16* A0[3]; const u16* A1[3];
    const u16* W0[3]; const u16* W1[3];
    const void* bias[3];
    const u16* R10[3]; const u16* R11[3];   // Wql, Wkl, Wvl
    const void* rb1[3];                      // bql, bkl, bvl
    const u16* R20; const u16* R21; const void* rb2;   // Wel, bel
    const u16* R30; const u16* R31; const void* rb3;   // Wq2, bq2
    u16 *Kp, *q1b, *q2r, *krb, *vrb;
};

__global__ __launch_bounds__(256, 3) void qkv_fused_kernel(
    QKVArgs a, const int* __restrict__ flag)
{
    __shared__ __align__(16) u16 smem[16384];   // 32 KB: As+Ws; epilogue 4x8KB/wave
    u16 (*As)[64] = (u16(*)[64])smem;
    u16 (*Ws)[64] = (u16(*)[64])(smem + 8192);

    const int z = blockIdx.z;
    const int f = *flag;
    const u16* __restrict__ A = f ? a.A1[z] : a.A0[z];
    const u16* __restrict__ W = f ? a.W1[z] : a.W0[z];
    const void* biasp = a.bias[z];

    const int m0   = blockIdx.y * 128;
    const int n0   = blockIdx.x * 128;
    const int tid  = threadIdx.x;
    const int w    = tid >> 6;
    const int lane = tid & 63;
    const int l16  = lane & 15;
    const int quad = lane >> 4;
    const int wr   = (w >> 1) * 64;
    const int wc   = (w & 1) * 64;

    const int srow = lane >> 3;
    const int sgrp = (lane & 7) ^ srow;

    f32x4 acc[4][4];
#pragma unroll
    for (int rt = 0; rt < 4; ++rt)
#pragma unroll
        for (int ct = 0; ct < 4; ++ct) acc[rt][ct] = (f32x4){0.f, 0.f, 0.f, 0.f};

    for (int k0 = 0; k0 < DM_; k0 += 64) {
#pragma unroll
        for (int s = 0; s < 4; ++s) {
            int seg = w * 4 + s;
            async_ld16(&A[(size_t)(m0 + seg * 8 + srow) * DM_ + k0 + sgrp * 8],
                       &As[seg * 8][0]);
            async_ld16(&W[(size_t)(n0 + seg * 8 + srow) * DM_ + k0 + sgrp * 8],
                       &Ws[seg * 8][0]);
        }
        __syncthreads();
#pragma unroll
        for (int kk = 0; kk < 2; ++kk) {
            const int p = (kk * 4 + quad) ^ (l16 & 7);
            bf16x8 av[4], bv[4];
#pragma unroll
            for (int rt = 0; rt < 4; ++rt)
                av[rt] = *(const bf16x8*)&As[wr + rt * 16 + l16][p * 8];
#pragma unroll
            for (int ct = 0; ct < 4; ++ct)
                bv[ct] = *(const bf16x8*)&Ws[wc + ct * 16 + l16][p * 8];
#pragma unroll
            for (int rt = 0; rt < 4; ++rt)
#pragma unroll
                for (int ct = 0; ct < 4; ++ct)
                    acc[rt][ct] = __builtin_amdgcn_mfma_f32_16x16x32_bf16(
                        av[rt], bv[ct], acc[rt][ct], 0, 0, 0);
        }
        __syncthreads();   // trailing barrier: all waves done reading As/Ws
    }

    // ---- fused refinement epilogue (per-wave private LDS region) ----
    const int hcol = n0 + wc;                       // = head * 64
    u16 (*Es)[64] = (u16(*)[64])(smem + w * 4096);

    // projected tile (+bias, bf16) -> Es in A-layout swizzle; z==1 also -> Kp
#pragma unroll
    for (int ct = 0; ct < 4; ++ct) {
        int col = hcol + ct * 16 + l16;
        float bv = f ? ((const float*)biasp)[col] : bf2f(((const u16*)biasp)[col]);
#pragma unroll
        for (int rt = 0; rt < 4; ++rt)
#pragma unroll
            for (int r = 0; r < 4; ++r) {
                int ml = rt * 16 + quad * 4 + r;
                int cl = ct * 16 + l16;
                u16 bb = f2bf(acc[rt][ct][r] + bv);
                if (z == 1) a.Kp[(size_t)(m0 + wr + ml) * DM_ + col] = bb;
                Es[ml][((((cl >> 3) ^ (ml & 7)) << 3) | (cl & 7))] = bb;
            }
    }

    // A-frags of the projected tile (same-wave DS in-order; no barrier needed)
    bf16x8 af[4][2];
#pragma unroll
    for (int rt = 0; rt < 4; ++rt)
#pragma unroll
        for (int kk = 0; kk < 2; ++kk)
            af[rt][kk] = *(const bf16x8*)
                &Es[rt * 16 + l16][(((kk * 4 + quad) ^ (l16 & 7)) << 3)];

    // stage-1 weight B-frags from global (64x64, L2-hot)
    const u16* R1 = f ? a.R11[z] : a.R10[z];
    bf16x8 wb[2][4];
#pragma unroll
    for (int kk = 0; kk < 2; ++kk)
#pragma unroll
        for (int ct = 0; ct < 4; ++ct)
            wb[kk][ct] = *(const bf16x8*)
                &R1[(size_t)(ct * 16 + l16) * 64 + kk * 32 + quad * 8];

    f32x4 r1[4][4];
#pragma unroll
    for (int rt = 0; rt < 4; ++rt)
#pragma unroll
        for (int ct = 0; ct < 4; ++ct) r1[rt][ct] = (f32x4){0.f, 0.f, 0.f, 0.f};
#pragma unroll
    for (int kk = 0; kk < 2; ++kk)
#pragma unroll
        for (int rt = 0; rt < 4; ++rt)
#pragma unroll
            for (int ct = 0; ct < 4; ++ct)
                r1[rt][ct] = __builtin_amdgcn_mfma_f32_16x16x32_bf16(
                    af[rt][kk], wb[kk][ct], r1[rt][ct], 0, 0, 0);

    if (z != 0) {
        // single-stage: krb (z==1) or vrb (z==2) = relu(r1 + rb1)
        const void* rb = a.rb1[z];
        u16* out = (z == 1) ? a.krb : a.vrb;
#pragma unroll
        for (int ct = 0; ct < 4; ++ct) {
            int cl = ct * 16 + l16;
            float bv = f ? ((const float*)rb)[cl] : bf2f(((const u16*)rb)[cl]);
#pragma unroll
            for (int rt = 0; rt < 4; ++rt)
#pragma unroll
                for (int r = 0; r < 4; ++r) {
                    float v = r1[rt][ct][r] + bv;
                    v = v > 0.f ? v : 0.f;
                    out[(size_t)(m0 + wr + rt * 16 + quad * 4 + r) * DM_ + hcol + cl]
                        = f2bf(v);
                }
        }
    } else {
        // q1a = relu(r1 + bql) -> Es (round-trip for stage 2)
        {
            const void* rb = a.rb1[0];
#pragma unroll
            for (int ct = 0; ct < 4; ++ct) {
                int cl = ct * 16 + l16;
                float bv = f ? ((const float*)rb)[cl] : bf2f(((const u16*)rb)[cl]);
#pragma unroll
                for (int rt = 0; rt < 4; ++rt)
#pragma unroll
                    for (int r = 0; r < 4; ++r) {
                        float v = r1[rt][ct][r] + bv;
                        v = v > 0.f ? v : 0.f;
                        int ml = rt * 16 + quad * 4 + r;
                        Es[ml][((((cl >> 3) ^ (ml & 7)) << 3) | (cl & 7))] = f2bf(v);
                    }
            }
        }
        // q2r = relu(proj @ Wq2^T + bq2)  (reuses af while Es writes land)
        {
            const u16* R3 = f ? a.R31 : a.R30;
#pragma unroll
            for (int kk = 0; kk < 2; ++kk)
#pragma unroll
                for (int ct = 0; ct < 4; ++ct)
                    wb[kk][ct] = *(const bf16x8*)
                        &R3[(size_t)(ct * 16 + l16) * 64 + kk * 32 + quad * 8];
            f32x4 r3[4][4];
#pragma unroll
            for (int rt = 0; rt < 4; ++rt)
#pragma unroll
                for (int ct = 0; ct < 4; ++ct) r3[rt][ct] = (f32x4){0.f, 0.f, 0.f, 0.f};
#pragma unroll
            for (int kk = 0; kk < 2; ++kk)
#pragma unroll
                for (int rt = 0; rt < 4; ++rt)
#pragma unroll
                    for (int ct = 0; ct < 4; ++ct)
                        r3[rt][ct] = __builtin_amdgcn_mfma_f32_16x16x32_bf16(
                            af[rt][kk], wb[kk][ct], r3[rt][ct], 0, 0, 0);
            const void* rb = a.rb3;
#pragma unroll
            for (int ct = 0; ct < 4; ++ct) {
                int cl = ct * 16 + l16;
                float bv = f ? ((const float*)rb)[cl] : bf2f(((const u16*)rb)[cl]);
#pragma unroll
                for (int rt = 0; rt < 4; ++rt)
#pragma unroll
                    for (int r = 0; r < 4; ++r) {
                        float v = r3[rt][ct][r] + bv;
                        v = v > 0.f ? v : 0.f;
                        a.q2r[(size_t)(m0 + wr + rt * 16 + quad * 4 + r) * DM_
                              + hcol + cl] = f2bf(v);
                    }
            }
        }
        // q1b = relu(q1a @ Wel^T + bel)
        {
#pragma unroll
            for (int rt = 0; rt < 4; ++rt)
#pragma unroll
                for (int kk = 0; kk < 2; ++kk)
                    af[rt][kk] = *(const bf16x8*)
                        &Es[rt * 16 + l16][(((kk * 4 + quad) ^ (l16 & 7)) << 3)];
            const u16* R2 = f ? a.R21 : a.R20;
#pragma unroll
            for (int kk = 0; kk < 2; ++kk)
#pragma unroll
                for (int ct = 0; ct < 4; ++ct)
                    wb[kk][ct] = *(const bf16x8*)
                        &R2[(size_t)(ct * 16 + l16) * 64 + kk * 32 + quad * 8];
            f32x4 r2[4][4];
#pragma unroll
            for (int rt = 0; rt < 4; ++rt)
#pragma unroll
                for (int ct = 0; ct < 4; ++ct) r2[rt][ct] = (f32x4){0.f, 0.f, 0.f, 0.f};
#pragma unroll
            for (int kk = 0; kk < 2; ++kk)
#pragma unroll
                for (int rt = 0; rt < 4; ++rt)
#pragma unroll
                    for (int ct = 0; ct < 4; ++ct)
                        r2[rt][ct] = __builtin_amdgcn_mfma_f32_16x16x32_bf16(
                            af[rt][kk], wb[kk][ct], r2[rt][ct], 0, 0, 0);
            const void* rb = a.rb2;
#pragma unroll
            for (int ct = 0; ct < 4; ++ct) {
                int cl = ct * 16 + l16;
                float bv = f ? ((const float*)rb)[cl] : bf2f(((const u16*)rb)[cl]);
#pragma unroll
                for (int rt = 0; rt < 4; ++rt)
#pragma unroll
                    for (int r = 0; r < 4; ++r) {
                        float v = r2[rt][ct][r] + bv;
                        v = v > 0.f ? v : 0.f;
                        a.q1b[(size_t)(m0 + wr + rt * 16 + quad * 4 + r) * DM_
                              + hcol + cl] = f2bf(v);
                    }
            }
        }
    }
}

// ---------------------------------------------------------------------------
// Output-projection GEMM (m97 structure), dtype-dynamic bias/out.
// ---------------------------------------------------------------------------
__global__ __launch_bounds__(256, 3) void gemm_async_kernel(
    const u16* __restrict__ Ain, const u16* __restrict__ W0,
    const u16* __restrict__ W1, const void* __restrict__ biasp,
    void* __restrict__ Cp, const int* __restrict__ flag)
{
    __shared__ __align__(16) u16 As[128][64];
    __shared__ __align__(16) u16 Ws[128][64];

    const int f = *flag;
    const u16* __restrict__ W = f ? W1 : W0;

    const int m0   = blockIdx.y * 128;
    const int n0   = blockIdx.x * 128;
    const int tid  = threadIdx.x;
    const int w    = tid >> 6;
    const int lane = tid & 63;
    const int l16  = lane & 15;
    const int quad = lane >> 4;
    const int wr   = (w >> 1) * 64;
    const int wc   = (w & 1) * 64;

    const int srow = lane >> 3;
    const int sgrp = (lane & 7) ^ srow;

    f32x4 acc[4][4];
#pragma unroll
    for (int rt = 0; rt < 4; ++rt)
#pragma unroll
        for (int ct = 0; ct < 4; ++ct) acc[rt][ct] = (f32x4){0.f, 0.f, 0.f, 0.f};

    for (int k0 = 0; k0 < DM_; k0 += 64) {
#pragma unroll
        for (int s = 0; s < 4; ++s) {
            int seg = w * 4 + s;
            async_ld16(&Ain[(size_t)(m0 + seg * 8 + srow) * DM_ + k0 + sgrp * 8],
                       &As[seg * 8][0]);
            async_ld16(&W[(size_t)(n0 + seg * 8 + srow) * DM_ + k0 + sgrp * 8],
                       &Ws[seg * 8][0]);
        }
        __syncthreads();
#pragma unroll
        for (int kk = 0; kk < 2; ++kk) {
            const int p = (kk * 4 + quad) ^ (l16 & 7);
            bf16x8 av[4], bv[4];
#pragma unroll
            for (int rt = 0; rt < 4; ++rt)
                av[rt] = *(const bf16x8*)&As[wr + rt * 16 + l16][p * 8];
#pragma unroll
            for (int ct = 0; ct < 4; ++ct)
                bv[ct] = *(const bf16x8*)&Ws[wc + ct * 16 + l16][p * 8];
#pragma unroll
            for (int rt = 0; rt < 4; ++rt)
#pragma unroll
                for (int ct = 0; ct < 4; ++ct)
                    acc[rt][ct] = __builtin_amdgcn_mfma_f32_16x16x32_bf16(
                        av[rt], bv[ct], acc[rt][ct], 0, 0, 0);
        }
        __syncthreads();
    }

#pragma unroll
    for (int ct = 0; ct < 4; ++ct) {
        int col = n0 + wc + ct * 16 + l16;
        float bv = f ? ((const float*)biasp)[col] : bf2f(((const u16*)biasp)[col]);
#pragma unroll
        for (int rt = 0; rt < 4; ++rt)
#pragma unroll
            for (int r = 0; r < 4; ++r) {
                int row = m0 + wr + rt * 16 + quad * 4 + r;
                float v = acc[rt][ct][r] + bv;
                size_t idx = (size_t)row * DM_ + col;
                if (f) ((float*)Cp)[idx] = v;
                else   ((u16*)Cp)[idx]   = f2bf(v);
            }
    }
}

// ---------------------------------------------------------------------------
// Fused attention, R13 = R1 (best-known 70.2 us: double-buffered LDS tiles,
// async-STAGE split, 1 barrier/K-tile, XCD swizzle, setprio) + T13 defer-max:
// cheap per-quad-group tile max (in-lane fmax + 4 shfl) gates the expensive
// path; when no row's max grew by >8 we keep m_old (alpha=1), skipping the
// 32-shfl row-max tree, the 8 rescale-exps, and the 32-mul O-rescale.
// p <= e^8 is safe in bf16/f32; normalized result mathematically identical.
// [R3 lesson: do NOT drop LDS staging at 2 waves/SIMD — raw L2 latency on
// the MFMA operand path cost +32 us even spill-free.]
// ---------------------------------------------------------------------------
__global__ __launch_bounds__(256, 2) void attn_kernel(
    const u16* __restrict__ q1, const u16* __restrict__ q2,
    const u16* __restrict__ kr, const u16* __restrict__ vr,
    const u16* __restrict__ kpt, const int* __restrict__ mask,
    const int* __restrict__ tflags, u16* __restrict__ om)
{
    __shared__ __align__(16) u16 krs[2][64][72];
    __shared__ __align__(16) u16 vrs[2][64][72];
    __shared__ __align__(16) u16 kts[2][64][72];   // KpT tile: rows d, cols k
    __shared__ __align__(16) u16 pts[4][32][72];   // per-wave P~ staging

    // bijective XCD swizzle: hw XCD = bid%8; XCD x gets orig ids x*64..x*64+63
    // = (b,h) pairs 8x..8x+7 complete (8 q-tiles each).
    const int bid  = blockIdx.x;                  // 0..511 flat
    const int orig = (bid & 7) * 64 + (bid >> 3);
    const int qt = orig & 7;
    const int h  = (orig >> 3) & 15;
    const int b  = orig >> 7;

    const int q0   = qt * 128;
    const int tid  = threadIdx.x;
    const int w    = tid >> 6;
    const int lane = tid & 63;
    const int l16  = lane & 15;
    const int quad = lane >> 4;

    const size_t base  = (size_t)b * S_ * DM_ + (size_t)h * DK_;
    const size_t baseT = (size_t)(b * H_ + h) * DK_ * S_;

    // staging coords: thread handles rows sr and sr+32, 16B at col sc
    const int sr = tid >> 3;
    const int sc = (tid & 7) * 8;

    bf16x8 a1[2][2], a2[2][2];
#pragma unroll
    for (int rt = 0; rt < 2; ++rt) {
        const int qrow = q0 + w * 32 + rt * 16 + l16;
#pragma unroll
        for (int kk = 0; kk < 2; ++kk) {
            a1[rt][kk] = *(const bf16x8*)&q1[base + (size_t)qrow * DM_ + kk * 32 + quad * 8];
            a2[rt][kk] = *(const bf16x8*)&q2[base + (size_t)qrow * DM_ + kk * 32 + quad * 8];
        }
    }

    float m_run[2][4], l_run[2][4];
    f32x4 oacc[2][4];
#pragma unroll
    for (int rt = 0; rt < 2; ++rt)
#pragma unroll
        for (int r = 0; r < 4; ++r) { m_run[rt][r] = -1e30f; l_run[rt][r] = 0.f; }
#pragma unroll
    for (int rt = 0; rt < 2; ++rt)
#pragma unroll
        for (int ct = 0; ct < 4; ++ct) oacc[rt][ct] = (f32x4){0.f, 0.f, 0.f, 0.f};

    // ---- prologue: stage tile 0 into buffer 0 ----
    {
        uint4 ka = *(const uint4*)&kr[base + (size_t)(sr) * DM_ + sc];
        uint4 kb = *(const uint4*)&kr[base + (size_t)(sr + 32) * DM_ + sc];
        uint4 va = *(const uint4*)&vr[base + (size_t)(sr) * DM_ + sc];
        uint4 vb = *(const uint4*)&vr[base + (size_t)(sr + 32) * DM_ + sc];
        uint4 ta = *(const uint4*)&kpt[baseT + (size_t)sr * S_ + sc];
        uint4 tb = *(const uint4*)&kpt[baseT + (size_t)(sr + 32) * S_ + sc];
        *(uint4*)&krs[0][sr][sc]      = ka;
        *(uint4*)&krs[0][sr + 32][sc] = kb;
        *(uint4*)&vrs[0][sr][sc]      = va;
        *(uint4*)&vrs[0][sr + 32][sc] = vb;
        *(uint4*)&kts[0][sr][sc]      = ta;
        *(uint4*)&kts[0][sr + 32][sc] = tb;
    }
    __syncthreads();

    for (int kt = 0; kt < S_ / 64; ++kt) {
        const int cur = kt & 1;
        const int k0  = kt * 64;
        const bool pf = (kt + 1 < S_ / 64);

        // issue next-tile global loads first — latency hides under compute
        uint4 ka, kb, va, vb, ta, tb;
        if (pf) {
            const int kn = k0 + 64;
            ka = *(const uint4*)&kr[base + (size_t)(kn + sr) * DM_ + sc];
            kb = *(const uint4*)&kr[base + (size_t)(kn + sr + 32) * DM_ + sc];
            va = *(const uint4*)&vr[base + (size_t)(kn + sr) * DM_ + sc];
            vb = *(const uint4*)&vr[base + (size_t)(kn + sr + 32) * DM_ + sc];
            ta = *(const uint4*)&kpt[baseT + (size_t)sr * S_ + kn + sc];
            tb = *(const uint4*)&kpt[baseT + (size_t)(sr + 32) * S_ + kn + sc];
        }

        const int tf = tflags[b * 16 + kt];

        f32x4 s1[2][4], s2[2][4];
#pragma unroll
        for (int rt = 0; rt < 2; ++rt)
#pragma unroll
            for (int ct = 0; ct < 4; ++ct) {
                s1[rt][ct] = (f32x4){0.f, 0.f, 0.f, 0.f};
                s2[rt][ct] = (f32x4){0.f, 0.f, 0.f, 0.f};
            }
        __builtin_amdgcn_s_setprio(1);
#pragma unroll
        for (int kk = 0; kk < 2; ++kk) {
            bf16x8 b1[4], b2[4];
#pragma unroll
            for (int ct = 0; ct < 4; ++ct) {
                b1[ct] = *(const bf16x8*)&krs[cur][ct * 16 + l16][kk * 32 + quad * 8];
                b2[ct] = *(const bf16x8*)&vrs[cur][ct * 16 + l16][kk * 32 + quad * 8];
            }
#pragma unroll
            for (int rt = 0; rt < 2; ++rt)
#pragma unroll
                for (int ct = 0; ct < 4; ++ct) {
                    s1[rt][ct] = __builtin_amdgcn_mfma_f32_16x16x32_bf16(
                        a1[rt][kk], b1[ct], s1[rt][ct], 0, 0, 0);
                    s2[rt][ct] = __builtin_amdgcn_mfma_f32_16x16x32_bf16(
                        a2[rt][kk], b2[ct], s2[rt][ct], 0, 0, 0);
                }
        }
        __builtin_amdgcn_s_setprio(0);

        if (tf) {
#pragma unroll
            for (int rt = 0; rt < 2; ++rt)
#pragma unroll
                for (int ct = 0; ct < 4; ++ct)
#pragma unroll
                    for (int r = 0; r < 4; ++r) {
                        int qrow = q0 + w * 32 + rt * 16 + quad * 4 + r;
                        int kc   = k0 + ct * 16 + l16;
                        if (mask[((size_t)b * S_ + qrow) * S_ + kc] == 0)
                            s1[rt][ct][r] = -1e9f;
                    }
        }

        // ---- defer-max (T13): per-quad-group tile max, 4 shfl only ----
        float gmax = s1[0][0][0];
#pragma unroll
        for (int rt = 0; rt < 2; ++rt)
#pragma unroll
            for (int ct = 0; ct < 4; ++ct)
#pragma unroll
                for (int r = 0; r < 4; ++r)
                    gmax = fmaxf(gmax, s1[rt][ct][r]);
#pragma unroll
        for (int off = 1; off < 16; off <<= 1)
            gmax = fmaxf(gmax, __shfl_xor(gmax, off, 64));
        // gmax = max over this lane's 8 rows (all cols of the k-tile)
        int need = 0;
#pragma unroll
        for (int rt = 0; rt < 2; ++rt)
#pragma unroll
            for (int r = 0; r < 4; ++r)
                need |= (gmax > m_run[rt][r] + 8.f) ? 1 : 0;
        const bool full = __any(need);

        float alpha[2][4], newm[2][4];
        if (full) {
            float tmax[2][4];
#pragma unroll
            for (int rt = 0; rt < 2; ++rt)
#pragma unroll
                for (int r = 0; r < 4; ++r) tmax[rt][r] = -1e30f;
#pragma unroll
            for (int rt = 0; rt < 2; ++rt)
#pragma unroll
                for (int ct = 0; ct < 4; ++ct)
#pragma unroll
                    for (int r = 0; r < 4; ++r)
                        tmax[rt][r] = fmaxf(tmax[rt][r], s1[rt][ct][r]);
#pragma unroll
            for (int off = 1; off < 16; off <<= 1)
#pragma unroll
                for (int rt = 0; rt < 2; ++rt)
#pragma unroll
                    for (int r = 0; r < 4; ++r)
                        tmax[rt][r] = fmaxf(tmax[rt][r], __shfl_xor(tmax[rt][r], off, 64));
#pragma unroll
            for (int rt = 0; rt < 2; ++rt)
#pragma unroll
                for (int r = 0; r < 4; ++r) {
                    newm[rt][r]  = fmaxf(m_run[rt][r], tmax[rt][r]);
                    alpha[rt][r] = __expf(m_run[rt][r] - newm[rt][r]);
                    m_run[rt][r] = newm[rt][r];
                }
        } else {
#pragma unroll
            for (int rt = 0; rt < 2; ++rt)
#pragma unroll
                for (int r = 0; r < 4; ++r) {
                    newm[rt][r]  = m_run[rt][r];
                    alpha[rt][r] = 1.f;
                }
        }

        float psum[2][4] = {};
#pragma unroll
        for (int rt = 0; rt < 2; ++rt)
#pragma unroll
            for (int ct = 0; ct < 4; ++ct)
#pragma unroll
                for (int r = 0; r < 4; ++r) {
                    float p = __expf(s1[rt][ct][r] - newm[rt][r]);
                    psum[rt][r] += p;
                    pts[w][rt * 16 + quad * 4 + r][ct * 16 + l16] =
                        f2bf_fast(p * s2[rt][ct][r]);
                }
#pragma unroll
        for (int off = 1; off < 16; off <<= 1)
#pragma unroll
            for (int rt = 0; rt < 2; ++rt)
#pragma unroll
                for (int r = 0; r < 4; ++r)
                    psum[rt][r] += __shfl_xor(psum[rt][r], off, 64);
#pragma unroll
        for (int rt = 0; rt < 2; ++rt)
#pragma unroll
            for (int r = 0; r < 4; ++r)
                l_run[rt][r] = l_run[rt][r] * alpha[rt][r] + psum[rt][r];
        if (full) {
#pragma unroll
            for (int rt = 0; rt < 2; ++rt)
#pragma unroll
                for (int ct = 0; ct < 4; ++ct)
#pragma unroll
                    for (int r = 0; r < 4; ++r) oacc[rt][ct][r] *= alpha[rt][r];
        }

        {
            __builtin_amdgcn_s_setprio(1);
            bf16x8 bb[2][4];
#pragma unroll
            for (int kk = 0; kk < 2; ++kk)
#pragma unroll
                for (int ct = 0; ct < 4; ++ct)
                    bb[kk][ct] = *(const bf16x8*)&kts[cur][ct * 16 + l16][kk * 32 + quad * 8];
#pragma unroll
            for (int rt = 0; rt < 2; ++rt)
#pragma unroll
                for (int kk = 0; kk < 2; ++kk) {
                    bf16x8 a = *(const bf16x8*)&pts[w][rt * 16 + l16][kk * 32 + quad * 8];
#pragma unroll
                    for (int ct = 0; ct < 4; ++ct)
                        oacc[rt][ct] = __builtin_amdgcn_mfma_f32_16x16x32_bf16(
                            a, bb[kk][ct], oacc[rt][ct], 0, 0, 0);
                }
            __builtin_amdgcn_s_setprio(0);
        }

        // land next tile into the other buffer; single barrier per K-tile
        if (pf) {
            const int nxt = cur ^ 1;
            *(uint4*)&krs[nxt][sr][sc]      = ka;
            *(uint4*)&krs[nxt][sr + 32][sc] = kb;
            *(uint4*)&vrs[nxt][sr][sc]      = va;
            *(uint4*)&vrs[nxt][sr + 32][sc] = vb;
            *(uint4*)&kts[nxt][sr][sc]      = ta;
            *(uint4*)&kts[nxt][sr + 32][sc] = tb;
            __syncthreads();
        }
    }

#pragma unroll
    for (int rt = 0; rt < 2; ++rt)
#pragma unroll
        for (int ct = 0; ct < 4; ++ct)
#pragma unroll
            for (int r = 0; r < 4; ++r) {
                int row = q0 + w * 32 + rt * 16 + quad * 4 + r;
                int col = ct * 16 + l16;
                float v = oacc[rt][ct][r] / l_run[rt][r];
                om[base + (size_t)row * DM_ + col] = f2bf_fast(v);
            }
}

// ---------------------------------------------------------------------------
extern "C" void kernel_launch(void* const* d_in, const int* in_sizes, int n_in,
                              void* d_out, int out_size, void* d_ws, size_t ws_size,
                              hipStream_t stream)
{
    const void* query = d_in[0];
    const void* key   = d_in[1];
    const void* value = d_in[2];
    const int*  mask  = (const int*)d_in[3];
    const void* Wq  = d_in[4];  const void* bq  = d_in[5];
    const void* Wk  = d_in[6];  const void* bk  = d_in[7];
    const void* Wv  = d_in[8];  const void* bv  = d_in[9];
    const void* Wo  = d_in[10]; const void* bo  = d_in[11];
    const void* Wkl = d_in[12]; const void* bkl = d_in[13];
    const void* Wql = d_in[14]; const void* bql = d_in[15];
    const void* Wq2 = d_in[16]; const void* bq2 = d_in[17];
    const void* Wvl = d_in[18]; const void* bvl = d_in[19];
    const void* Wel = d_in[20]; const void* bel = d_in[21];

    int* flag   = (int*)d_ws;
    int* tflags = (int*)d_ws + 4;                     // 64 ints
    u16* ws     = (u16*)((char*)d_ws + 512);
    const size_t BUF = (size_t)(B_ * S_) * DM_;       // 4M elems = 8 MB bf16
    u16* Kp  = ws + 0 * BUF;
    u16* krb = ws + 1 * BUF;
    u16* q1b = ws + 2 * BUF;
    u16* q2r = ws + 3 * BUF;
    u16* vrb = ws + 4 * BUF;
    u16* Om  = ws + 5 * BUF;
    u16* KpT = ws + 6 * BUF;
    u16* Qc  = ws + 7 * BUF;
    u16* Kc  = ws + 8 * BUF;
    u16* Vc  = ws + 9 * BUF;
    u16* Wbig = ws + 10 * BUF;
    u16* Wqc = Wbig + 0 * (size_t)(DM_ * DM_);
    u16* Wkc = Wbig + 1 * (size_t)(DM_ * DM_);
    u16* Wvc = Wbig + 2 * (size_t)(DM_ * DM_);
    u16* Woc = Wbig + 3 * (size_t)(DM_ * DM_);
    u16* Wsm = Wbig + 4 * (size_t)(DM_ * DM_);
    u16* Wklc = Wsm + 0 * (DK_ * DK_);
    u16* Wqlc = Wsm + 1 * (DK_ * DK_);
    u16* Welc = Wsm + 2 * (DK_ * DK_);
    u16* Wq2c = Wsm + 3 * (DK_ * DK_);
    u16* Wvlc = Wsm + 4 * (DK_ * DK_);

    const int M = B_ * S_;
    dim3 blk(256);

    detect_kernel<<<1, 64, 0, stream>>>((const u16*)query, flag);

    // fused mask-flag scan + dtype conversion
    hipMemsetAsync(tflags, 0, 64 * sizeof(int), stream);
    CvtArgs ca;
    const unsigned VIN = (unsigned)(BUF / 8);
    const unsigned VWB = (unsigned)(DM_ * DM_ / 8);
    const unsigned VWS = (unsigned)(DK_ * DK_ / 8);
    const void* srcs[NSEG] = {query, key, value, Wq, Wk, Wv, Wo, Wkl, Wql, Wel, Wq2, Wvl};
    void* dsts[NSEG] = {Qc, Kc, Vc, Wqc, Wkc, Wvc, Woc, Wklc, Wqlc, Welc, Wq2c, Wvlc};
    unsigned vcn[NSEG] = {VIN, VIN, VIN, VWB, VWB, VWB, VWB, VWS, VWS, VWS, VWS, VWS};
    unsigned off = 0;
    for (int i = 0; i < NSEG; ++i) { ca.src[i] = srcs[i]; ca.dst[i] = dsts[i]; ca.off[i] = off; off += vcn[i]; }
    ca.off[NSEG] = off;
    prep_kernel<<<dim3(512 + (off + 255) / 256), blk, 0, stream>>>(ca, off, flag, mask, tflags);

    // Q/K/V projections + fused per-head refinements (768 blocks)
    QKVArgs qa = {};
    qa.A0[0] = (const u16*)query; qa.A1[0] = Qc;
    qa.A0[1] = (const u16*)key;   qa.A1[1] = Kc;
    qa.A0[2] = (const u16*)value; qa.A1[2] = Vc;
    qa.W0[0] = (const u16*)Wq; qa.W1[0] = Wqc;
    qa.W0[1] = (const u16*)Wk; qa.W1[1] = Wkc;
    qa.W0[2] = (const u16*)Wv; qa.W1[2] = Wvc;
    qa.bias[0] = bq; qa.bias[1] = bk; qa.bias[2] = bv;
    qa.R10[0] = (const u16*)Wql; qa.R11[0] = Wqlc; qa.rb1[0] = bql;
    qa.R10[1] = (const u16*)Wkl; qa.R11[1] = Wklc; qa.rb1[1] = bkl;
    qa.R10[2] = (const u16*)Wvl; qa.R11[2] = Wvlc; qa.rb1[2] = bvl;
    qa.R20 = (const u16*)Wel; qa.R21 = Welc; qa.rb2 = bel;
    qa.R30 = (const u16*)Wq2; qa.R31 = Wq2c; qa.rb3 = bq2;
    qa.Kp = Kp; qa.q1b = q1b; qa.q2r = q2r; qa.krb = krb; qa.vrb = vrb;
    dim3 gBig(DM_ / 128, M / 128, 3);
    qkv_fused_kernel<<<gBig, blk, 0, stream>>>(qa, flag);

    // Kp -> per-head transposed copy
    dim3 gT(S_ / 64, H_, B_);
    transpose_kernel<<<gT, blk, 0, stream>>>(Kp, KpT);

    // fused attention -> merged (B,S,DM) layout (128 q-rows per block,
    // flat grid + XCD swizzle: one (b,h) pair's 8 q-blocks per XCD)
    attn_kernel<<<dim3(512), blk, 0, stream>>>(q1b, q2r, krb, vrb, KpT, mask, tflags, Om);

    // output projection -> d_out
    dim3 gO(DM_ / 128, M / 128);
    gemm_async_kernel<<<gO, blk, 0, stream>>>(Om, (const u16*)Wo, Woc, bo, d_out, flag);
}

// Round 5
// 309.853 us; speedup vs baseline: 1.2542x; 1.0001x over previous
//
#include <hip/hip_runtime.h>
#include <hip/hip_bf16.h>

#define B_  4
#define S_  1024
#define DM_ 1024
#define H_  16
#define DK_ 64

typedef unsigned short u16;
typedef __attribute__((ext_vector_type(8))) short bf16x8;
typedef __attribute__((ext_vector_type(4))) float f32x4;

__device__ __forceinline__ float bf2f(u16 u) {
    union { unsigned int i; float f; } c;
    c.i = ((unsigned int)u) << 16;
    return c.f;
}
__device__ __forceinline__ u16 f2bf(float f) {
    union { float f; unsigned int i; } c;
    c.f = f;
    unsigned int x = c.i;
    unsigned int lsb = (x >> 16) & 1u;
    x += 0x7fffu + lsb;          // round-to-nearest-even
    return (u16)(x >> 16);
}
__device__ __forceinline__ u16 f2bf_fast(float f) {
    __hip_bfloat16 h = __float2bfloat16(f);   // HW cvt, RNE
    return *reinterpret_cast<u16*>(&h);
}

// async global->LDS, 16B per lane; LDS dest = wave-uniform base + lane*16
__device__ __forceinline__ void async_ld16(const u16* g, u16* l) {
    __builtin_amdgcn_global_load_lds(
        (const __attribute__((address_space(1))) unsigned int*)(const void*)g,
        (__attribute__((address_space(3))) unsigned int*)(void*)l, 16, 0, 0);
}

// ---------------------------------------------------------------------------
// Runtime dtype detection (one wave). flag=1: inputs are fp32.
// ---------------------------------------------------------------------------
__global__ void detect_kernel(const u16* __restrict__ q, int* __restrict__ flag) {
    int lane = threadIdx.x & 63;
    int cnt = 0;
#pragma unroll
    for (int i = 0; i < 4; ++i) {
        u16 u = q[2 * (lane * 4 + i)];
        int e = (u >> 7) & 0xFF;
        cnt += (e >= 100 && e <= 140) ? 1 : 0;
    }
#pragma unroll
    for (int off = 1; off < 64; off <<= 1) cnt += __shfl_xor(cnt, off, 64);
    if (lane == 0) *flag = (cnt < 128) ? 1 : 0;
}

// ---------------------------------------------------------------------------
// Fused prep: blocks [0,512) scan mask -> per-(b,k64-tile) any-zero flags
// (tflags pre-zeroed via hipMemsetAsync; dirty -> atomicOr 1). Blocks >= 512
// do packed fp32->bf16 conversion (early-out when inputs already bf16).
// ---------------------------------------------------------------------------
#define NSEG 12
struct CvtArgs {
    const void* src[NSEG];
    void*       dst[NSEG];
    unsigned    off[NSEG + 1];
};

__global__ __launch_bounds__(256) void prep_kernel(
    CvtArgs a, unsigned total, const int* __restrict__ flag,
    const int* __restrict__ mask, int* __restrict__ tflags)
{
    const int tid = threadIdx.x;
    if (blockIdx.x < 512) {
        const int bx = blockIdx.x;
        const int kt = bx & 15, b = (bx >> 4) & 3, z = bx >> 6;
        int ok = 1;
#pragma unroll
        for (int i = tid; i < 128 * 16; i += 256) {
            int row = z * 128 + (i >> 4), seg = i & 15;
            int4 m = *(const int4*)&mask[((size_t)b * S_ + row) * S_ + kt * 64 + seg * 4];
            ok &= (m.x != 0) & (m.y != 0) & (m.z != 0) & (m.w != 0);
        }
        if (!ok) atomicOr(&tflags[b * 16 + kt], 1);
        return;
    }
    if (!*flag) return;   // bf16 inputs: GEMMs read originals directly
    unsigned v = (blockIdx.x - 512) * 256 + tid;
    if (v >= total) return;
    int s = 0;
    while (s < NSEG - 1 && v >= a.off[s + 1]) ++s;
    unsigned local = v - a.off[s];
    u16* dp = (u16*)a.dst[s] + (size_t)local * 8;
    const float* sp = (const float*)a.src[s] + (size_t)local * 8;
    float4 x = *(const float4*)sp, y = *(const float4*)(sp + 4);
    u16 t[8] = {f2bf(x.x), f2bf(x.y), f2bf(x.z), f2bf(x.w),
                f2bf(y.x), f2bf(y.y), f2bf(y.z), f2bf(y.w)};
    *(uint4*)dp = *(uint4*)t;
}

// ---------------------------------------------------------------------------
// Per-head transpose: Kp (b,s,h,d) -> KpT[((b*H+h)*DK + d)*S + s].
// ---------------------------------------------------------------------------
__global__ __launch_bounds__(256) void transpose_kernel(
    const u16* __restrict__ kp, u16* __restrict__ kpt)
{
    __shared__ u16 T[64][65];
    const int s0 = blockIdx.x * 64, h = blockIdx.y, b = blockIdx.z;
    const int tid = threadIdx.x;
    const size_t base = (size_t)b * S_ * DM_ + (size_t)h * DK_;
    for (int c = tid; c < 512; c += 256) {
        int row = c >> 3, cc = (c & 7) * 8;
        union { uint4 v; u16 u[8]; } x;
        x.v = *(const uint4*)&kp[base + (size_t)(s0 + row) * DM_ + cc];
#pragma unroll
        for (int j = 0; j < 8; ++j) T[row][cc + j] = x.u[j];
    }
    __syncthreads();
    const size_t baseT = (size_t)(b * H_ + h) * DK_ * S_;
    for (int c = tid; c < 512; c += 256) {
        int d = c >> 3, ss = (c & 7) * 8;
        u16 t[8];
#pragma unroll
        for (int j = 0; j < 8; ++j) t[j] = T[ss + j][d];
        *(uint4*)&kpt[baseT + (size_t)d * S_ + s0 + ss] = *(uint4*)t;
    }
}

// ---------------------------------------------------------------------------
// QKV projection + fused per-head refinements. 128x128 tile, BK=64, async
// global->LDS staging, XOR column-group swizzle (m97 structure). After the
// K-loop each wave's 64x64 quadrant is ONE head's complete column block for
// 64 rows, so the row-local 64x64 refinements run entirely in the epilogue:
// C-layout acc -> per-wave LDS region (A-layout swizzled) -> MFMA with
// weight B-frags read straight from global (L2-hot, shared across heads).
// z=0 (Q): emits q1b (Wql->Wel chain) + q2r. z=1 (K): Kp + krb. z=2: vrb.
// ---------------------------------------------------------------------------
struct QKVArgs {
    const u16* A0[3]; const u16* A1[3];
    const u16* W0[3]; const u16* W1[3];
    const void* bias[3];
    const u16* R10[3]; const u16* R11[3];   // Wql, Wkl, Wvl
    const void* rb1[3];                      // bql, bkl, bvl
    const u16* R20; const u16* R21; const void* rb2;   // Wel, bel
    const u16* R30; const u16* R31; const void* rb3;   // Wq2, bq2
    u16 *Kp, *q1b, *q2r, *krb, *vrb;
};

__global__ __launch_bounds__(256, 3) void qkv_fused_kernel(
    QKVArgs a, const int* __restrict__ flag)
{
    __shared__ __align__(16) u16 smem[16384];   // 32 KB: As+Ws; epilogue 4x8KB/wave
    u16 (*As)[64] = (u16(*)[64])smem;
    u16 (*Ws)[64] = (u16(*)[64])(smem + 8192);

    const int z = blockIdx.z;
    const int f = *flag;
    const u16* __restrict__ A = f ? a.A1[z] : a.A0[z];
    const u16* __restrict__ W = f ? a.W1[z] : a.W0[z];
    const void* biasp = a.bias[z];

    const int m0   = blockIdx.y * 128;
    const int n0   = blockIdx.x * 128;
    const int tid  = threadIdx.x;
    const int w    = tid >> 6;
    const int lane = tid & 63;
    const int l16  = lane & 15;
    const int quad = lane >> 4;
    const int wr   = (w >> 1) * 64;
    const int wc   = (w & 1) * 64;

    const int srow = lane >> 3;
    const int sgrp = (lane & 7) ^ srow;

    f32x4 acc[4][4];
#pragma unroll
    for (int rt = 0; rt < 4; ++rt)
#pragma unroll
        for (int ct = 0; ct < 4; ++ct) acc[rt][ct] = (f32x4){0.f, 0.f, 0.f, 0.f};

    for (int k0 = 0; k0 < DM_; k0 += 64) {
#pragma unroll
        for (int s = 0; s < 4; ++s) {
            int seg = w * 4 + s;
            async_ld16(&A[(size_t)(m0 + seg * 8 + srow) * DM_ + k0 + sgrp * 8],
                       &As[seg * 8][0]);
            async_ld16(&W[(size_t)(n0 + seg * 8 + srow) * DM_ + k0 + sgrp * 8],
                       &Ws[seg * 8][0]);
        }
        __syncthreads();
#pragma unroll
        for (int kk = 0; kk < 2; ++kk) {
            const int p = (kk * 4 + quad) ^ (l16 & 7);
            bf16x8 av[4], bv[4];
#pragma unroll
            for (int rt = 0; rt < 4; ++rt)
                av[rt] = *(const bf16x8*)&As[wr + rt * 16 + l16][p * 8];
#pragma unroll
            for (int ct = 0; ct < 4; ++ct)
                bv[ct] = *(const bf16x8*)&Ws[wc + ct * 16 + l16][p * 8];
#pragma unroll
            for (int rt = 0; rt < 4; ++rt)
#pragma unroll
                for (int ct = 0; ct < 4; ++ct)
                    acc[rt][ct] = __builtin_amdgcn_mfma_f32_16x16x32_bf16(
                        av[rt], bv[ct], acc[rt][ct], 0, 0, 0);
        }
        __syncthreads();   // trailing barrier: all waves done reading As/Ws
    }

    // ---- fused refinement epilogue (per-wave private LDS region) ----
    const int hcol = n0 + wc;                       // = head * 64
    u16 (*Es)[64] = (u16(*)[64])(smem + w * 4096);

    // projected tile (+bias, bf16) -> Es in A-layout swizzle; z==1 also -> Kp
#pragma unroll
    for (int ct = 0; ct < 4; ++ct) {
        int col = hcol + ct * 16 + l16;
        float bv = f ? ((const float*)biasp)[col] : bf2f(((const u16*)biasp)[col]);
#pragma unroll
        for (int rt = 0; rt < 4; ++rt)
#pragma unroll
            for (int r = 0; r < 4; ++r) {
                int ml = rt * 16 + quad * 4 + r;
                int cl = ct * 16 + l16;
                u16 bb = f2bf(acc[rt][ct][r] + bv);
                if (z == 1) a.Kp[(size_t)(m0 + wr + ml) * DM_ + col] = bb;
                Es[ml][((((cl >> 3) ^ (ml & 7)) << 3) | (cl & 7))] = bb;
            }
    }

    // A-frags of the projected tile (same-wave DS in-order; no barrier needed)
    bf16x8 af[4][2];
#pragma unroll
    for (int rt = 0; rt < 4; ++rt)
#pragma unroll
        for (int kk = 0; kk < 2; ++kk)
            af[rt][kk] = *(const bf16x8*)
                &Es[rt * 16 + l16][(((kk * 4 + quad) ^ (l16 & 7)) << 3)];

    // stage-1 weight B-frags from global (64x64, L2-hot)
    const u16* R1 = f ? a.R11[z] : a.R10[z];
    bf16x8 wb[2][4];
#pragma unroll
    for (int kk = 0; kk < 2; ++kk)
#pragma unroll
        for (int ct = 0; ct < 4; ++ct)
            wb[kk][ct] = *(const bf16x8*)
                &R1[(size_t)(ct * 16 + l16) * 64 + kk * 32 + quad * 8];

    f32x4 r1[4][4];
#pragma unroll
    for (int rt = 0; rt < 4; ++rt)
#pragma unroll
        for (int ct = 0; ct < 4; ++ct) r1[rt][ct] = (f32x4){0.f, 0.f, 0.f, 0.f};
#pragma unroll
    for (int kk = 0; kk < 2; ++kk)
#pragma unroll
        for (int rt = 0; rt < 4; ++rt)
#pragma unroll
            for (int ct = 0; ct < 4; ++ct)
                r1[rt][ct] = __builtin_amdgcn_mfma_f32_16x16x32_bf16(
                    af[rt][kk], wb[kk][ct], r1[rt][ct], 0, 0, 0);

    if (z != 0) {
        // single-stage: krb (z==1) or vrb (z==2) = relu(r1 + rb1)
        const void* rb = a.rb1[z];
        u16* out = (z == 1) ? a.krb : a.vrb;
#pragma unroll
        for (int ct = 0; ct < 4; ++ct) {
            int cl = ct * 16 + l16;
            float bv = f ? ((const float*)rb)[cl] : bf2f(((const u16*)rb)[cl]);
#pragma unroll
            for (int rt = 0; rt < 4; ++rt)
#pragma unroll
                for (int r = 0; r < 4; ++r) {
                    float v = r1[rt][ct][r] + bv;
                    v = v > 0.f ? v : 0.f;
                    out[(size_t)(m0 + wr + rt * 16 + quad * 4 + r) * DM_ + hcol + cl]
                        = f2bf(v);
                }
        }
    } else {
        // q1a = relu(r1 + bql) -> Es (round-trip for stage 2)
        {
            const void* rb = a.rb1[0];
#pragma unroll
            for (int ct = 0; ct < 4; ++ct) {
                int cl = ct * 16 + l16;
                float bv = f ? ((const float*)rb)[cl] : bf2f(((const u16*)rb)[cl]);
#pragma unroll
                for (int rt = 0; rt < 4; ++rt)
#pragma unroll
                    for (int r = 0; r < 4; ++r) {
                        float v = r1[rt][ct][r] + bv;
                        v = v > 0.f ? v : 0.f;
                        int ml = rt * 16 + quad * 4 + r;
                        Es[ml][((((cl >> 3) ^ (ml & 7)) << 3) | (cl & 7))] = f2bf(v);
                    }
            }
        }
        // q2r = relu(proj @ Wq2^T + bq2)  (reuses af while Es writes land)
        {
            const u16* R3 = f ? a.R31 : a.R30;
#pragma unroll
            for (int kk = 0; kk < 2; ++kk)
#pragma unroll
                for (int ct = 0; ct < 4; ++ct)
                    wb[kk][ct] = *(const bf16x8*)
                        &R3[(size_t)(ct * 16 + l16) * 64 + kk * 32 + quad * 8];
            f32x4 r3[4][4];
#pragma unroll
            for (int rt = 0; rt < 4; ++rt)
#pragma unroll
                for (int ct = 0; ct < 4; ++ct) r3[rt][ct] = (f32x4){0.f, 0.f, 0.f, 0.f};
#pragma unroll
            for (int kk = 0; kk < 2; ++kk)
#pragma unroll
                for (int rt = 0; rt < 4; ++rt)
#pragma unroll
                    for (int ct = 0; ct < 4; ++ct)
                        r3[rt][ct] = __builtin_amdgcn_mfma_f32_16x16x32_bf16(
                            af[rt][kk], wb[kk][ct], r3[rt][ct], 0, 0, 0);
            const void* rb = a.rb3;
#pragma unroll
            for (int ct = 0; ct < 4; ++ct) {
                int cl = ct * 16 + l16;
                float bv = f ? ((const float*)rb)[cl] : bf2f(((const u16*)rb)[cl]);
#pragma unroll
                for (int rt = 0; rt < 4; ++rt)
#pragma unroll
                    for (int r = 0; r < 4; ++r) {
                        float v = r3[rt][ct][r] + bv;
                        v = v > 0.f ? v : 0.f;
                        a.q2r[(size_t)(m0 + wr + rt * 16 + quad * 4 + r) * DM_
                              + hcol + cl] = f2bf(v);
                    }
            }
        }
        // q1b = relu(q1a @ Wel^T + bel)
        {
#pragma unroll
            for (int rt = 0; rt < 4; ++rt)
#pragma unroll
                for (int kk = 0; kk < 2; ++kk)
                    af[rt][kk] = *(const bf16x8*)
                        &Es[rt * 16 + l16][(((kk * 4 + quad) ^ (l16 & 7)) << 3)];
            const u16* R2 = f ? a.R21 : a.R20;
#pragma unroll
            for (int kk = 0; kk < 2; ++kk)
#pragma unroll
                for (int ct = 0; ct < 4; ++ct)
                    wb[kk][ct] = *(const bf16x8*)
                        &R2[(size_t)(ct * 16 + l16) * 64 + kk * 32 + quad * 8];
            f32x4 r2[4][4];
#pragma unroll
            for (int rt = 0; rt < 4; ++rt)
#pragma unroll
                for (int ct = 0; ct < 4; ++ct) r2[rt][ct] = (f32x4){0.f, 0.f, 0.f, 0.f};
#pragma unroll
            for (int kk = 0; kk < 2; ++kk)
#pragma unroll
                for (int rt = 0; rt < 4; ++rt)
#pragma unroll
                    for (int ct = 0; ct < 4; ++ct)
                        r2[rt][ct] = __builtin_amdgcn_mfma_f32_16x16x32_bf16(
                            af[rt][kk], wb[kk][ct], r2[rt][ct], 0, 0, 0);
            const void* rb = a.rb2;
#pragma unroll
            for (int ct = 0; ct < 4; ++ct) {
                int cl = ct * 16 + l16;
                float bv = f ? ((const float*)rb)[cl] : bf2f(((const u16*)rb)[cl]);
#pragma unroll
                for (int rt = 0; rt < 4; ++rt)
#pragma unroll
                    for (int r = 0; r < 4; ++r) {
                        float v = r2[rt][ct][r] + bv;
                        v = v > 0.f ? v : 0.f;
                        a.q1b[(size_t)(m0 + wr + rt * 16 + quad * 4 + r) * DM_
                              + hcol + cl] = f2bf(v);
                    }
            }
        }
    }
}

// ---------------------------------------------------------------------------
// Output-projection GEMM (m97 structure), dtype-dynamic bias/out.
// ---------------------------------------------------------------------------
__global__ __launch_bounds__(256, 3) void gemm_async_kernel(
    const u16* __restrict__ Ain, const u16* __restrict__ W0,
    const u16* __restrict__ W1, const void* __restrict__ biasp,
    void* __restrict__ Cp, const int* __restrict__ flag)
{
    __shared__ __align__(16) u16 As[128][64];
    __shared__ __align__(16) u16 Ws[128][64];

    const int f = *flag;
    const u16* __restrict__ W = f ? W1 : W0;

    const int m0   = blockIdx.y * 128;
    const int n0   = blockIdx.x * 128;
    const int tid  = threadIdx.x;
    const int w    = tid >> 6;
    const int lane = tid & 63;
    const int l16  = lane & 15;
    const int quad = lane >> 4;
    const int wr   = (w >> 1) * 64;
    const int wc   = (w & 1) * 64;

    const int srow = lane >> 3;
    const int sgrp = (lane & 7) ^ srow;

    f32x4 acc[4][4];
#pragma unroll
    for (int rt = 0; rt < 4; ++rt)
#pragma unroll
        for (int ct = 0; ct < 4; ++ct) acc[rt][ct] = (f32x4){0.f, 0.f, 0.f, 0.f};

    for (int k0 = 0; k0 < DM_; k0 += 64) {
#pragma unroll
        for (int s = 0; s < 4; ++s) {
            int seg = w * 4 + s;
            async_ld16(&Ain[(size_t)(m0 + seg * 8 + srow) * DM_ + k0 + sgrp * 8],
                       &As[seg * 8][0]);
            async_ld16(&W[(size_t)(n0 + seg * 8 + srow) * DM_ + k0 + sgrp * 8],
                       &Ws[seg * 8][0]);
        }
        __syncthreads();
#pragma unroll
        for (int kk = 0; kk < 2; ++kk) {
            const int p = (kk * 4 + quad) ^ (l16 & 7);
            bf16x8 av[4], bv[4];
#pragma unroll
            for (int rt = 0; rt < 4; ++rt)
                av[rt] = *(const bf16x8*)&As[wr + rt * 16 + l16][p * 8];
#pragma unroll
            for (int ct = 0; ct < 4; ++ct)
                bv[ct] = *(const bf16x8*)&Ws[wc + ct * 16 + l16][p * 8];
#pragma unroll
            for (int rt = 0; rt < 4; ++rt)
#pragma unroll
                for (int ct = 0; ct < 4; ++ct)
                    acc[rt][ct] = __builtin_amdgcn_mfma_f32_16x16x32_bf16(
                        av[rt], bv[ct], acc[rt][ct], 0, 0, 0);
        }
        __syncthreads();
    }

#pragma unroll
    for (int ct = 0; ct < 4; ++ct) {
        int col = n0 + wc + ct * 16 + l16;
        float bv = f ? ((const float*)biasp)[col] : bf2f(((const u16*)biasp)[col]);
#pragma unroll
        for (int rt = 0; rt < 4; ++rt)
#pragma unroll
            for (int r = 0; r < 4; ++r) {
                int row = m0 + wr + rt * 16 + quad * 4 + r;
                float v = acc[rt][ct][r] + bv;
                size_t idx = (size_t)row * DM_ + col;
                if (f) ((float*)Cp)[idx] = v;
                else   ((u16*)Cp)[idx]   = f2bf(v);
            }
    }
}

// ---------------------------------------------------------------------------
// Fused attention, R14: R1 structure (best known, 70.2 us) with the K/V/KpT
// staging converted from VGPR round-trip (12 inst/thread/tile + 24 live regs)
// to global_load_lds DMA (6 issues/wave/tile, fire-and-forget). LDS tiles are
// unpadded [2][64][64]; bank conflicts avoided with qkv's proven both-sides
// XOR pattern: pre-swizzled GLOBAL source column-group (sgrp = (lane&7)^srow)
// + XOR'd read group ((kk*4+quad)^(l16&7)), LDS linear (rule #21 correct
// form). Defer-max (R4) reverted: gate cost ~= savings (+4.5 us). Softmax =
// R1 exact. XCD swizzle (T1) + setprio (T5) kept. 1 barrier per K-tile.
// ---------------------------------------------------------------------------
__global__ __launch_bounds__(256, 2) void attn_kernel(
    const u16* __restrict__ q1, const u16* __restrict__ q2,
    const u16* __restrict__ kr, const u16* __restrict__ vr,
    const u16* __restrict__ kpt, const int* __restrict__ mask,
    const int* __restrict__ tflags, u16* __restrict__ om)
{
    __shared__ __align__(16) u16 krs[2][64][64];
    __shared__ __align__(16) u16 vrs[2][64][64];
    __shared__ __align__(16) u16 kts[2][64][64];   // KpT tile: rows d, cols k
    __shared__ __align__(16) u16 pts[4][32][72];   // per-wave P~ staging

    // bijective XCD swizzle: hw XCD = bid%8; XCD x gets orig ids x*64..x*64+63
    // = (b,h) pairs 8x..8x+7 complete (8 q-tiles each).
    const int bid  = blockIdx.x;                  // 0..511 flat
    const int orig = (bid & 7) * 64 + (bid >> 3);
    const int qt = orig & 7;
    const int h  = (orig >> 3) & 15;
    const int b  = orig >> 7;

    const int q0   = qt * 128;
    const int tid  = threadIdx.x;
    const int w    = tid >> 6;
    const int lane = tid & 63;
    const int l16  = lane & 15;
    const int quad = lane >> 4;

    const size_t base  = (size_t)b * S_ * DM_ + (size_t)h * DK_;
    const size_t baseT = (size_t)(b * H_ + h) * DK_ * S_;

    // staging lane coords (qkv pattern): row-in-segment + XOR'd col group
    const int srow = lane >> 3;                  // 0..7
    const int sgrp = (lane & 7) ^ srow;          // swizzled source col group

    // issue 6 global_load_lds per wave covering 24 segments of 8 rows:
    // flat seg s = w*6+i; tile t = s/8 (0:krs 1:vrs 2:kts); r8 = (s%8)*8.
#define STAGE_TILES(buf, kn)                                                   \
    {                                                                          \
        _Pragma("unroll")                                                      \
        for (int i = 0; i < 6; ++i) {                                          \
            int s_ = w * 6 + i;                                                \
            int t_ = s_ >> 3;                                                  \
            int r8 = (s_ & 7) * 8;                                             \
            if (t_ == 0)                                                       \
                async_ld16(&kr[base + (size_t)((kn) + r8 + srow) * DM_ +       \
                               sgrp * 8], &krs[buf][r8][0]);                   \
            else if (t_ == 1)                                                  \
                async_ld16(&vr[base + (size_t)((kn) + r8 + srow) * DM_ +       \
                               sgrp * 8], &vrs[buf][r8][0]);                   \
            else                                                               \
                async_ld16(&kpt[baseT + (size_t)(r8 + srow) * S_ + (kn) +      \
                                sgrp * 8], &kts[buf][r8][0]);                  \
        }                                                                      \
    }

    bf16x8 a1[2][2], a2[2][2];
#pragma unroll
    for (int rt = 0; rt < 2; ++rt) {
        const int qrow = q0 + w * 32 + rt * 16 + l16;
#pragma unroll
        for (int kk = 0; kk < 2; ++kk) {
            a1[rt][kk] = *(const bf16x8*)&q1[base + (size_t)qrow * DM_ + kk * 32 + quad * 8];
            a2[rt][kk] = *(const bf16x8*)&q2[base + (size_t)qrow * DM_ + kk * 32 + quad * 8];
        }
    }

    float m_run[2][4], l_run[2][4];
    f32x4 oacc[2][4];
#pragma unroll
    for (int rt = 0; rt < 2; ++rt)
#pragma unroll
        for (int r = 0; r < 4; ++r) { m_run[rt][r] = -1e30f; l_run[rt][r] = 0.f; }
#pragma unroll
    for (int rt = 0; rt < 2; ++rt)
#pragma unroll
        for (int ct = 0; ct < 4; ++ct) oacc[rt][ct] = (f32x4){0.f, 0.f, 0.f, 0.f};

    // ---- prologue: stage tile 0 into buffer 0 (barrier drains vmcnt) ----
    STAGE_TILES(0, 0)
    __syncthreads();

    for (int kt = 0; kt < S_ / 64; ++kt) {
        const int cur = kt & 1;
        const int k0  = kt * 64;
        const bool pf = (kt + 1 < S_ / 64);

        // issue next-tile DMA first — lands during compute, drained by barrier
        if (pf) STAGE_TILES(cur ^ 1, k0 + 64)

        const int tf = tflags[b * 16 + kt];

        f32x4 s1[2][4], s2[2][4];
#pragma unroll
        for (int rt = 0; rt < 2; ++rt)
#pragma unroll
            for (int ct = 0; ct < 4; ++ct) {
                s1[rt][ct] = (f32x4){0.f, 0.f, 0.f, 0.f};
                s2[rt][ct] = (f32x4){0.f, 0.f, 0.f, 0.f};
            }
        __builtin_amdgcn_s_setprio(1);
#pragma unroll
        for (int kk = 0; kk < 2; ++kk) {
            const int p = ((kk * 4 + quad) ^ (l16 & 7)) * 8;
            bf16x8 b1[4], b2[4];
#pragma unroll
            for (int ct = 0; ct < 4; ++ct) {
                b1[ct] = *(const bf16x8*)&krs[cur][ct * 16 + l16][p];
                b2[ct] = *(const bf16x8*)&vrs[cur][ct * 16 + l16][p];
            }
#pragma unroll
            for (int rt = 0; rt < 2; ++rt)
#pragma unroll
                for (int ct = 0; ct < 4; ++ct) {
                    s1[rt][ct] = __builtin_amdgcn_mfma_f32_16x16x32_bf16(
                        a1[rt][kk], b1[ct], s1[rt][ct], 0, 0, 0);
                    s2[rt][ct] = __builtin_amdgcn_mfma_f32_16x16x32_bf16(
                        a2[rt][kk], b2[ct], s2[rt][ct], 0, 0, 0);
                }
        }
        __builtin_amdgcn_s_setprio(0);

        if (tf) {
#pragma unroll
            for (int rt = 0; rt < 2; ++rt)
#pragma unroll
                for (int ct = 0; ct < 4; ++ct)
#pragma unroll
                    for (int r = 0; r < 4; ++r) {
                        int qrow = q0 + w * 32 + rt * 16 + quad * 4 + r;
                        int kc   = k0 + ct * 16 + l16;
                        if (mask[((size_t)b * S_ + qrow) * S_ + kc] == 0)
                            s1[rt][ct][r] = -1e9f;
                    }
        }

        float tmax[2][4];
#pragma unroll
        for (int rt = 0; rt < 2; ++rt)
#pragma unroll
            for (int r = 0; r < 4; ++r) tmax[rt][r] = -1e30f;
#pragma unroll
        for (int rt = 0; rt < 2; ++rt)
#pragma unroll
            for (int ct = 0; ct < 4; ++ct)
#pragma unroll
                for (int r = 0; r < 4; ++r)
                    tmax[rt][r] = fmaxf(tmax[rt][r], s1[rt][ct][r]);
#pragma unroll
        for (int off = 1; off < 16; off <<= 1)
#pragma unroll
            for (int rt = 0; rt < 2; ++rt)
#pragma unroll
                for (int r = 0; r < 4; ++r)
                    tmax[rt][r] = fmaxf(tmax[rt][r], __shfl_xor(tmax[rt][r], off, 64));

        float alpha[2][4], newm[2][4];
#pragma unroll
        for (int rt = 0; rt < 2; ++rt)
#pragma unroll
            for (int r = 0; r < 4; ++r) {
                newm[rt][r]  = fmaxf(m_run[rt][r], tmax[rt][r]);
                alpha[rt][r] = __expf(m_run[rt][r] - newm[rt][r]);
                m_run[rt][r] = newm[rt][r];
            }

        float psum[2][4] = {};
#pragma unroll
        for (int rt = 0; rt < 2; ++rt)
#pragma unroll
            for (int ct = 0; ct < 4; ++ct)
#pragma unroll
                for (int r = 0; r < 4; ++r) {
                    float p = __expf(s1[rt][ct][r] - newm[rt][r]);
                    psum[rt][r] += p;
                    pts[w][rt * 16 + quad * 4 + r][ct * 16 + l16] =
                        f2bf_fast(p * s2[rt][ct][r]);
                }
#pragma unroll
        for (int off = 1; off < 16; off <<= 1)
#pragma unroll
            for (int rt = 0; rt < 2; ++rt)
#pragma unroll
                for (int r = 0; r < 4; ++r)
                    psum[rt][r] += __shfl_xor(psum[rt][r], off, 64);
#pragma unroll
        for (int rt = 0; rt < 2; ++rt)
#pragma unroll
            for (int r = 0; r < 4; ++r)
                l_run[rt][r] = l_run[rt][r] * alpha[rt][r] + psum[rt][r];
#pragma unroll
        for (int rt = 0; rt < 2; ++rt)
#pragma unroll
            for (int ct = 0; ct < 4; ++ct)
#pragma unroll
                for (int r = 0; r < 4; ++r) oacc[rt][ct][r] *= alpha[rt][r];

        {
            __builtin_amdgcn_s_setprio(1);
            bf16x8 bb[2][4];
#pragma unroll
            for (int kk = 0; kk < 2; ++kk) {
                const int p = ((kk * 4 + quad) ^ (l16 & 7)) * 8;
#pragma unroll
                for (int ct = 0; ct < 4; ++ct)
                    bb[kk][ct] = *(const bf16x8*)&kts[cur][ct * 16 + l16][p];
            }
#pragma unroll
            for (int rt = 0; rt < 2; ++rt)
#pragma unroll
                for (int kk = 0; kk < 2; ++kk) {
                    // per-wave DS in-order: reads see this wave's pts writes
                    bf16x8 a = *(const bf16x8*)&pts[w][rt * 16 + l16][kk * 32 + quad * 8];
#pragma unroll
                    for (int ct = 0; ct < 4; ++ct)
                        oacc[rt][ct] = __builtin_amdgcn_mfma_f32_16x16x32_bf16(
                            a, bb[kk][ct], oacc[rt][ct], 0, 0, 0);
                }
            __builtin_amdgcn_s_setprio(0);
        }

        // barrier releases next buffer (drains the in-flight DMA)
        if (pf) __syncthreads();
    }

#pragma unroll
    for (int rt = 0; rt < 2; ++rt)
#pragma unroll
        for (int ct = 0; ct < 4; ++ct)
#pragma unroll
            for (int r = 0; r < 4; ++r) {
                int row = q0 + w * 32 + rt * 16 + quad * 4 + r;
                int col = ct * 16 + l16;
                float v = oacc[rt][ct][r] / l_run[rt][r];
                om[base + (size_t)row * DM_ + col] = f2bf_fast(v);
            }
#undef STAGE_TILES
}

// ---------------------------------------------------------------------------
extern "C" void kernel_launch(void* const* d_in, const int* in_sizes, int n_in,
                              void* d_out, int out_size, void* d_ws, size_t ws_size,
                              hipStream_t stream)
{
    const void* query = d_in[0];
    const void* key   = d_in[1];
    const void* value = d_in[2];
    const int*  mask  = (const int*)d_in[3];
    const void* Wq  = d_in[4];  const void* bq  = d_in[5];
    const void* Wk  = d_in[6];  const void* bk  = d_in[7];
    const void* Wv  = d_in[8];  const void* bv  = d_in[9];
    const void* Wo  = d_in[10]; const void* bo  = d_in[11];
    const void* Wkl = d_in[12]; const void* bkl = d_in[13];
    const void* Wql = d_in[14]; const void* bql = d_in[15];
    const void* Wq2 = d_in[16]; const void* bq2 = d_in[17];
    const void* Wvl = d_in[18]; const void* bvl = d_in[19];
    const void* Wel = d_in[20]; const void* bel = d_in[21];

    int* flag   = (int*)d_ws;
    int* tflags = (int*)d_ws + 4;                     // 64 ints
    u16* ws     = (u16*)((char*)d_ws + 512);
    const size_t BUF = (size_t)(B_ * S_) * DM_;       // 4M elems = 8 MB bf16
    u16* Kp  = ws + 0 * BUF;
    u16* krb = ws + 1 * BUF;
    u16* q1b = ws + 2 * BUF;
    u16* q2r = ws + 3 * BUF;
    u16* vrb = ws + 4 * BUF;
    u16* Om  = ws + 5 * BUF;
    u16* KpT = ws + 6 * BUF;
    u16* Qc  = ws + 7 * BUF;
    u16* Kc  = ws + 8 * BUF;
    u16* Vc  = ws + 9 * BUF;
    u16* Wbig = ws + 10 * BUF;
    u16* Wqc = Wbig + 0 * (size_t)(DM_ * DM_);
    u16* Wkc = Wbig + 1 * (size_t)(DM_ * DM_);
    u16* Wvc = Wbig + 2 * (size_t)(DM_ * DM_);
    u16* Woc = Wbig + 3 * (size_t)(DM_ * DM_);
    u16* Wsm = Wbig + 4 * (size_t)(DM_ * DM_);
    u16* Wklc = Wsm + 0 * (DK_ * DK_);
    u16* Wqlc = Wsm + 1 * (DK_ * DK_);
    u16* Welc = Wsm + 2 * (DK_ * DK_);
    u16* Wq2c = Wsm + 3 * (DK_ * DK_);
    u16* Wvlc = Wsm + 4 * (DK_ * DK_);

    const int M = B_ * S_;
    dim3 blk(256);

    detect_kernel<<<1, 64, 0, stream>>>((const u16*)query, flag);

    // fused mask-flag scan + dtype conversion
    hipMemsetAsync(tflags, 0, 64 * sizeof(int), stream);
    CvtArgs ca;
    const unsigned VIN = (unsigned)(BUF / 8);
    const unsigned VWB = (unsigned)(DM_ * DM_ / 8);
    const unsigned VWS = (unsigned)(DK_ * DK_ / 8);
    const void* srcs[NSEG] = {query, key, value, Wq, Wk, Wv, Wo, Wkl, Wql, Wel, Wq2, Wvl};
    void* dsts[NSEG] = {Qc, Kc, Vc, Wqc, Wkc, Wvc, Woc, Wklc, Wqlc, Welc, Wq2c, Wvlc};
    unsigned vcn[NSEG] = {VIN, VIN, VIN, VWB, VWB, VWB, VWB, VWS, VWS, VWS, VWS, VWS};
    unsigned off = 0;
    for (int i = 0; i < NSEG; ++i) { ca.src[i] = srcs[i]; ca.dst[i] = dsts[i]; ca.off[i] = off; off += vcn[i]; }
    ca.off[NSEG] = off;
    prep_kernel<<<dim3(512 + (off + 255) / 256), blk, 0, stream>>>(ca, off, flag, mask, tflags);

    // Q/K/V projections + fused per-head refinements (768 blocks)
    QKVArgs qa = {};
    qa.A0[0] = (const u16*)query; qa.A1[0] = Qc;
    qa.A0[1] = (const u16*)key;   qa.A1[1] = Kc;
    qa.A0[2] = (const u16*)value; qa.A1[2] = Vc;
    qa.W0[0] = (const u16*)Wq; qa.W1[0] = Wqc;
    qa.W0[1] = (const u16*)Wk; qa.W1[1] = Wkc;
    qa.W0[2] = (const u16*)Wv; qa.W1[2] = Wvc;
    qa.bias[0] = bq; qa.bias[1] = bk; qa.bias[2] = bv;
    qa.R10[0] = (const u16*)Wql; qa.R11[0] = Wqlc; qa.rb1[0] = bql;
    qa.R10[1] = (const u16*)Wkl; qa.R11[1] = Wklc; qa.rb1[1] = bkl;
    qa.R10[2] = (const u16*)Wvl; qa.R11[2] = Wvlc; qa.rb1[2] = bvl;
    qa.R20 = (const u16*)Wel; qa.R21 = Welc; qa.rb2 = bel;
    qa.R30 = (const u16*)Wq2; qa.R31 = Wq2c; qa.rb3 = bq2;
    qa.Kp = Kp; qa.q1b = q1b; qa.q2r = q2r; qa.krb = krb; qa.vrb = vrb;
    dim3 gBig(DM_ / 128, M / 128, 3);
    qkv_fused_kernel<<<gBig, blk, 0, stream>>>(qa, flag);

    // Kp -> per-head transposed copy
    dim3 gT(S_ / 64, H_, B_);
    transpose_kernel<<<gT, blk, 0, stream>>>(Kp, KpT);

    // fused attention -> merged (B,S,DM) layout (128 q-rows per block,
    // flat grid + XCD swizzle: one (b,h) pair's 8 q-blocks per XCD)
    attn_kernel<<<dim3(512), blk, 0, stream>>>(q1b, q2r, krb, vrb, KpT, mask, tflags, Om);

    // output projection -> d_out
    dim3 gO(DM_ / 128, M / 128);
    gemm_async_kernel<<<gO, blk, 0, stream>>>(Om, (const u16*)Wo, Woc, bo, d_out, flag);
}

// Round 6
// 290.040 us; speedup vs baseline: 1.3398x; 1.0683x over previous
//
#include <hip/hip_runtime.h>
#include <hip/hip_bf16.h>

#define B_  4
#define S_  1024
#define DM_ 1024
#define H_  16
#define DK_ 64

typedef unsigned short u16;
typedef __attribute__((ext_vector_type(8))) short bf16x8;
typedef __attribute__((ext_vector_type(4))) float f32x4;

__device__ __forceinline__ float bf2f(u16 u) {
    union { unsigned int i; float f; } c;
    c.i = ((unsigned int)u) << 16;
    return c.f;
}
__device__ __forceinline__ u16 f2bf(float f) {
    union { float f; unsigned int i; } c;
    c.f = f;
    unsigned int x = c.i;
    unsigned int lsb = (x >> 16) & 1u;
    x += 0x7fffu + lsb;          // round-to-nearest-even
    return (u16)(x >> 16);
}
__device__ __forceinline__ u16 f2bf_fast(float f) {
    __hip_bfloat16 h = __float2bfloat16(f);   // HW cvt, RNE
    return *reinterpret_cast<u16*>(&h);
}

// async global->LDS, 16B per lane; LDS dest = wave-uniform base + lane*16
__device__ __forceinline__ void async_ld16(const u16* g, u16* l) {
    __builtin_amdgcn_global_load_lds(
        (const __attribute__((address_space(1))) unsigned int*)(const void*)g,
        (__attribute__((address_space(3))) unsigned int*)(void*)l, 16, 0, 0);
}

// ---------------------------------------------------------------------------
// Runtime dtype detection (one wave). flag=1: inputs are fp32.
// ---------------------------------------------------------------------------
__global__ void detect_kernel(const u16* __restrict__ q, int* __restrict__ flag) {
    int lane = threadIdx.x & 63;
    int cnt = 0;
#pragma unroll
    for (int i = 0; i < 4; ++i) {
        u16 u = q[2 * (lane * 4 + i)];
        int e = (u >> 7) & 0xFF;
        cnt += (e >= 100 && e <= 140) ? 1 : 0;
    }
#pragma unroll
    for (int off = 1; off < 64; off <<= 1) cnt += __shfl_xor(cnt, off, 64);
    if (lane == 0) *flag = (cnt < 128) ? 1 : 0;
}

// ---------------------------------------------------------------------------
// Fused prep: blocks [0,512) scan mask -> per-(b,k64-tile) any-zero flags
// (tflags pre-zeroed via hipMemsetAsync; dirty -> atomicOr 1). Blocks >= 512
// do packed fp32->bf16 conversion (early-out when inputs already bf16).
// ---------------------------------------------------------------------------
#define NSEG 12
struct CvtArgs {
    const void* src[NSEG];
    void*       dst[NSEG];
    unsigned    off[NSEG + 1];
};

__global__ __launch_bounds__(256) void prep_kernel(
    CvtArgs a, unsigned total, const int* __restrict__ flag,
    const int* __restrict__ mask, int* __restrict__ tflags)
{
    const int tid = threadIdx.x;
    if (blockIdx.x < 512) {
        const int bx = blockIdx.x;
        const int kt = bx & 15, b = (bx >> 4) & 3, z = bx >> 6;
        int ok = 1;
#pragma unroll
        for (int i = tid; i < 128 * 16; i += 256) {
            int row = z * 128 + (i >> 4), seg = i & 15;
            int4 m = *(const int4*)&mask[((size_t)b * S_ + row) * S_ + kt * 64 + seg * 4];
            ok &= (m.x != 0) & (m.y != 0) & (m.z != 0) & (m.w != 0);
        }
        if (!ok) atomicOr(&tflags[b * 16 + kt], 1);
        return;
    }
    if (!*flag) return;   // bf16 inputs: GEMMs read originals directly
    unsigned v = (blockIdx.x - 512) * 256 + tid;
    if (v >= total) return;
    int s = 0;
    while (s < NSEG - 1 && v >= a.off[s + 1]) ++s;
    unsigned local = v - a.off[s];
    u16* dp = (u16*)a.dst[s] + (size_t)local * 8;
    const float* sp = (const float*)a.src[s] + (size_t)local * 8;
    float4 x = *(const float4*)sp, y = *(const float4*)(sp + 4);
    u16 t[8] = {f2bf(x.x), f2bf(x.y), f2bf(x.z), f2bf(x.w),
                f2bf(y.x), f2bf(y.y), f2bf(y.z), f2bf(y.w)};
    *(uint4*)dp = *(uint4*)t;
}

// ---------------------------------------------------------------------------
// Per-head transpose: Kp (b,s,h,d) -> KpT[((b*H+h)*DK + d)*S + s].
// ---------------------------------------------------------------------------
__global__ __launch_bounds__(256) void transpose_kernel(
    const u16* __restrict__ kp, u16* __restrict__ kpt)
{
    __shared__ u16 T[64][65];
    const int s0 = blockIdx.x * 64, h = blockIdx.y, b = blockIdx.z;
    const int tid = threadIdx.x;
    const size_t base = (size_t)b * S_ * DM_ + (size_t)h * DK_;
    for (int c = tid; c < 512; c += 256) {
        int row = c >> 3, cc = (c & 7) * 8;
        union { uint4 v; u16 u[8]; } x;
        x.v = *(const uint4*)&kp[base + (size_t)(s0 + row) * DM_ + cc];
#pragma unroll
        for (int j = 0; j < 8; ++j) T[row][cc + j] = x.u[j];
    }
    __syncthreads();
    const size_t baseT = (size_t)(b * H_ + h) * DK_ * S_;
    for (int c = tid; c < 512; c += 256) {
        int d = c >> 3, ss = (c & 7) * 8;
        u16 t[8];
#pragma unroll
        for (int j = 0; j < 8; ++j) t[j] = T[ss + j][d];
        *(uint4*)&kpt[baseT + (size_t)d * S_ + s0 + ss] = *(uint4*)t;
    }
}

// ---------------------------------------------------------------------------
// QKV projection + fused per-head refinements. 128x128 tile, BK=64, async
// global->LDS staging, XOR column-group swizzle (m97 structure). After the
// K-loop each wave's 64x64 quadrant is ONE head's complete column block for
// 64 rows, so the row-local 64x64 refinements run entirely in the epilogue:
// C-layout acc -> per-wave LDS region (A-layout swizzled) -> MFMA with
// weight B-frags read straight from global (L2-hot, shared across heads).
// z=0 (Q): emits q1b (Wql->Wel chain) + q2r. z=1 (K): Kp + krb. z=2: vrb.
// ---------------------------------------------------------------------------
struct QKVArgs {
    const u16* A0[3]; const u16* A1[3];
    const u16* W0[3]; const u16* W1[3];
    const void* bias[3];
    const u16* R10[3]; const u16* R11[3];   // Wql, Wkl, Wvl
    const void* rb1[3];                      // bql, bkl, bvl
    const u16* R20; const u16* R21; const void* rb2;   // Wel, bel
    const u16* R30; const u16* R31; const void* rb3;   // Wq2, bq2
    u16 *Kp, *q1b, *q2r, *krb, *vrb;
};

__global__ __launch_bounds__(256, 3) void qkv_fused_kernel(
    QKVArgs a, const int* __restrict__ flag)
{
    __shared__ __align__(16) u16 smem[16384];   // 32 KB: As+Ws; epilogue 4x8KB/wave
    u16 (*As)[64] = (u16(*)[64])smem;
    u16 (*Ws)[64] = (u16(*)[64])(smem + 8192);

    const int z = blockIdx.z;
    const int f = *flag;
    const u16* __restrict__ A = f ? a.A1[z] : a.A0[z];
    const u16* __restrict__ W = f ? a.W1[z] : a.W0[z];
    const void* biasp = a.bias[z];

    const int m0   = blockIdx.y * 128;
    const int n0   = blockIdx.x * 128;
    const int tid  = threadIdx.x;
    const int w    = tid >> 6;
    const int lane = tid & 63;
    const int l16  = lane & 15;
    const int quad = lane >> 4;
    const int wr   = (w >> 1) * 64;
    const int wc   = (w & 1) * 64;

    const int srow = lane >> 3;
    const int sgrp = (lane & 7) ^ srow;

    f32x4 acc[4][4];
#pragma unroll
    for (int rt = 0; rt < 4; ++rt)
#pragma unroll
        for (int ct = 0; ct < 4; ++ct) acc[rt][ct] = (f32x4){0.f, 0.f, 0.f, 0.f};

    for (int k0 = 0; k0 < DM_; k0 += 64) {
#pragma unroll
        for (int s = 0; s < 4; ++s) {
            int seg = w * 4 + s;
            async_ld16(&A[(size_t)(m0 + seg * 8 + srow) * DM_ + k0 + sgrp * 8],
                       &As[seg * 8][0]);
            async_ld16(&W[(size_t)(n0 + seg * 8 + srow) * DM_ + k0 + sgrp * 8],
                       &Ws[seg * 8][0]);
        }
        __syncthreads();
#pragma unroll
        for (int kk = 0; kk < 2; ++kk) {
            const int p = (kk * 4 + quad) ^ (l16 & 7);
            bf16x8 av[4], bv[4];
#pragma unroll
            for (int rt = 0; rt < 4; ++rt)
                av[rt] = *(const bf16x8*)&As[wr + rt * 16 + l16][p * 8];
#pragma unroll
            for (int ct = 0; ct < 4; ++ct)
                bv[ct] = *(const bf16x8*)&Ws[wc + ct * 16 + l16][p * 8];
#pragma unroll
            for (int rt = 0; rt < 4; ++rt)
#pragma unroll
                for (int ct = 0; ct < 4; ++ct)
                    acc[rt][ct] = __builtin_amdgcn_mfma_f32_16x16x32_bf16(
                        av[rt], bv[ct], acc[rt][ct], 0, 0, 0);
        }
        __syncthreads();   // trailing barrier: all waves done reading As/Ws
    }

    // ---- fused refinement epilogue (per-wave private LDS region) ----
    const int hcol = n0 + wc;                       // = head * 64
    u16 (*Es)[64] = (u16(*)[64])(smem + w * 4096);

    // projected tile (+bias, bf16) -> Es in A-layout swizzle; z==1 also -> Kp
#pragma unroll
    for (int ct = 0; ct < 4; ++ct) {
        int col = hcol + ct * 16 + l16;
        float bv = f ? ((const float*)biasp)[col] : bf2f(((const u16*)biasp)[col]);
#pragma unroll
        for (int rt = 0; rt < 4; ++rt)
#pragma unroll
            for (int r = 0; r < 4; ++r) {
                int ml = rt * 16 + quad * 4 + r;
                int cl = ct * 16 + l16;
                u16 bb = f2bf(acc[rt][ct][r] + bv);
                if (z == 1) a.Kp[(size_t)(m0 + wr + ml) * DM_ + col] = bb;
                Es[ml][((((cl >> 3) ^ (ml & 7)) << 3) | (cl & 7))] = bb;
            }
    }

    // A-frags of the projected tile (same-wave DS in-order; no barrier needed)
    bf16x8 af[4][2];
#pragma unroll
    for (int rt = 0; rt < 4; ++rt)
#pragma unroll
        for (int kk = 0; kk < 2; ++kk)
            af[rt][kk] = *(const bf16x8*)
                &Es[rt * 16 + l16][(((kk * 4 + quad) ^ (l16 & 7)) << 3)];

    // stage-1 weight B-frags from global (64x64, L2-hot)
    const u16* R1 = f ? a.R11[z] : a.R10[z];
    bf16x8 wb[2][4];
#pragma unroll
    for (int kk = 0; kk < 2; ++kk)
#pragma unroll
        for (int ct = 0; ct < 4; ++ct)
            wb[kk][ct] = *(const bf16x8*)
                &R1[(size_t)(ct * 16 + l16) * 64 + kk * 32 + quad * 8];

    f32x4 r1[4][4];
#pragma unroll
    for (int rt = 0; rt < 4; ++rt)
#pragma unroll
        for (int ct = 0; ct < 4; ++ct) r1[rt][ct] = (f32x4){0.f, 0.f, 0.f, 0.f};
#pragma unroll
    for (int kk = 0; kk < 2; ++kk)
#pragma unroll
        for (int rt = 0; rt < 4; ++rt)
#pragma unroll
            for (int ct = 0; ct < 4; ++ct)
                r1[rt][ct] = __builtin_amdgcn_mfma_f32_16x16x32_bf16(
                    af[rt][kk], wb[kk][ct], r1[rt][ct], 0, 0, 0);

    if (z != 0) {
        // single-stage: krb (z==1) or vrb (z==2) = relu(r1 + rb1)
        const void* rb = a.rb1[z];
        u16* out = (z == 1) ? a.krb : a.vrb;
#pragma unroll
        for (int ct = 0; ct < 4; ++ct) {
            int cl = ct * 16 + l16;
            float bv = f ? ((const float*)rb)[cl] : bf2f(((const u16*)rb)[cl]);
#pragma unroll
            for (int rt = 0; rt < 4; ++rt)
#pragma unroll
                for (int r = 0; r < 4; ++r) {
                    float v = r1[rt][ct][r] + bv;
                    v = v > 0.f ? v : 0.f;
                    out[(size_t)(m0 + wr + rt * 16 + quad * 4 + r) * DM_ + hcol + cl]
                        = f2bf(v);
                }
        }
    } else {
        // q1a = relu(r1 + bql) -> Es (round-trip for stage 2)
        {
            const void* rb = a.rb1[0];
#pragma unroll
            for (int ct = 0; ct < 4; ++ct) {
                int cl = ct * 16 + l16;
                float bv = f ? ((const float*)rb)[cl] : bf2f(((const u16*)rb)[cl]);
#pragma unroll
                for (int rt = 0; rt < 4; ++rt)
#pragma unroll
                    for (int r = 0; r < 4; ++r) {
                        float v = r1[rt][ct][r] + bv;
                        v = v > 0.f ? v : 0.f;
                        int ml = rt * 16 + quad * 4 + r;
                        Es[ml][((((cl >> 3) ^ (ml & 7)) << 3) | (cl & 7))] = f2bf(v);
                    }
            }
        }
        // q2r = relu(proj @ Wq2^T + bq2)  (reuses af while Es writes land)
        {
            const u16* R3 = f ? a.R31 : a.R30;
#pragma unroll
            for (int kk = 0; kk < 2; ++kk)
#pragma unroll
                for (int ct = 0; ct < 4; ++ct)
                    wb[kk][ct] = *(const bf16x8*)
                        &R3[(size_t)(ct * 16 + l16) * 64 + kk * 32 + quad * 8];
            f32x4 r3[4][4];
#pragma unroll
            for (int rt = 0; rt < 4; ++rt)
#pragma unroll
                for (int ct = 0; ct < 4; ++ct) r3[rt][ct] = (f32x4){0.f, 0.f, 0.f, 0.f};
#pragma unroll
            for (int kk = 0; kk < 2; ++kk)
#pragma unroll
                for (int rt = 0; rt < 4; ++rt)
#pragma unroll
                    for (int ct = 0; ct < 4; ++ct)
                        r3[rt][ct] = __builtin_amdgcn_mfma_f32_16x16x32_bf16(
                            af[rt][kk], wb[kk][ct], r3[rt][ct], 0, 0, 0);
            const void* rb = a.rb3;
#pragma unroll
            for (int ct = 0; ct < 4; ++ct) {
                int cl = ct * 16 + l16;
                float bv = f ? ((const float*)rb)[cl] : bf2f(((const u16*)rb)[cl]);
#pragma unroll
                for (int rt = 0; rt < 4; ++rt)
#pragma unroll
                    for (int r = 0; r < 4; ++r) {
                        float v = r3[rt][ct][r] + bv;
                        v = v > 0.f ? v : 0.f;
                        a.q2r[(size_t)(m0 + wr + rt * 16 + quad * 4 + r) * DM_
                              + hcol + cl] = f2bf(v);
                    }
            }
        }
        // q1b = relu(q1a @ Wel^T + bel)
        {
#pragma unroll
            for (int rt = 0; rt < 4; ++rt)
#pragma unroll
                for (int kk = 0; kk < 2; ++kk)
                    af[rt][kk] = *(const bf16x8*)
                        &Es[rt * 16 + l16][(((kk * 4 + quad) ^ (l16 & 7)) << 3)];
            const u16* R2 = f ? a.R21 : a.R20;
#pragma unroll
            for (int kk = 0; kk < 2; ++kk)
#pragma unroll
                for (int ct = 0; ct < 4; ++ct)
                    wb[kk][ct] = *(const bf16x8*)
                        &R2[(size_t)(ct * 16 + l16) * 64 + kk * 32 + quad * 8];
            f32x4 r2[4][4];
#pragma unroll
            for (int rt = 0; rt < 4; ++rt)
#pragma unroll
                for (int ct = 0; ct < 4; ++ct) r2[rt][ct] = (f32x4){0.f, 0.f, 0.f, 0.f};
#pragma unroll
            for (int kk = 0; kk < 2; ++kk)
#pragma unroll
                for (int rt = 0; rt < 4; ++rt)
#pragma unroll
                    for (int ct = 0; ct < 4; ++ct)
                        r2[rt][ct] = __builtin_amdgcn_mfma_f32_16x16x32_bf16(
                            af[rt][kk], wb[kk][ct], r2[rt][ct], 0, 0, 0);
            const void* rb = a.rb2;
#pragma unroll
            for (int ct = 0; ct < 4; ++ct) {
                int cl = ct * 16 + l16;
                float bv = f ? ((const float*)rb)[cl] : bf2f(((const u16*)rb)[cl]);
#pragma unroll
                for (int rt = 0; rt < 4; ++rt)
#pragma unroll
                    for (int r = 0; r < 4; ++r) {
                        float v = r2[rt][ct][r] + bv;
                        v = v > 0.f ? v : 0.f;
                        a.q1b[(size_t)(m0 + wr + rt * 16 + quad * 4 + r) * DM_
                              + hcol + cl] = f2bf(v);
                    }
            }
        }
    }
}

// ---------------------------------------------------------------------------
// Output-projection GEMM (m97 structure), dtype-dynamic bias/out.
// ---------------------------------------------------------------------------
__global__ __launch_bounds__(256, 3) void gemm_async_kernel(
    const u16* __restrict__ Ain, const u16* __restrict__ W0,
    const u16* __restrict__ W1, const void* __restrict__ biasp,
    void* __restrict__ Cp, const int* __restrict__ flag)
{
    __shared__ __align__(16) u16 As[128][64];
    __shared__ __align__(16) u16 Ws[128][64];

    const int f = *flag;
    const u16* __restrict__ W = f ? W1 : W0;

    const int m0   = blockIdx.y * 128;
    const int n0   = blockIdx.x * 128;
    const int tid  = threadIdx.x;
    const int w    = tid >> 6;
    const int lane = tid & 63;
    const int l16  = lane & 15;
    const int quad = lane >> 4;
    const int wr   = (w >> 1) * 64;
    const int wc   = (w & 1) * 64;

    const int srow = lane >> 3;
    const int sgrp = (lane & 7) ^ srow;

    f32x4 acc[4][4];
#pragma unroll
    for (int rt = 0; rt < 4; ++rt)
#pragma unroll
        for (int ct = 0; ct < 4; ++ct) acc[rt][ct] = (f32x4){0.f, 0.f, 0.f, 0.f};

    for (int k0 = 0; k0 < DM_; k0 += 64) {
#pragma unroll
        for (int s = 0; s < 4; ++s) {
            int seg = w * 4 + s;
            async_ld16(&Ain[(size_t)(m0 + seg * 8 + srow) * DM_ + k0 + sgrp * 8],
                       &As[seg * 8][0]);
            async_ld16(&W[(size_t)(n0 + seg * 8 + srow) * DM_ + k0 + sgrp * 8],
                       &Ws[seg * 8][0]);
        }
        __syncthreads();
#pragma unroll
        for (int kk = 0; kk < 2; ++kk) {
            const int p = (kk * 4 + quad) ^ (l16 & 7);
            bf16x8 av[4], bv[4];
#pragma unroll
            for (int rt = 0; rt < 4; ++rt)
                av[rt] = *(const bf16x8*)&As[wr + rt * 16 + l16][p * 8];
#pragma unroll
            for (int ct = 0; ct < 4; ++ct)
                bv[ct] = *(const bf16x8*)&Ws[wc + ct * 16 + l16][p * 8];
#pragma unroll
            for (int rt = 0; rt < 4; ++rt)
#pragma unroll
                for (int ct = 0; ct < 4; ++ct)
                    acc[rt][ct] = __builtin_amdgcn_mfma_f32_16x16x32_bf16(
                        av[rt], bv[ct], acc[rt][ct], 0, 0, 0);
        }
        __syncthreads();
    }

#pragma unroll
    for (int ct = 0; ct < 4; ++ct) {
        int col = n0 + wc + ct * 16 + l16;
        float bv = f ? ((const float*)biasp)[col] : bf2f(((const u16*)biasp)[col]);
#pragma unroll
        for (int rt = 0; rt < 4; ++rt)
#pragma unroll
            for (int r = 0; r < 4; ++r) {
                int row = m0 + wr + rt * 16 + quad * 4 + r;
                float v = acc[rt][ct][r] + bv;
                size_t idx = (size_t)row * DM_ + col;
                if (f) ((float*)Cp)[idx] = v;
                else   ((u16*)Cp)[idx]   = f2bf(v);
            }
    }
}

// ---------------------------------------------------------------------------
// Fused attention, R15: R5 structure (DMA staging, 1 barrier/tile, XCD
// swizzle, setprio) + SWAPPED QK^T (T12 prerequisite). A/B fragments of
// mfma_16x16x32 have identical per-lane layouts, so mfma(kr,q) instead of
// mfma(q,kr) gives D[k][q]: each lane owns 16 k-values of ONE q-row
// (q = qt*16+l16). Row max/sum become in-lane folds + 2 shfl_xor(16,32)
// instead of 4-round 16-lane trees; pts writes become 16 packed u32 instead
// of 32 u16. DS ops/thread/tile: ~104 -> ~40 (DS pipe was ~half the kernel).
// oacc (PV C-layout, rows q=quad*4+r) needs an 8-bpermute alpha broadcast
// per tile + one l_run broadcast at the end. PV path unchanged.
// ---------------------------------------------------------------------------
__global__ __launch_bounds__(256, 2) void attn_kernel(
    const u16* __restrict__ q1, const u16* __restrict__ q2,
    const u16* __restrict__ kr, const u16* __restrict__ vr,
    const u16* __restrict__ kpt, const int* __restrict__ mask,
    const int* __restrict__ tflags, u16* __restrict__ om)
{
    __shared__ __align__(16) u16 krs[2][64][64];
    __shared__ __align__(16) u16 vrs[2][64][64];
    __shared__ __align__(16) u16 kts[2][64][64];   // KpT tile: rows d, cols k
    __shared__ __align__(16) u16 pts[4][32][72];   // per-wave P~ staging

    // bijective XCD swizzle: hw XCD = bid%8; XCD x gets orig ids x*64..x*64+63
    // = (b,h) pairs 8x..8x+7 complete (8 q-tiles each).
    const int bid  = blockIdx.x;                  // 0..511 flat
    const int orig = (bid & 7) * 64 + (bid >> 3);
    const int qt = orig & 7;
    const int h  = (orig >> 3) & 15;
    const int b  = orig >> 7;

    const int q0   = qt * 128;
    const int tid  = threadIdx.x;
    const int w    = tid >> 6;
    const int lane = tid & 63;
    const int l16  = lane & 15;
    const int quad = lane >> 4;

    const size_t base  = (size_t)b * S_ * DM_ + (size_t)h * DK_;
    const size_t baseT = (size_t)(b * H_ + h) * DK_ * S_;

    // staging lane coords (qkv pattern): row-in-segment + XOR'd col group
    const int srow = lane >> 3;                  // 0..7
    const int sgrp = (lane & 7) ^ srow;          // swizzled source col group

    // issue 6 global_load_lds per wave covering 24 segments of 8 rows:
    // flat seg s = w*6+i; tile t = s/8 (0:krs 1:vrs 2:kts); r8 = (s%8)*8.
#define STAGE_TILES(buf, kn)                                                   \
    {                                                                          \
        _Pragma("unroll")                                                      \
        for (int i = 0; i < 6; ++i) {                                          \
            int s_ = w * 6 + i;                                                \
            int t_ = s_ >> 3;                                                  \
            int r8 = (s_ & 7) * 8;                                             \
            if (t_ == 0)                                                       \
                async_ld16(&kr[base + (size_t)((kn) + r8 + srow) * DM_ +       \
                               sgrp * 8], &krs[buf][r8][0]);                   \
            else if (t_ == 1)                                                  \
                async_ld16(&vr[base + (size_t)((kn) + r8 + srow) * DM_ +       \
                               sgrp * 8], &vrs[buf][r8][0]);                   \
            else                                                               \
                async_ld16(&kpt[baseT + (size_t)(r8 + srow) * S_ + (kn) +      \
                                sgrp * 8], &kts[buf][r8][0]);                  \
        }                                                                      \
    }

    bf16x8 a1[2][2], a2[2][2];
#pragma unroll
    for (int rt = 0; rt < 2; ++rt) {
        const int qrow = q0 + w * 32 + rt * 16 + l16;
#pragma unroll
        for (int kk = 0; kk < 2; ++kk) {
            a1[rt][kk] = *(const bf16x8*)&q1[base + (size_t)qrow * DM_ + kk * 32 + quad * 8];
            a2[rt][kk] = *(const bf16x8*)&q2[base + (size_t)qrow * DM_ + kk * 32 + quad * 8];
        }
    }

    // softmax state: per qt half, this lane owns q = qt*16 + l16
    float m_run[2], l_run[2];
    f32x4 oacc[2][4];
#pragma unroll
    for (int qt2 = 0; qt2 < 2; ++qt2) { m_run[qt2] = -1e30f; l_run[qt2] = 0.f; }
#pragma unroll
    for (int rt = 0; rt < 2; ++rt)
#pragma unroll
        for (int ct = 0; ct < 4; ++ct) oacc[rt][ct] = (f32x4){0.f, 0.f, 0.f, 0.f};

    // ---- prologue: stage tile 0 into buffer 0 (barrier drains vmcnt) ----
    STAGE_TILES(0, 0)
    __syncthreads();

    for (int kt = 0; kt < S_ / 64; ++kt) {
        const int cur = kt & 1;
        const int k0  = kt * 64;
        const bool pf = (kt + 1 < S_ / 64);

        // issue next-tile DMA first — lands during compute, drained by barrier
        if (pf) STAGE_TILES(cur ^ 1, k0 + 64)

        const int tf = tflags[b * 16 + kt];

        // st[qt][kt4] = D[k][q]: row k = kt4*16 + quad*4 + r, col q = qt*16+l16
        f32x4 st1[2][4], st2[2][4];
#pragma unroll
        for (int qt2 = 0; qt2 < 2; ++qt2)
#pragma unroll
            for (int kt4 = 0; kt4 < 4; ++kt4) {
                st1[qt2][kt4] = (f32x4){0.f, 0.f, 0.f, 0.f};
                st2[qt2][kt4] = (f32x4){0.f, 0.f, 0.f, 0.f};
            }
        __builtin_amdgcn_s_setprio(1);
#pragma unroll
        for (int kk = 0; kk < 2; ++kk) {
            const int p = ((kk * 4 + quad) ^ (l16 & 7)) * 8;
            bf16x8 b1[4], b2[4];
#pragma unroll
            for (int kt4 = 0; kt4 < 4; ++kt4) {
                b1[kt4] = *(const bf16x8*)&krs[cur][kt4 * 16 + l16][p];
                b2[kt4] = *(const bf16x8*)&vrs[cur][kt4 * 16 + l16][p];
            }
            // SWAPPED operand order: A=K/V rows (k), B=Q rows (q)
#pragma unroll
            for (int qt2 = 0; qt2 < 2; ++qt2)
#pragma unroll
                for (int kt4 = 0; kt4 < 4; ++kt4) {
                    st1[qt2][kt4] = __builtin_amdgcn_mfma_f32_16x16x32_bf16(
                        b1[kt4], a1[qt2][kk], st1[qt2][kt4], 0, 0, 0);
                    st2[qt2][kt4] = __builtin_amdgcn_mfma_f32_16x16x32_bf16(
                        b2[kt4], a2[qt2][kk], st2[qt2][kt4], 0, 0, 0);
                }
        }
        __builtin_amdgcn_s_setprio(0);

        if (tf) {
#pragma unroll
            for (int qt2 = 0; qt2 < 2; ++qt2)
#pragma unroll
                for (int kt4 = 0; kt4 < 4; ++kt4)
#pragma unroll
                    for (int r = 0; r < 4; ++r) {
                        int qrow = q0 + w * 32 + qt2 * 16 + l16;
                        int kc   = k0 + kt4 * 16 + quad * 4 + r;
                        if (mask[((size_t)b * S_ + qrow) * S_ + kc] == 0)
                            st1[qt2][kt4][r] = -1e9f;
                    }
        }

        // ---- row-local softmax: in-lane fold + 2 shfl_xor per quantity ----
        float alphaq[2], newm[2];
#pragma unroll
        for (int qt2 = 0; qt2 < 2; ++qt2) {
            float m = st1[qt2][0][0];
#pragma unroll
            for (int kt4 = 0; kt4 < 4; ++kt4)
#pragma unroll
                for (int r = 0; r < 4; ++r)
                    m = fmaxf(m, st1[qt2][kt4][r]);
            m = fmaxf(m, __shfl_xor(m, 16, 64));
            m = fmaxf(m, __shfl_xor(m, 32, 64));
            newm[qt2]   = fmaxf(m_run[qt2], m);
            alphaq[qt2] = __expf(m_run[qt2] - newm[qt2]);
            m_run[qt2]  = newm[qt2];
        }

#pragma unroll
        for (int qt2 = 0; qt2 < 2; ++qt2) {
            float s = 0.f;
#pragma unroll
            for (int kt4 = 0; kt4 < 4; ++kt4)
#pragma unroll
                for (int pp = 0; pp < 2; ++pp) {
                    float p0 = __expf(st1[qt2][kt4][2 * pp]     - newm[qt2]);
                    float p1 = __expf(st1[qt2][kt4][2 * pp + 1] - newm[qt2]);
                    s += p0 + p1;
                    unsigned u = (unsigned)f2bf_fast(p0 * st2[qt2][kt4][2 * pp])
                               | ((unsigned)f2bf_fast(p1 * st2[qt2][kt4][2 * pp + 1]) << 16);
                    *(unsigned*)&pts[w][qt2 * 16 + l16][kt4 * 16 + quad * 4 + 2 * pp] = u;
                }
            s += __shfl_xor(s, 16, 64);
            s += __shfl_xor(s, 32, 64);
            l_run[qt2] = l_run[qt2] * alphaq[qt2] + s;
        }

        // oacc rescale: broadcast alpha from softmax layout (q=l16) to
        // C-layout rows (q=quad*4+r); value uniform across source quads.
#pragma unroll
        for (int rt = 0; rt < 2; ++rt)
#pragma unroll
            for (int r = 0; r < 4; ++r) {
                float ao = __shfl(alphaq[rt], quad * 4 + r, 64);
#pragma unroll
                for (int ct = 0; ct < 4; ++ct) oacc[rt][ct][r] *= ao;
            }

        {
            __builtin_amdgcn_s_setprio(1);
            bf16x8 bb[2][4];
#pragma unroll
            for (int kk = 0; kk < 2; ++kk) {
                const int p = ((kk * 4 + quad) ^ (l16 & 7)) * 8;
#pragma unroll
                for (int ct = 0; ct < 4; ++ct)
                    bb[kk][ct] = *(const bf16x8*)&kts[cur][ct * 16 + l16][p];
            }
#pragma unroll
            for (int rt = 0; rt < 2; ++rt)
#pragma unroll
                for (int kk = 0; kk < 2; ++kk) {
                    // per-wave DS in-order: reads see this wave's pts writes
                    bf16x8 a = *(const bf16x8*)&pts[w][rt * 16 + l16][kk * 32 + quad * 8];
#pragma unroll
                    for (int ct = 0; ct < 4; ++ct)
                        oacc[rt][ct] = __builtin_amdgcn_mfma_f32_16x16x32_bf16(
                            a, bb[kk][ct], oacc[rt][ct], 0, 0, 0);
                }
            __builtin_amdgcn_s_setprio(0);
        }

        // barrier releases next buffer (drains the in-flight DMA)
        if (pf) __syncthreads();
    }

#pragma unroll
    for (int rt = 0; rt < 2; ++rt)
#pragma unroll
        for (int r = 0; r < 4; ++r) {
            float lo = __shfl(l_run[rt], quad * 4 + r, 64);
            float inv = 1.f / lo;
#pragma unroll
            for (int ct = 0; ct < 4; ++ct) {
                int row = q0 + w * 32 + rt * 16 + quad * 4 + r;
                int col = ct * 16 + l16;
                om[base + (size_t)row * DM_ + col] = f2bf_fast(oacc[rt][ct][r] * inv);
            }
        }
#undef STAGE_TILES
}

// ---------------------------------------------------------------------------
extern "C" void kernel_launch(void* const* d_in, const int* in_sizes, int n_in,
                              void* d_out, int out_size, void* d_ws, size_t ws_size,
                              hipStream_t stream)
{
    const void* query = d_in[0];
    const void* key   = d_in[1];
    const void* value = d_in[2];
    const int*  mask  = (const int*)d_in[3];
    const void* Wq  = d_in[4];  const void* bq  = d_in[5];
    const void* Wk  = d_in[6];  const void* bk  = d_in[7];
    const void* Wv  = d_in[8];  const void* bv  = d_in[9];
    const void* Wo  = d_in[10]; const void* bo  = d_in[11];
    const void* Wkl = d_in[12]; const void* bkl = d_in[13];
    const void* Wql = d_in[14]; const void* bql = d_in[15];
    const void* Wq2 = d_in[16]; const void* bq2 = d_in[17];
    const void* Wvl = d_in[18]; const void* bvl = d_in[19];
    const void* Wel = d_in[20]; const void* bel = d_in[21];

    int* flag   = (int*)d_ws;
    int* tflags = (int*)d_ws + 4;                     // 64 ints
    u16* ws     = (u16*)((char*)d_ws + 512);
    const size_t BUF = (size_t)(B_ * S_) * DM_;       // 4M elems = 8 MB bf16
    u16* Kp  = ws + 0 * BUF;
    u16* krb = ws + 1 * BUF;
    u16* q1b = ws + 2 * BUF;
    u16* q2r = ws + 3 * BUF;
    u16* vrb = ws + 4 * BUF;
    u16* Om  = ws + 5 * BUF;
    u16* KpT = ws + 6 * BUF;
    u16* Qc  = ws + 7 * BUF;
    u16* Kc  = ws + 8 * BUF;
    u16* Vc  = ws + 9 * BUF;
    u16* Wbig = ws + 10 * BUF;
    u16* Wqc = Wbig + 0 * (size_t)(DM_ * DM_);
    u16* Wkc = Wbig + 1 * (size_t)(DM_ * DM_);
    u16* Wvc = Wbig + 2 * (size_t)(DM_ * DM_);
    u16* Woc = Wbig + 3 * (size_t)(DM_ * DM_);
    u16* Wsm = Wbig + 4 * (size_t)(DM_ * DM_);
    u16* Wklc = Wsm + 0 * (DK_ * DK_);
    u16* Wqlc = Wsm + 1 * (DK_ * DK_);
    u16* Welc = Wsm + 2 * (DK_ * DK_);
    u16* Wq2c = Wsm + 3 * (DK_ * DK_);
    u16* Wvlc = Wsm + 4 * (DK_ * DK_);

    const int M = B_ * S_;
    dim3 blk(256);

    detect_kernel<<<1, 64, 0, stream>>>((const u16*)query, flag);

    // fused mask-flag scan + dtype conversion
    hipMemsetAsync(tflags, 0, 64 * sizeof(int), stream);
    CvtArgs ca;
    const unsigned VIN = (unsigned)(BUF / 8);
    const unsigned VWB = (unsigned)(DM_ * DM_ / 8);
    const unsigned VWS = (unsigned)(DK_ * DK_ / 8);
    const void* srcs[NSEG] = {query, key, value, Wq, Wk, Wv, Wo, Wkl, Wql, Wel, Wq2, Wvl};
    void* dsts[NSEG] = {Qc, Kc, Vc, Wqc, Wkc, Wvc, Woc, Wklc, Wqlc, Welc, Wq2c, Wvlc};
    unsigned vcn[NSEG] = {VIN, VIN, VIN, VWB, VWB, VWB, VWB, VWS, VWS, VWS, VWS, VWS};
    unsigned off = 0;
    for (int i = 0; i < NSEG; ++i) { ca.src[i] = srcs[i]; ca.dst[i] = dsts[i]; ca.off[i] = off; off += vcn[i]; }
    ca.off[NSEG] = off;
    prep_kernel<<<dim3(512 + (off + 255) / 256), blk, 0, stream>>>(ca, off, flag, mask, tflags);

    // Q/K/V projections + fused per-head refinements (768 blocks)
    QKVArgs qa = {};
    qa.A0[0] = (const u16*)query; qa.A1[0] = Qc;
    qa.A0[1] = (const u16*)key;   qa.A1[1] = Kc;
    qa.A0[2] = (const u16*)value; qa.A1[2] = Vc;
    qa.W0[0] = (const u16*)Wq; qa.W1[0] = Wqc;
    qa.W0[1] = (const u16*)Wk; qa.W1[1] = Wkc;
    qa.W0[2] = (const u16*)Wv; qa.W1[2] = Wvc;
    qa.bias[0] = bq; qa.bias[1] = bk; qa.bias[2] = bv;
    qa.R10[0] = (const u16*)Wql; qa.R11[0] = Wqlc; qa.rb1[0] = bql;
    qa.R10[1] = (const u16*)Wkl; qa.R11[1] = Wklc; qa.rb1[1] = bkl;
    qa.R10[2] = (const u16*)Wvl; qa.R11[2] = Wvlc; qa.rb1[2] = bvl;
    qa.R20 = (const u16*)Wel; qa.R21 = Welc; qa.rb2 = bel;
    qa.R30 = (const u16*)Wq2; qa.R31 = Wq2c; qa.rb3 = bq2;
    qa.Kp = Kp; qa.q1b = q1b; qa.q2r = q2r; qa.krb = krb; qa.vrb = vrb;
    dim3 gBig(DM_ / 128, M / 128, 3);
    qkv_fused_kernel<<<gBig, blk, 0, stream>>>(qa, flag);

    // Kp -> per-head transposed copy
    dim3 gT(S_ / 64, H_, B_);
    transpose_kernel<<<gT, blk, 0, stream>>>(Kp, KpT);

    // fused attention -> merged (B,S,DM) layout (128 q-rows per block,
    // flat grid + XCD swizzle: one (b,h) pair's 8 q-blocks per XCD)
    attn_kernel<<<dim3(512), blk, 0, stream>>>(q1b, q2r, krb, vrb, KpT, mask, tflags, Om);

    // output projection -> d_out
    dim3 gO(DM_ / 128, M / 128);
    gemm_async_kernel<<<gO, blk, 0, stream>>>(Om, (const u16*)Wo, Woc, bo, d_out, flag);
}

// Round 7
// 280.086 us; speedup vs baseline: 1.3874x; 1.0355x over previous
//
#include <hip/hip_runtime.h>
#include <hip/hip_bf16.h>

#define B_  4
#define S_  1024
#define DM_ 1024
#define H_  16
#define DK_ 64

typedef unsigned short u16;
typedef __attribute__((ext_vector_type(8))) short bf16x8;
typedef __attribute__((ext_vector_type(4))) float f32x4;

__device__ __forceinline__ float bf2f(u16 u) {
    union { unsigned int i; float f; } c;
    c.i = ((unsigned int)u) << 16;
    return c.f;
}
__device__ __forceinline__ u16 f2bf(float f) {
    union { float f; unsigned int i; } c;
    c.f = f;
    unsigned int x = c.i;
    unsigned int lsb = (x >> 16) & 1u;
    x += 0x7fffu + lsb;          // round-to-nearest-even
    return (u16)(x >> 16);
}
__device__ __forceinline__ u16 f2bf_fast(float f) {
    __hip_bfloat16 h = __float2bfloat16(f);   // HW cvt, RNE
    return *reinterpret_cast<u16*>(&h);
}

// async global->LDS, 16B per lane; LDS dest = wave-uniform base + lane*16
__device__ __forceinline__ void async_ld16(const u16* g, u16* l) {
    __builtin_amdgcn_global_load_lds(
        (const __attribute__((address_space(1))) unsigned int*)(const void*)g,
        (__attribute__((address_space(3))) unsigned int*)(void*)l, 16, 0, 0);
}

// ---------------------------------------------------------------------------
// Runtime dtype detection (one wave). flag=1: inputs are fp32.
// ---------------------------------------------------------------------------
__global__ void detect_kernel(const u16* __restrict__ q, int* __restrict__ flag) {
    int lane = threadIdx.x & 63;
    int cnt = 0;
#pragma unroll
    for (int i = 0; i < 4; ++i) {
        u16 u = q[2 * (lane * 4 + i)];
        int e = (u >> 7) & 0xFF;
        cnt += (e >= 100 && e <= 140) ? 1 : 0;
    }
#pragma unroll
    for (int off = 1; off < 64; off <<= 1) cnt += __shfl_xor(cnt, off, 64);
    if (lane == 0) *flag = (cnt < 128) ? 1 : 0;
}

// ---------------------------------------------------------------------------
// Fused prep: blocks [0,512) scan mask -> per-(b,k64-tile) any-zero flags
// (tflags pre-zeroed via hipMemsetAsync; dirty -> atomicOr 1). Blocks >= 512
// do packed fp32->bf16 conversion (early-out when inputs already bf16).
// ---------------------------------------------------------------------------
#define NSEG 12
struct CvtArgs {
    const void* src[NSEG];
    void*       dst[NSEG];
    unsigned    off[NSEG + 1];
};

__global__ __launch_bounds__(256) void prep_kernel(
    CvtArgs a, unsigned total, const int* __restrict__ flag,
    const int* __restrict__ mask, int* __restrict__ tflags)
{
    const int tid = threadIdx.x;
    if (blockIdx.x < 512) {
        const int bx = blockIdx.x;
        const int kt = bx & 15, b = (bx >> 4) & 3, z = bx >> 6;
        int ok = 1;
#pragma unroll
        for (int i = tid; i < 128 * 16; i += 256) {
            int row = z * 128 + (i >> 4), seg = i & 15;
            int4 m = *(const int4*)&mask[((size_t)b * S_ + row) * S_ + kt * 64 + seg * 4];
            ok &= (m.x != 0) & (m.y != 0) & (m.z != 0) & (m.w != 0);
        }
        if (!ok) atomicOr(&tflags[b * 16 + kt], 1);
        return;
    }
    if (!*flag) return;   // bf16 inputs: GEMMs read originals directly
    unsigned v = (blockIdx.x - 512) * 256 + tid;
    if (v >= total) return;
    int s = 0;
    while (s < NSEG - 1 && v >= a.off[s + 1]) ++s;
    unsigned local = v - a.off[s];
    u16* dp = (u16*)a.dst[s] + (size_t)local * 8;
    const float* sp = (const float*)a.src[s] + (size_t)local * 8;
    float4 x = *(const float4*)sp, y = *(const float4*)(sp + 4);
    u16 t[8] = {f2bf(x.x), f2bf(x.y), f2bf(x.z), f2bf(x.w),
                f2bf(y.x), f2bf(y.y), f2bf(y.z), f2bf(y.w)};
    *(uint4*)dp = *(uint4*)t;
}

// ---------------------------------------------------------------------------
// Per-head transpose: Kp (b,s,h,d) -> KpT[((b*H+h)*DK + d)*S + s].
// ---------------------------------------------------------------------------
__global__ __launch_bounds__(256) void transpose_kernel(
    const u16* __restrict__ kp, u16* __restrict__ kpt)
{
    __shared__ u16 T[64][65];
    const int s0 = blockIdx.x * 64, h = blockIdx.y, b = blockIdx.z;
    const int tid = threadIdx.x;
    const size_t base = (size_t)b * S_ * DM_ + (size_t)h * DK_;
    for (int c = tid; c < 512; c += 256) {
        int row = c >> 3, cc = (c & 7) * 8;
        union { uint4 v; u16 u[8]; } x;
        x.v = *(const uint4*)&kp[base + (size_t)(s0 + row) * DM_ + cc];
#pragma unroll
        for (int j = 0; j < 8; ++j) T[row][cc + j] = x.u[j];
    }
    __syncthreads();
    const size_t baseT = (size_t)(b * H_ + h) * DK_ * S_;
    for (int c = tid; c < 512; c += 256) {
        int d = c >> 3, ss = (c & 7) * 8;
        u16 t[8];
#pragma unroll
        for (int j = 0; j < 8; ++j) t[j] = T[ss + j][d];
        *(uint4*)&kpt[baseT + (size_t)d * S_ + s0 + ss] = *(uint4*)t;
    }
}

// ---------------------------------------------------------------------------
// QKV projection + fused per-head refinements. 128x128 tile, BK=64, async
// global->LDS staging, XOR column-group swizzle (m97 structure). After the
// K-loop each wave's 64x64 quadrant is ONE head's complete column block for
// 64 rows, so the row-local 64x64 refinements run entirely in the epilogue:
// C-layout acc -> per-wave LDS region (A-layout swizzled) -> MFMA with
// weight B-frags read straight from global (L2-hot, shared across heads).
// z=0 (Q): emits q1b (Wql->Wel chain) + q2r. z=1 (K): Kp + krb. z=2: vrb.
// R16: launch_bounds (256,3)->(256,2). The 3-arg form capped VGPR at 84
// (R2's spill mapping); main-loop acc[4][4]=64 + epilogue r*[4][4] live set
// ~110 regs spilled ~46 MB scratch/dispatch (WRITE 86.5 vs 40 MB ideal).
// ---------------------------------------------------------------------------
struct QKVArgs {
    const u16* A0[3]; const u16* A1[3];
    const u16* W0[3]; const u16* W1[3];
    const void* bias[3];
    const u16* R10[3]; const u16* R11[3];   // Wql, Wkl, Wvl
    const void* rb1[3];                      // bql, bkl, bvl
    const u16* R20; const u16* R21; const void* rb2;   // Wel, bel
    const u16* R30; const u16* R31; const void* rb3;   // Wq2, bq2
    u16 *Kp, *q1b, *q2r, *krb, *vrb;
};

__global__ __launch_bounds__(256, 2) void qkv_fused_kernel(
    QKVArgs a, const int* __restrict__ flag)
{
    __shared__ __align__(16) u16 smem[16384];   // 32 KB: As+Ws; epilogue 4x8KB/wave
    u16 (*As)[64] = (u16(*)[64])smem;
    u16 (*Ws)[64] = (u16(*)[64])(smem + 8192);

    const int z = blockIdx.z;
    const int f = *flag;
    const u16* __restrict__ A = f ? a.A1[z] : a.A0[z];
    const u16* __restrict__ W = f ? a.W1[z] : a.W0[z];
    const void* biasp = a.bias[z];

    const int m0   = blockIdx.y * 128;
    const int n0   = blockIdx.x * 128;
    const int tid  = threadIdx.x;
    const int w    = tid >> 6;
    const int lane = tid & 63;
    const int l16  = lane & 15;
    const int quad = lane >> 4;
    const int wr   = (w >> 1) * 64;
    const int wc   = (w & 1) * 64;

    const int srow = lane >> 3;
    const int sgrp = (lane & 7) ^ srow;

    f32x4 acc[4][4];
#pragma unroll
    for (int rt = 0; rt < 4; ++rt)
#pragma unroll
        for (int ct = 0; ct < 4; ++ct) acc[rt][ct] = (f32x4){0.f, 0.f, 0.f, 0.f};

    for (int k0 = 0; k0 < DM_; k0 += 64) {
#pragma unroll
        for (int s = 0; s < 4; ++s) {
            int seg = w * 4 + s;
            async_ld16(&A[(size_t)(m0 + seg * 8 + srow) * DM_ + k0 + sgrp * 8],
                       &As[seg * 8][0]);
            async_ld16(&W[(size_t)(n0 + seg * 8 + srow) * DM_ + k0 + sgrp * 8],
                       &Ws[seg * 8][0]);
        }
        __syncthreads();
#pragma unroll
        for (int kk = 0; kk < 2; ++kk) {
            const int p = (kk * 4 + quad) ^ (l16 & 7);
            bf16x8 av[4], bv[4];
#pragma unroll
            for (int rt = 0; rt < 4; ++rt)
                av[rt] = *(const bf16x8*)&As[wr + rt * 16 + l16][p * 8];
#pragma unroll
            for (int ct = 0; ct < 4; ++ct)
                bv[ct] = *(const bf16x8*)&Ws[wc + ct * 16 + l16][p * 8];
#pragma unroll
            for (int rt = 0; rt < 4; ++rt)
#pragma unroll
                for (int ct = 0; ct < 4; ++ct)
                    acc[rt][ct] = __builtin_amdgcn_mfma_f32_16x16x32_bf16(
                        av[rt], bv[ct], acc[rt][ct], 0, 0, 0);
        }
        __syncthreads();   // trailing barrier: all waves done reading As/Ws
    }

    // ---- fused refinement epilogue (per-wave private LDS region) ----
    const int hcol = n0 + wc;                       // = head * 64
    u16 (*Es)[64] = (u16(*)[64])(smem + w * 4096);

    // projected tile (+bias, bf16) -> Es in A-layout swizzle; z==1 also -> Kp
#pragma unroll
    for (int ct = 0; ct < 4; ++ct) {
        int col = hcol + ct * 16 + l16;
        float bv = f ? ((const float*)biasp)[col] : bf2f(((const u16*)biasp)[col]);
#pragma unroll
        for (int rt = 0; rt < 4; ++rt)
#pragma unroll
            for (int r = 0; r < 4; ++r) {
                int ml = rt * 16 + quad * 4 + r;
                int cl = ct * 16 + l16;
                u16 bb = f2bf(acc[rt][ct][r] + bv);
                if (z == 1) a.Kp[(size_t)(m0 + wr + ml) * DM_ + col] = bb;
                Es[ml][((((cl >> 3) ^ (ml & 7)) << 3) | (cl & 7))] = bb;
            }
    }

    // A-frags of the projected tile (same-wave DS in-order; no barrier needed)
    bf16x8 af[4][2];
#pragma unroll
    for (int rt = 0; rt < 4; ++rt)
#pragma unroll
        for (int kk = 0; kk < 2; ++kk)
            af[rt][kk] = *(const bf16x8*)
                &Es[rt * 16 + l16][(((kk * 4 + quad) ^ (l16 & 7)) << 3)];

    // stage-1 weight B-frags from global (64x64, L2-hot)
    const u16* R1 = f ? a.R11[z] : a.R10[z];
    bf16x8 wb[2][4];
#pragma unroll
    for (int kk = 0; kk < 2; ++kk)
#pragma unroll
        for (int ct = 0; ct < 4; ++ct)
            wb[kk][ct] = *(const bf16x8*)
                &R1[(size_t)(ct * 16 + l16) * 64 + kk * 32 + quad * 8];

    f32x4 r1[4][4];
#pragma unroll
    for (int rt = 0; rt < 4; ++rt)
#pragma unroll
        for (int ct = 0; ct < 4; ++ct) r1[rt][ct] = (f32x4){0.f, 0.f, 0.f, 0.f};
#pragma unroll
    for (int kk = 0; kk < 2; ++kk)
#pragma unroll
        for (int rt = 0; rt < 4; ++rt)
#pragma unroll
            for (int ct = 0; ct < 4; ++ct)
                r1[rt][ct] = __builtin_amdgcn_mfma_f32_16x16x32_bf16(
                    af[rt][kk], wb[kk][ct], r1[rt][ct], 0, 0, 0);

    if (z != 0) {
        // single-stage: krb (z==1) or vrb (z==2) = relu(r1 + rb1)
        const void* rb = a.rb1[z];
        u16* out = (z == 1) ? a.krb : a.vrb;
#pragma unroll
        for (int ct = 0; ct < 4; ++ct) {
            int cl = ct * 16 + l16;
            float bv = f ? ((const float*)rb)[cl] : bf2f(((const u16*)rb)[cl]);
#pragma unroll
            for (int rt = 0; rt < 4; ++rt)
#pragma unroll
                for (int r = 0; r < 4; ++r) {
                    float v = r1[rt][ct][r] + bv;
                    v = v > 0.f ? v : 0.f;
                    out[(size_t)(m0 + wr + rt * 16 + quad * 4 + r) * DM_ + hcol + cl]
                        = f2bf(v);
                }
        }
    } else {
        // q1a = relu(r1 + bql) -> Es (round-trip for stage 2)
        {
            const void* rb = a.rb1[0];
#pragma unroll
            for (int ct = 0; ct < 4; ++ct) {
                int cl = ct * 16 + l16;
                float bv = f ? ((const float*)rb)[cl] : bf2f(((const u16*)rb)[cl]);
#pragma unroll
                for (int rt = 0; rt < 4; ++rt)
#pragma unroll
                    for (int r = 0; r < 4; ++r) {
                        float v = r1[rt][ct][r] + bv;
                        v = v > 0.f ? v : 0.f;
                        int ml = rt * 16 + quad * 4 + r;
                        Es[ml][((((cl >> 3) ^ (ml & 7)) << 3) | (cl & 7))] = f2bf(v);
                    }
            }
        }
        // q2r = relu(proj @ Wq2^T + bq2)  (reuses af while Es writes land)
        {
            const u16* R3 = f ? a.R31 : a.R30;
#pragma unroll
            for (int kk = 0; kk < 2; ++kk)
#pragma unroll
                for (int ct = 0; ct < 4; ++ct)
                    wb[kk][ct] = *(const bf16x8*)
                        &R3[(size_t)(ct * 16 + l16) * 64 + kk * 32 + quad * 8];
            f32x4 r3[4][4];
#pragma unroll
            for (int rt = 0; rt < 4; ++rt)
#pragma unroll
                for (int ct = 0; ct < 4; ++ct) r3[rt][ct] = (f32x4){0.f, 0.f, 0.f, 0.f};
#pragma unroll
            for (int kk = 0; kk < 2; ++kk)
#pragma unroll
                for (int rt = 0; rt < 4; ++rt)
#pragma unroll
                    for (int ct = 0; ct < 4; ++ct)
                        r3[rt][ct] = __builtin_amdgcn_mfma_f32_16x16x32_bf16(
                            af[rt][kk], wb[kk][ct], r3[rt][ct], 0, 0, 0);
            const void* rb = a.rb3;
#pragma unroll
            for (int ct = 0; ct < 4; ++ct) {
                int cl = ct * 16 + l16;
                float bv = f ? ((const float*)rb)[cl] : bf2f(((const u16*)rb)[cl]);
#pragma unroll
                for (int rt = 0; rt < 4; ++rt)
#pragma unroll
                    for (int r = 0; r < 4; ++r) {
                        float v = r3[rt][ct][r] + bv;
                        v = v > 0.f ? v : 0.f;
                        a.q2r[(size_t)(m0 + wr + rt * 16 + quad * 4 + r) * DM_
                              + hcol + cl] = f2bf(v);
                    }
            }
        }
        // q1b = relu(q1a @ Wel^T + bel)
        {
#pragma unroll
            for (int rt = 0; rt < 4; ++rt)
#pragma unroll
                for (int kk = 0; kk < 2; ++kk)
                    af[rt][kk] = *(const bf16x8*)
                        &Es[rt * 16 + l16][(((kk * 4 + quad) ^ (l16 & 7)) << 3)];
            const u16* R2 = f ? a.R21 : a.R20;
#pragma unroll
            for (int kk = 0; kk < 2; ++kk)
#pragma unroll
                for (int ct = 0; ct < 4; ++ct)
                    wb[kk][ct] = *(const bf16x8*)
                        &R2[(size_t)(ct * 16 + l16) * 64 + kk * 32 + quad * 8];
            f32x4 r2[4][4];
#pragma unroll
            for (int rt = 0; rt < 4; ++rt)
#pragma unroll
                for (int ct = 0; ct < 4; ++ct) r2[rt][ct] = (f32x4){0.f, 0.f, 0.f, 0.f};
#pragma unroll
            for (int kk = 0; kk < 2; ++kk)
#pragma unroll
                for (int rt = 0; rt < 4; ++rt)
#pragma unroll
                    for (int ct = 0; ct < 4; ++ct)
                        r2[rt][ct] = __builtin_amdgcn_mfma_f32_16x16x32_bf16(
                            af[rt][kk], wb[kk][ct], r2[rt][ct], 0, 0, 0);
            const void* rb = a.rb2;
#pragma unroll
            for (int ct = 0; ct < 4; ++ct) {
                int cl = ct * 16 + l16;
                float bv = f ? ((const float*)rb)[cl] : bf2f(((const u16*)rb)[cl]);
#pragma unroll
                for (int rt = 0; rt < 4; ++rt)
#pragma unroll
                    for (int r = 0; r < 4; ++r) {
                        float v = r2[rt][ct][r] + bv;
                        v = v > 0.f ? v : 0.f;
                        a.q1b[(size_t)(m0 + wr + rt * 16 + quad * 4 + r) * DM_
                              + hcol + cl] = f2bf(v);
                    }
            }
        }
    }
}

// ---------------------------------------------------------------------------
// Output-projection GEMM (m97 structure), dtype-dynamic bias/out.
// R16: (256,3)->(256,2) — same spill fix as qkv (acc 64 + av/bv 32 live).
// ---------------------------------------------------------------------------
__global__ __launch_bounds__(256, 2) void gemm_async_kernel(
    const u16* __restrict__ Ain, const u16* __restrict__ W0,
    const u16* __restrict__ W1, const void* __restrict__ biasp,
    void* __restrict__ Cp, const int* __restrict__ flag)
{
    __shared__ __align__(16) u16 As[128][64];
    __shared__ __align__(16) u16 Ws[128][64];

    const int f = *flag;
    const u16* __restrict__ W = f ? W1 : W0;

    const int m0   = blockIdx.y * 128;
    const int n0   = blockIdx.x * 128;
    const int tid  = threadIdx.x;
    const int w    = tid >> 6;
    const int lane = tid & 63;
    const int l16  = lane & 15;
    const int quad = lane >> 4;
    const int wr   = (w >> 1) * 64;
    const int wc   = (w & 1) * 64;

    const int srow = lane >> 3;
    const int sgrp = (lane & 7) ^ srow;

    f32x4 acc[4][4];
#pragma unroll
    for (int rt = 0; rt < 4; ++rt)
#pragma unroll
        for (int ct = 0; ct < 4; ++ct) acc[rt][ct] = (f32x4){0.f, 0.f, 0.f, 0.f};

    for (int k0 = 0; k0 < DM_; k0 += 64) {
#pragma unroll
        for (int s = 0; s < 4; ++s) {
            int seg = w * 4 + s;
            async_ld16(&Ain[(size_t)(m0 + seg * 8 + srow) * DM_ + k0 + sgrp * 8],
                       &As[seg * 8][0]);
            async_ld16(&W[(size_t)(n0 + seg * 8 + srow) * DM_ + k0 + sgrp * 8],
                       &Ws[seg * 8][0]);
        }
        __syncthreads();
#pragma unroll
        for (int kk = 0; kk < 2; ++kk) {
            const int p = (kk * 4 + quad) ^ (l16 & 7);
            bf16x8 av[4], bv[4];
#pragma unroll
            for (int rt = 0; rt < 4; ++rt)
                av[rt] = *(const bf16x8*)&As[wr + rt * 16 + l16][p * 8];
#pragma unroll
            for (int ct = 0; ct < 4; ++ct)
                bv[ct] = *(const bf16x8*)&Ws[wc + ct * 16 + l16][p * 8];
#pragma unroll
            for (int rt = 0; rt < 4; ++rt)
#pragma unroll
                for (int ct = 0; ct < 4; ++ct)
                    acc[rt][ct] = __builtin_amdgcn_mfma_f32_16x16x32_bf16(
                        av[rt], bv[ct], acc[rt][ct], 0, 0, 0);
        }
        __syncthreads();
    }

#pragma unroll
    for (int ct = 0; ct < 4; ++ct) {
        int col = n0 + wc + ct * 16 + l16;
        float bv = f ? ((const float*)biasp)[col] : bf2f(((const u16*)biasp)[col]);
#pragma unroll
        for (int rt = 0; rt < 4; ++rt)
#pragma unroll
            for (int r = 0; r < 4; ++r) {
                int row = m0 + wr + rt * 16 + quad * 4 + r;
                float v = acc[rt][ct][r] + bv;
                size_t idx = (size_t)row * DM_ + col;
                if (f) ((float*)Cp)[idx] = v;
                else   ((u16*)Cp)[idx]   = f2bf(v);
            }
    }
}

// ---------------------------------------------------------------------------
// Fused attention, R15 (unchanged): DMA staging, 1 barrier/tile, XCD swizzle,
// setprio, SWAPPED QK^T (row-local softmax: in-lane folds + 2 shfl_xor).
// ---------------------------------------------------------------------------
__global__ __launch_bounds__(256, 2) void attn_kernel(
    const u16* __restrict__ q1, const u16* __restrict__ q2,
    const u16* __restrict__ kr, const u16* __restrict__ vr,
    const u16* __restrict__ kpt, const int* __restrict__ mask,
    const int* __restrict__ tflags, u16* __restrict__ om)
{
    __shared__ __align__(16) u16 krs[2][64][64];
    __shared__ __align__(16) u16 vrs[2][64][64];
    __shared__ __align__(16) u16 kts[2][64][64];   // KpT tile: rows d, cols k
    __shared__ __align__(16) u16 pts[4][32][72];   // per-wave P~ staging

    // bijective XCD swizzle: hw XCD = bid%8; XCD x gets orig ids x*64..x*64+63
    // = (b,h) pairs 8x..8x+7 complete (8 q-tiles each).
    const int bid  = blockIdx.x;                  // 0..511 flat
    const int orig = (bid & 7) * 64 + (bid >> 3);
    const int qt = orig & 7;
    const int h  = (orig >> 3) & 15;
    const int b  = orig >> 7;

    const int q0   = qt * 128;
    const int tid  = threadIdx.x;
    const int w    = tid >> 6;
    const int lane = tid & 63;
    const int l16  = lane & 15;
    const int quad = lane >> 4;

    const size_t base  = (size_t)b * S_ * DM_ + (size_t)h * DK_;
    const size_t baseT = (size_t)(b * H_ + h) * DK_ * S_;

    // staging lane coords (qkv pattern): row-in-segment + XOR'd col group
    const int srow = lane >> 3;                  // 0..7
    const int sgrp = (lane & 7) ^ srow;          // swizzled source col group

    // issue 6 global_load_lds per wave covering 24 segments of 8 rows:
    // flat seg s = w*6+i; tile t = s/8 (0:krs 1:vrs 2:kts); r8 = (s%8)*8.
#define STAGE_TILES(buf, kn)                                                   \
    {                                                                          \
        _Pragma("unroll")                                                      \
        for (int i = 0; i < 6; ++i) {                                          \
            int s_ = w * 6 + i;                                                \
            int t_ = s_ >> 3;                                                  \
            int r8 = (s_ & 7) * 8;                                             \
            if (t_ == 0)                                                       \
                async_ld16(&kr[base + (size_t)((kn) + r8 + srow) * DM_ +       \
                               sgrp * 8], &krs[buf][r8][0]);                   \
            else if (t_ == 1)                                                  \
                async_ld16(&vr[base + (size_t)((kn) + r8 + srow) * DM_ +       \
                               sgrp * 8], &vrs[buf][r8][0]);                   \
            else                                                               \
                async_ld16(&kpt[baseT + (size_t)(r8 + srow) * S_ + (kn) +      \
                                sgrp * 8], &kts[buf][r8][0]);                  \
        }                                                                      \
    }

    bf16x8 a1[2][2], a2[2][2];
#pragma unroll
    for (int rt = 0; rt < 2; ++rt) {
        const int qrow = q0 + w * 32 + rt * 16 + l16;
#pragma unroll
        for (int kk = 0; kk < 2; ++kk) {
            a1[rt][kk] = *(const bf16x8*)&q1[base + (size_t)qrow * DM_ + kk * 32 + quad * 8];
            a2[rt][kk] = *(const bf16x8*)&q2[base + (size_t)qrow * DM_ + kk * 32 + quad * 8];
        }
    }

    // softmax state: per qt half, this lane owns q = qt*16 + l16
    float m_run[2], l_run[2];
    f32x4 oacc[2][4];
#pragma unroll
    for (int qt2 = 0; qt2 < 2; ++qt2) { m_run[qt2] = -1e30f; l_run[qt2] = 0.f; }
#pragma unroll
    for (int rt = 0; rt < 2; ++rt)
#pragma unroll
        for (int ct = 0; ct < 4; ++ct) oacc[rt][ct] = (f32x4){0.f, 0.f, 0.f, 0.f};

    // ---- prologue: stage tile 0 into buffer 0 (barrier drains vmcnt) ----
    STAGE_TILES(0, 0)
    __syncthreads();

    for (int kt = 0; kt < S_ / 64; ++kt) {
        const int cur = kt & 1;
        const int k0  = kt * 64;
        const bool pf = (kt + 1 < S_ / 64);

        // issue next-tile DMA first — lands during compute, drained by barrier
        if (pf) STAGE_TILES(cur ^ 1, k0 + 64)

        const int tf = tflags[b * 16 + kt];

        // st[qt][kt4] = D[k][q]: row k = kt4*16 + quad*4 + r, col q = qt*16+l16
        f32x4 st1[2][4], st2[2][4];
#pragma unroll
        for (int qt2 = 0; qt2 < 2; ++qt2)
#pragma unroll
            for (int kt4 = 0; kt4 < 4; ++kt4) {
                st1[qt2][kt4] = (f32x4){0.f, 0.f, 0.f, 0.f};
                st2[qt2][kt4] = (f32x4){0.f, 0.f, 0.f, 0.f};
            }
        __builtin_amdgcn_s_setprio(1);
#pragma unroll
        for (int kk = 0; kk < 2; ++kk) {
            const int p = ((kk * 4 + quad) ^ (l16 & 7)) * 8;
            bf16x8 b1[4], b2[4];
#pragma unroll
            for (int kt4 = 0; kt4 < 4; ++kt4) {
                b1[kt4] = *(const bf16x8*)&krs[cur][kt4 * 16 + l16][p];
                b2[kt4] = *(const bf16x8*)&vrs[cur][kt4 * 16 + l16][p];
            }
            // SWAPPED operand order: A=K/V rows (k), B=Q rows (q)
#pragma unroll
            for (int qt2 = 0; qt2 < 2; ++qt2)
#pragma unroll
                for (int kt4 = 0; kt4 < 4; ++kt4) {
                    st1[qt2][kt4] = __builtin_amdgcn_mfma_f32_16x16x32_bf16(
                        b1[kt4], a1[qt2][kk], st1[qt2][kt4], 0, 0, 0);
                    st2[qt2][kt4] = __builtin_amdgcn_mfma_f32_16x16x32_bf16(
                        b2[kt4], a2[qt2][kk], st2[qt2][kt4], 0, 0, 0);
                }
        }
        __builtin_amdgcn_s_setprio(0);

        if (tf) {
#pragma unroll
            for (int qt2 = 0; qt2 < 2; ++qt2)
#pragma unroll
                for (int kt4 = 0; kt4 < 4; ++kt4)
#pragma unroll
                    for (int r = 0; r < 4; ++r) {
                        int qrow = q0 + w * 32 + qt2 * 16 + l16;
                        int kc   = k0 + kt4 * 16 + quad * 4 + r;
                        if (mask[((size_t)b * S_ + qrow) * S_ + kc] == 0)
                            st1[qt2][kt4][r] = -1e9f;
                    }
        }

        // ---- row-local softmax: in-lane fold + 2 shfl_xor per quantity ----
        float alphaq[2], newm[2];
#pragma unroll
        for (int qt2 = 0; qt2 < 2; ++qt2) {
            float m = st1[qt2][0][0];
#pragma unroll
            for (int kt4 = 0; kt4 < 4; ++kt4)
#pragma unroll
                for (int r = 0; r < 4; ++r)
                    m = fmaxf(m, st1[qt2][kt4][r]);
            m = fmaxf(m, __shfl_xor(m, 16, 64));
            m = fmaxf(m, __shfl_xor(m, 32, 64));
            newm[qt2]   = fmaxf(m_run[qt2], m);
            alphaq[qt2] = __expf(m_run[qt2] - newm[qt2]);
            m_run[qt2]  = newm[qt2];
        }

#pragma unroll
        for (int qt2 = 0; qt2 < 2; ++qt2) {
            float s = 0.f;
#pragma unroll
            for (int kt4 = 0; kt4 < 4; ++kt4)
#pragma unroll
                for (int pp = 0; pp < 2; ++pp) {
                    float p0 = __expf(st1[qt2][kt4][2 * pp]     - newm[qt2]);
                    float p1 = __expf(st1[qt2][kt4][2 * pp + 1] - newm[qt2]);
                    s += p0 + p1;
                    unsigned u = (unsigned)f2bf_fast(p0 * st2[qt2][kt4][2 * pp])
                               | ((unsigned)f2bf_fast(p1 * st2[qt2][kt4][2 * pp + 1]) << 16);
                    *(unsigned*)&pts[w][qt2 * 16 + l16][kt4 * 16 + quad * 4 + 2 * pp] = u;
                }
            s += __shfl_xor(s, 16, 64);
            s += __shfl_xor(s, 32, 64);
            l_run[qt2] = l_run[qt2] * alphaq[qt2] + s;
        }

        // oacc rescale: broadcast alpha from softmax layout (q=l16) to
        // C-layout rows (q=quad*4+r); value uniform across source quads.
#pragma unroll
        for (int rt = 0; rt < 2; ++rt)
#pragma unroll
            for (int r = 0; r < 4; ++r) {
                float ao = __shfl(alphaq[rt], quad * 4 + r, 64);
#pragma unroll
                for (int ct = 0; ct < 4; ++ct) oacc[rt][ct][r] *= ao;
            }

        {
            __builtin_amdgcn_s_setprio(1);
            bf16x8 bb[2][4];
#pragma unroll
            for (int kk = 0; kk < 2; ++kk) {
                const int p = ((kk * 4 + quad) ^ (l16 & 7)) * 8;
#pragma unroll
                for (int ct = 0; ct < 4; ++ct)
                    bb[kk][ct] = *(const bf16x8*)&kts[cur][ct * 16 + l16][p];
            }
#pragma unroll
            for (int rt = 0; rt < 2; ++rt)
#pragma unroll
                for (int kk = 0; kk < 2; ++kk) {
                    // per-wave DS in-order: reads see this wave's pts writes
                    bf16x8 a = *(const bf16x8*)&pts[w][rt * 16 + l16][kk * 32 + quad * 8];
#pragma unroll
                    for (int ct = 0; ct < 4; ++ct)
                        oacc[rt][ct] = __builtin_amdgcn_mfma_f32_16x16x32_bf16(
                            a, bb[kk][ct], oacc[rt][ct], 0, 0, 0);
                }
            __builtin_amdgcn_s_setprio(0);
        }

        // barrier releases next buffer (drains the in-flight DMA)
        if (pf) __syncthreads();
    }

#pragma unroll
    for (int rt = 0; rt < 2; ++rt)
#pragma unroll
        for (int r = 0; r < 4; ++r) {
            float lo = __shfl(l_run[rt], quad * 4 + r, 64);
            float inv = 1.f / lo;
#pragma unroll
            for (int ct = 0; ct < 4; ++ct) {
                int row = q0 + w * 32 + rt * 16 + quad * 4 + r;
                int col = ct * 16 + l16;
                om[base + (size_t)row * DM_ + col] = f2bf_fast(oacc[rt][ct][r] * inv);
            }
        }
#undef STAGE_TILES
}

// ---------------------------------------------------------------------------
extern "C" void kernel_launch(void* const* d_in, const int* in_sizes, int n_in,
                              void* d_out, int out_size, void* d_ws, size_t ws_size,
                              hipStream_t stream)
{
    const void* query = d_in[0];
    const void* key   = d_in[1];
    const void* value = d_in[2];
    const int*  mask  = (const int*)d_in[3];
    const void* Wq  = d_in[4];  const void* bq  = d_in[5];
    const void* Wk  = d_in[6];  const void* bk  = d_in[7];
    const void* Wv  = d_in[8];  const void* bv  = d_in[9];
    const void* Wo  = d_in[10]; const void* bo  = d_in[11];
    const void* Wkl = d_in[12]; const void* bkl = d_in[13];
    const void* Wql = d_in[14]; const void* bql = d_in[15];
    const void* Wq2 = d_in[16]; const void* bq2 = d_in[17];
    const void* Wvl = d_in[18]; const void* bvl = d_in[19];
    const void* Wel = d_in[20]; const void* bel = d_in[21];

    int* flag   = (int*)d_ws;
    int* tflags = (int*)d_ws + 4;                     // 64 ints
    u16* ws     = (u16*)((char*)d_ws + 512);
    const size_t BUF = (size_t)(B_ * S_) * DM_;       // 4M elems = 8 MB bf16
    u16* Kp  = ws + 0 * BUF;
    u16* krb = ws + 1 * BUF;
    u16* q1b = ws + 2 * BUF;
    u16* q2r = ws + 3 * BUF;
    u16* vrb = ws + 4 * BUF;
    u16* Om  = ws + 5 * BUF;
    u16* KpT = ws + 6 * BUF;
    u16* Qc  = ws + 7 * BUF;
    u16* Kc  = ws + 8 * BUF;
    u16* Vc  = ws + 9 * BUF;
    u16* Wbig = ws + 10 * BUF;
    u16* Wqc = Wbig + 0 * (size_t)(DM_ * DM_);
    u16* Wkc = Wbig + 1 * (size_t)(DM_ * DM_);
    u16* Wvc = Wbig + 2 * (size_t)(DM_ * DM_);
    u16* Woc = Wbig + 3 * (size_t)(DM_ * DM_);
    u16* Wsm = Wbig + 4 * (size_t)(DM_ * DM_);
    u16* Wklc = Wsm + 0 * (DK_ * DK_);
    u16* Wqlc = Wsm + 1 * (DK_ * DK_);
    u16* Welc = Wsm + 2 * (DK_ * DK_);
    u16* Wq2c = Wsm + 3 * (DK_ * DK_);
    u16* Wvlc = Wsm + 4 * (DK_ * DK_);

    const int M = B_ * S_;
    dim3 blk(256);

    detect_kernel<<<1, 64, 0, stream>>>((const u16*)query, flag);

    // fused mask-flag scan + dtype conversion
    hipMemsetAsync(tflags, 0, 64 * sizeof(int), stream);
    CvtArgs ca;
    const unsigned VIN = (unsigned)(BUF / 8);
    const unsigned VWB = (unsigned)(DM_ * DM_ / 8);
    const unsigned VWS = (unsigned)(DK_ * DK_ / 8);
    const void* srcs[NSEG] = {query, key, value, Wq, Wk, Wv, Wo, Wkl, Wql, Wel, Wq2, Wvl};
    void* dsts[NSEG] = {Qc, Kc, Vc, Wqc, Wkc, Wvc, Woc, Wklc, Wqlc, Welc, Wq2c, Wvlc};
    unsigned vcn[NSEG] = {VIN, VIN, VIN, VWB, VWB, VWB, VWB, VWS, VWS, VWS, VWS, VWS};
    unsigned off = 0;
    for (int i = 0; i < NSEG; ++i) { ca.src[i] = srcs[i]; ca.dst[i] = dsts[i]; ca.off[i] = off; off += vcn[i]; }
    ca.off[NSEG] = off;
    prep_kernel<<<dim3(512 + (off + 255) / 256), blk, 0, stream>>>(ca, off, flag, mask, tflags);

    // Q/K/V projections + fused per-head refinements (768 blocks)
    QKVArgs qa = {};
    qa.A0[0] = (const u16*)query; qa.A1[0] = Qc;
    qa.A0[1] = (const u16*)key;   qa.A1[1] = Kc;
    qa.A0[2] = (const u16*)value; qa.A1[2] = Vc;
    qa.W0[0] = (const u16*)Wq; qa.W1[0] = Wqc;
    qa.W0[1] = (const u16*)Wk; qa.W1[1] = Wkc;
    qa.W0[2] = (const u16*)Wv; qa.W1[2] = Wvc;
    qa.bias[0] = bq; qa.bias[1] = bk; qa.bias[2] = bv;
    qa.R10[0] = (const u16*)Wql; qa.R11[0] = Wqlc; qa.rb1[0] = bql;
    qa.R10[1] = (const u16*)Wkl; qa.R11[1] = Wklc; qa.rb1[1] = bkl;
    qa.R10[2] = (const u16*)Wvl; qa.R11[2] = Wvlc; qa.rb1[2] = bvl;
    qa.R20 = (const u16*)Wel; qa.R21 = Welc; qa.rb2 = bel;
    qa.R30 = (const u16*)Wq2; qa.R31 = Wq2c; qa.rb3 = bq2;
    qa.Kp = Kp; qa.q1b = q1b; qa.q2r = q2r; qa.krb = krb; qa.vrb = vrb;
    dim3 gBig(DM_ / 128, M / 128, 3);
    qkv_fused_kernel<<<gBig, blk, 0, stream>>>(qa, flag);

    // Kp -> per-head transposed copy
    dim3 gT(S_ / 64, H_, B_);
    transpose_kernel<<<gT, blk, 0, stream>>>(Kp, KpT);

    // fused attention -> merged (B,S,DM) layout (128 q-rows per block,
    // flat grid + XCD swizzle: one (b,h) pair's 8 q-blocks per XCD)
    attn_kernel<<<dim3(512), blk, 0, stream>>>(q1b, q2r, krb, vrb, KpT, mask, tflags, Om);

    // output projection -> d_out
    dim3 gO(DM_ / 128, M / 128);
    gemm_async_kernel<<<gO, blk, 0, stream>>>(Om, (const u16*)Wo, Woc, bo, d_out, flag);
}

// Round 8
// 273.120 us; speedup vs baseline: 1.4228x; 1.0255x over previous
//
#include <hip/hip_runtime.h>
#include <hip/hip_bf16.h>

#define B_  4
#define S_  1024
#define DM_ 1024
#define H_  16
#define DK_ 64

typedef unsigned short u16;
typedef __attribute__((ext_vector_type(8))) short bf16x8;
typedef __attribute__((ext_vector_type(4))) float f32x4;

__device__ __forceinline__ float bf2f(u16 u) {
    union { unsigned int i; float f; } c;
    c.i = ((unsigned int)u) << 16;
    return c.f;
}
__device__ __forceinline__ u16 f2bf(float f) {
    union { float f; unsigned int i; } c;
    c.f = f;
    unsigned int x = c.i;
    unsigned int lsb = (x >> 16) & 1u;
    x += 0x7fffu + lsb;          // round-to-nearest-even
    return (u16)(x >> 16);
}
__device__ __forceinline__ u16 f2bf_fast(float f) {
    __hip_bfloat16 h = __float2bfloat16(f);   // HW cvt, RNE
    return *reinterpret_cast<u16*>(&h);
}

// async global->LDS, 16B per lane; LDS dest = wave-uniform base + lane*16
__device__ __forceinline__ void async_ld16(const u16* g, u16* l) {
    __builtin_amdgcn_global_load_lds(
        (const __attribute__((address_space(1))) unsigned int*)(const void*)g,
        (__attribute__((address_space(3))) unsigned int*)(void*)l, 16, 0, 0);
}

// ---------------------------------------------------------------------------
// Runtime dtype detection (one wave). flag=1: inputs are fp32.
// ---------------------------------------------------------------------------
__global__ void detect_kernel(const u16* __restrict__ q, int* __restrict__ flag) {
    int lane = threadIdx.x & 63;
    int cnt = 0;
#pragma unroll
    for (int i = 0; i < 4; ++i) {
        u16 u = q[2 * (lane * 4 + i)];
        int e = (u >> 7) & 0xFF;
        cnt += (e >= 100 && e <= 140) ? 1 : 0;
    }
#pragma unroll
    for (int off = 1; off < 64; off <<= 1) cnt += __shfl_xor(cnt, off, 64);
    if (lane == 0) *flag = (cnt < 128) ? 1 : 0;
}

// ---------------------------------------------------------------------------
// Fused prep: blocks [0,512) scan mask -> per-(b,k64-tile) any-zero flags
// (tflags pre-zeroed via hipMemsetAsync; dirty -> atomicOr 1). Blocks >= 512
// do packed fp32->bf16 conversion (early-out when inputs already bf16).
// ---------------------------------------------------------------------------
#define NSEG 12
struct CvtArgs {
    const void* src[NSEG];
    void*       dst[NSEG];
    unsigned    off[NSEG + 1];
};

__global__ __launch_bounds__(256) void prep_kernel(
    CvtArgs a, unsigned total, const int* __restrict__ flag,
    const int* __restrict__ mask, int* __restrict__ tflags)
{
    const int tid = threadIdx.x;
    if (blockIdx.x < 512) {
        const int bx = blockIdx.x;
        const int kt = bx & 15, b = (bx >> 4) & 3, z = bx >> 6;
        int ok = 1;
#pragma unroll
        for (int i = tid; i < 128 * 16; i += 256) {
            int row = z * 128 + (i >> 4), seg = i & 15;
            int4 m = *(const int4*)&mask[((size_t)b * S_ + row) * S_ + kt * 64 + seg * 4];
            ok &= (m.x != 0) & (m.y != 0) & (m.z != 0) & (m.w != 0);
        }
        if (!ok) atomicOr(&tflags[b * 16 + kt], 1);
        return;
    }
    if (!*flag) return;   // bf16 inputs: GEMMs read originals directly
    unsigned v = (blockIdx.x - 512) * 256 + tid;
    if (v >= total) return;
    int s = 0;
    while (s < NSEG - 1 && v >= a.off[s + 1]) ++s;
    unsigned local = v - a.off[s];
    u16* dp = (u16*)a.dst[s] + (size_t)local * 8;
    const float* sp = (const float*)a.src[s] + (size_t)local * 8;
    float4 x = *(const float4*)sp, y = *(const float4*)(sp + 4);
    u16 t[8] = {f2bf(x.x), f2bf(x.y), f2bf(x.z), f2bf(x.w),
                f2bf(y.x), f2bf(y.y), f2bf(y.z), f2bf(y.w)};
    *(uint4*)dp = *(uint4*)t;
}

// ---------------------------------------------------------------------------
// QKV projection + fused per-head refinements. 128x128 tile, BK=64, async
// global->LDS staging, XOR column-group swizzle (m97 structure). After the
// K-loop each wave's 64x64 quadrant is ONE head's complete column block for
// 64 rows, so the row-local 64x64 refinements run entirely in the epilogue:
// C-layout acc -> per-wave LDS region (A-layout swizzled) -> MFMA with
// weight B-frags read straight from global (L2-hot, shared across heads).
// z=0 (Q): emits q1b (Wql->Wel chain) + q2r. z=1 (K): KpT + krb. z=2: vrb.
// R17: transpose_kernel FUSED AWAY — z=1 writes KpT[((b*H+h)*DK+d)*S+s]
// directly via packed 8B stores (r-loop is contiguous in s). Drops the Kp
// 8MB scalar-store pass + 16MB transpose kernel + one launch.
// ---------------------------------------------------------------------------
struct QKVArgs {
    const u16* A0[3]; const u16* A1[3];
    const u16* W0[3]; const u16* W1[3];
    const void* bias[3];
    const u16* R10[3]; const u16* R11[3];   // Wql, Wkl, Wvl
    const void* rb1[3];                      // bql, bkl, bvl
    const u16* R20; const u16* R21; const void* rb2;   // Wel, bel
    const u16* R30; const u16* R31; const void* rb3;   // Wq2, bq2
    u16 *KpT, *q1b, *q2r, *krb, *vrb;
};

__global__ __launch_bounds__(256, 2) void qkv_fused_kernel(
    QKVArgs a, const int* __restrict__ flag)
{
    __shared__ __align__(16) u16 smem[16384];   // 32 KB: As+Ws; epilogue 4x8KB/wave
    u16 (*As)[64] = (u16(*)[64])smem;
    u16 (*Ws)[64] = (u16(*)[64])(smem + 8192);

    const int z = blockIdx.z;
    const int f = *flag;
    const u16* __restrict__ A = f ? a.A1[z] : a.A0[z];
    const u16* __restrict__ W = f ? a.W1[z] : a.W0[z];
    const void* biasp = a.bias[z];

    const int m0   = blockIdx.y * 128;
    const int n0   = blockIdx.x * 128;
    const int tid  = threadIdx.x;
    const int w    = tid >> 6;
    const int lane = tid & 63;
    const int l16  = lane & 15;
    const int quad = lane >> 4;
    const int wr   = (w >> 1) * 64;
    const int wc   = (w & 1) * 64;

    const int srow = lane >> 3;
    const int sgrp = (lane & 7) ^ srow;

    f32x4 acc[4][4];
#pragma unroll
    for (int rt = 0; rt < 4; ++rt)
#pragma unroll
        for (int ct = 0; ct < 4; ++ct) acc[rt][ct] = (f32x4){0.f, 0.f, 0.f, 0.f};

    for (int k0 = 0; k0 < DM_; k0 += 64) {
#pragma unroll
        for (int s = 0; s < 4; ++s) {
            int seg = w * 4 + s;
            async_ld16(&A[(size_t)(m0 + seg * 8 + srow) * DM_ + k0 + sgrp * 8],
                       &As[seg * 8][0]);
            async_ld16(&W[(size_t)(n0 + seg * 8 + srow) * DM_ + k0 + sgrp * 8],
                       &Ws[seg * 8][0]);
        }
        __syncthreads();
#pragma unroll
        for (int kk = 0; kk < 2; ++kk) {
            const int p = (kk * 4 + quad) ^ (l16 & 7);
            bf16x8 av[4], bv[4];
#pragma unroll
            for (int rt = 0; rt < 4; ++rt)
                av[rt] = *(const bf16x8*)&As[wr + rt * 16 + l16][p * 8];
#pragma unroll
            for (int ct = 0; ct < 4; ++ct)
                bv[ct] = *(const bf16x8*)&Ws[wc + ct * 16 + l16][p * 8];
#pragma unroll
            for (int rt = 0; rt < 4; ++rt)
#pragma unroll
                for (int ct = 0; ct < 4; ++ct)
                    acc[rt][ct] = __builtin_amdgcn_mfma_f32_16x16x32_bf16(
                        av[rt], bv[ct], acc[rt][ct], 0, 0, 0);
        }
        __syncthreads();   // trailing barrier: all waves done reading As/Ws
    }

    // ---- fused refinement epilogue (per-wave private LDS region) ----
    const int hcol = n0 + wc;                       // = head * 64
    u16 (*Es)[64] = (u16(*)[64])(smem + w * 4096);

    // projected tile (+bias, bf16) -> Es in A-layout swizzle; z==1 also -> KpT
    // (packed: r-loop is contiguous in s after the transpose, 8B per store)
#pragma unroll
    for (int ct = 0; ct < 4; ++ct) {
        int col = hcol + ct * 16 + l16;
        float bv = f ? ((const float*)biasp)[col] : bf2f(((const u16*)biasp)[col]);
#pragma unroll
        for (int rt = 0; rt < 4; ++rt) {
            u16 pk[4];
#pragma unroll
            for (int r = 0; r < 4; ++r) {
                int ml = rt * 16 + quad * 4 + r;
                int cl = ct * 16 + l16;
                u16 bb = f2bf(acc[rt][ct][r] + bv);
                pk[r] = bb;
                Es[ml][((((cl >> 3) ^ (ml & 7)) << 3) | (cl & 7))] = bb;
            }
            if (z == 1) {
                int mg = m0 + wr + rt * 16 + quad * 4;    // global row, 4-aligned
                int b_ = mg >> 10, s_ = mg & 1023;
                int h_ = hcol >> 6, d_ = ct * 16 + l16;
                size_t idx = ((size_t)(b_ * H_ + h_) * DK_ + d_) * S_ + s_;
                *(uint2*)&a.KpT[idx] = *(const uint2*)pk;
            }
        }
    }

    // A-frags of the projected tile (same-wave DS in-order; no barrier needed)
    bf16x8 af[4][2];
#pragma unroll
    for (int rt = 0; rt < 4; ++rt)
#pragma unroll
        for (int kk = 0; kk < 2; ++kk)
            af[rt][kk] = *(const bf16x8*)
                &Es[rt * 16 + l16][(((kk * 4 + quad) ^ (l16 & 7)) << 3)];

    // stage-1 weight B-frags from global (64x64, L2-hot)
    const u16* R1 = f ? a.R11[z] : a.R10[z];
    bf16x8 wb[2][4];
#pragma unroll
    for (int kk = 0; kk < 2; ++kk)
#pragma unroll
        for (int ct = 0; ct < 4; ++ct)
            wb[kk][ct] = *(const bf16x8*)
                &R1[(size_t)(ct * 16 + l16) * 64 + kk * 32 + quad * 8];

    f32x4 r1[4][4];
#pragma unroll
    for (int rt = 0; rt < 4; ++rt)
#pragma unroll
        for (int ct = 0; ct < 4; ++ct) r1[rt][ct] = (f32x4){0.f, 0.f, 0.f, 0.f};
#pragma unroll
    for (int kk = 0; kk < 2; ++kk)
#pragma unroll
        for (int rt = 0; rt < 4; ++rt)
#pragma unroll
            for (int ct = 0; ct < 4; ++ct)
                r1[rt][ct] = __builtin_amdgcn_mfma_f32_16x16x32_bf16(
                    af[rt][kk], wb[kk][ct], r1[rt][ct], 0, 0, 0);

    if (z != 0) {
        // single-stage: krb (z==1) or vrb (z==2) = relu(r1 + rb1)
        const void* rb = a.rb1[z];
        u16* out = (z == 1) ? a.krb : a.vrb;
#pragma unroll
        for (int ct = 0; ct < 4; ++ct) {
            int cl = ct * 16 + l16;
            float bv = f ? ((const float*)rb)[cl] : bf2f(((const u16*)rb)[cl]);
#pragma unroll
            for (int rt = 0; rt < 4; ++rt)
#pragma unroll
                for (int r = 0; r < 4; ++r) {
                    float v = r1[rt][ct][r] + bv;
                    v = v > 0.f ? v : 0.f;
                    out[(size_t)(m0 + wr + rt * 16 + quad * 4 + r) * DM_ + hcol + cl]
                        = f2bf(v);
                }
        }
    } else {
        // q1a = relu(r1 + bql) -> Es (round-trip for stage 2)
        {
            const void* rb = a.rb1[0];
#pragma unroll
            for (int ct = 0; ct < 4; ++ct) {
                int cl = ct * 16 + l16;
                float bv = f ? ((const float*)rb)[cl] : bf2f(((const u16*)rb)[cl]);
#pragma unroll
                for (int rt = 0; rt < 4; ++rt)
#pragma unroll
                    for (int r = 0; r < 4; ++r) {
                        float v = r1[rt][ct][r] + bv;
                        v = v > 0.f ? v : 0.f;
                        int ml = rt * 16 + quad * 4 + r;
                        Es[ml][((((cl >> 3) ^ (ml & 7)) << 3) | (cl & 7))] = f2bf(v);
                    }
            }
        }
        // q2r = relu(proj @ Wq2^T + bq2)  (reuses af while Es writes land)
        {
            const u16* R3 = f ? a.R31 : a.R30;
#pragma unroll
            for (int kk = 0; kk < 2; ++kk)
#pragma unroll
                for (int ct = 0; ct < 4; ++ct)
                    wb[kk][ct] = *(const bf16x8*)
                        &R3[(size_t)(ct * 16 + l16) * 64 + kk * 32 + quad * 8];
            f32x4 r3[4][4];
#pragma unroll
            for (int rt = 0; rt < 4; ++rt)
#pragma unroll
                for (int ct = 0; ct < 4; ++ct) r3[rt][ct] = (f32x4){0.f, 0.f, 0.f, 0.f};
#pragma unroll
            for (int kk = 0; kk < 2; ++kk)
#pragma unroll
                for (int rt = 0; rt < 4; ++rt)
#pragma unroll
                    for (int ct = 0; ct < 4; ++ct)
                        r3[rt][ct] = __builtin_amdgcn_mfma_f32_16x16x32_bf16(
                            af[rt][kk], wb[kk][ct], r3[rt][ct], 0, 0, 0);
            const void* rb = a.rb3;
#pragma unroll
            for (int ct = 0; ct < 4; ++ct) {
                int cl = ct * 16 + l16;
                float bv = f ? ((const float*)rb)[cl] : bf2f(((const u16*)rb)[cl]);
#pragma unroll
                for (int rt = 0; rt < 4; ++rt)
#pragma unroll
                    for (int r = 0; r < 4; ++r) {
                        float v = r3[rt][ct][r] + bv;
                        v = v > 0.f ? v : 0.f;
                        a.q2r[(size_t)(m0 + wr + rt * 16 + quad * 4 + r) * DM_
                              + hcol + cl] = f2bf(v);
                    }
            }
        }
        // q1b = relu(q1a @ Wel^T + bel)
        {
#pragma unroll
            for (int rt = 0; rt < 4; ++rt)
#pragma unroll
                for (int kk = 0; kk < 2; ++kk)
                    af[rt][kk] = *(const bf16x8*)
                        &Es[rt * 16 + l16][(((kk * 4 + quad) ^ (l16 & 7)) << 3)];
            const u16* R2 = f ? a.R21 : a.R20;
#pragma unroll
            for (int kk = 0; kk < 2; ++kk)
#pragma unroll
                for (int ct = 0; ct < 4; ++ct)
                    wb[kk][ct] = *(const bf16x8*)
                        &R2[(size_t)(ct * 16 + l16) * 64 + kk * 32 + quad * 8];
            f32x4 r2[4][4];
#pragma unroll
            for (int rt = 0; rt < 4; ++rt)
#pragma unroll
                for (int ct = 0; ct < 4; ++ct) r2[rt][ct] = (f32x4){0.f, 0.f, 0.f, 0.f};
#pragma unroll
            for (int kk = 0; kk < 2; ++kk)
#pragma unroll
                for (int rt = 0; rt < 4; ++rt)
#pragma unroll
                    for (int ct = 0; ct < 4; ++ct)
                        r2[rt][ct] = __builtin_amdgcn_mfma_f32_16x16x32_bf16(
                            af[rt][kk], wb[kk][ct], r2[rt][ct], 0, 0, 0);
            const void* rb = a.rb2;
#pragma unroll
            for (int ct = 0; ct < 4; ++ct) {
                int cl = ct * 16 + l16;
                float bv = f ? ((const float*)rb)[cl] : bf2f(((const u16*)rb)[cl]);
#pragma unroll
                for (int rt = 0; rt < 4; ++rt)
#pragma unroll
                    for (int r = 0; r < 4; ++r) {
                        float v = r2[rt][ct][r] + bv;
                        v = v > 0.f ? v : 0.f;
                        a.q1b[(size_t)(m0 + wr + rt * 16 + quad * 4 + r) * DM_
                              + hcol + cl] = f2bf(v);
                    }
            }
        }
    }
}

// ---------------------------------------------------------------------------
// Output-projection GEMM (m97 structure), dtype-dynamic bias/out.
// (256,2): spill-free mapping per R7 counters.
// ---------------------------------------------------------------------------
__global__ __launch_bounds__(256, 2) void gemm_async_kernel(
    const u16* __restrict__ Ain, const u16* __restrict__ W0,
    const u16* __restrict__ W1, const void* __restrict__ biasp,
    void* __restrict__ Cp, const int* __restrict__ flag)
{
    __shared__ __align__(16) u16 As[128][64];
    __shared__ __align__(16) u16 Ws[128][64];

    const int f = *flag;
    const u16* __restrict__ W = f ? W1 : W0;

    const int m0   = blockIdx.y * 128;
    const int n0   = blockIdx.x * 128;
    const int tid  = threadIdx.x;
    const int w    = tid >> 6;
    const int lane = tid & 63;
    const int l16  = lane & 15;
    const int quad = lane >> 4;
    const int wr   = (w >> 1) * 64;
    const int wc   = (w & 1) * 64;

    const int srow = lane >> 3;
    const int sgrp = (lane & 7) ^ srow;

    f32x4 acc[4][4];
#pragma unroll
    for (int rt = 0; rt < 4; ++rt)
#pragma unroll
        for (int ct = 0; ct < 4; ++ct) acc[rt][ct] = (f32x4){0.f, 0.f, 0.f, 0.f};

    for (int k0 = 0; k0 < DM_; k0 += 64) {
#pragma unroll
        for (int s = 0; s < 4; ++s) {
            int seg = w * 4 + s;
            async_ld16(&Ain[(size_t)(m0 + seg * 8 + srow) * DM_ + k0 + sgrp * 8],
                       &As[seg * 8][0]);
            async_ld16(&W[(size_t)(n0 + seg * 8 + srow) * DM_ + k0 + sgrp * 8],
                       &Ws[seg * 8][0]);
        }
        __syncthreads();
#pragma unroll
        for (int kk = 0; kk < 2; ++kk) {
            const int p = (kk * 4 + quad) ^ (l16 & 7);
            bf16x8 av[4], bv[4];
#pragma unroll
            for (int rt = 0; rt < 4; ++rt)
                av[rt] = *(const bf16x8*)&As[wr + rt * 16 + l16][p * 8];
#pragma unroll
            for (int ct = 0; ct < 4; ++ct)
                bv[ct] = *(const bf16x8*)&Ws[wc + ct * 16 + l16][p * 8];
#pragma unroll
            for (int rt = 0; rt < 4; ++rt)
#pragma unroll
                for (int ct = 0; ct < 4; ++ct)
                    acc[rt][ct] = __builtin_amdgcn_mfma_f32_16x16x32_bf16(
                        av[rt], bv[ct], acc[rt][ct], 0, 0, 0);
        }
        __syncthreads();
    }

#pragma unroll
    for (int ct = 0; ct < 4; ++ct) {
        int col = n0 + wc + ct * 16 + l16;
        float bv = f ? ((const float*)biasp)[col] : bf2f(((const u16*)biasp)[col]);
#pragma unroll
        for (int rt = 0; rt < 4; ++rt)
#pragma unroll
            for (int r = 0; r < 4; ++r) {
                int row = m0 + wr + rt * 16 + quad * 4 + r;
                float v = acc[rt][ct][r] + bv;
                size_t idx = (size_t)row * DM_ + col;
                if (f) ((float*)Cp)[idx] = v;
                else   ((u16*)Cp)[idx]   = f2bf(v);
            }
    }
}

// ---------------------------------------------------------------------------
// Fused attention (R15, unchanged): DMA staging, 1 barrier/tile, XCD swizzle,
// setprio, SWAPPED QK^T (row-local softmax: in-lane folds + 2 shfl_xor).
// ---------------------------------------------------------------------------
__global__ __launch_bounds__(256, 2) void attn_kernel(
    const u16* __restrict__ q1, const u16* __restrict__ q2,
    const u16* __restrict__ kr, const u16* __restrict__ vr,
    const u16* __restrict__ kpt, const int* __restrict__ mask,
    const int* __restrict__ tflags, u16* __restrict__ om)
{
    __shared__ __align__(16) u16 krs[2][64][64];
    __shared__ __align__(16) u16 vrs[2][64][64];
    __shared__ __align__(16) u16 kts[2][64][64];   // KpT tile: rows d, cols k
    __shared__ __align__(16) u16 pts[4][32][72];   // per-wave P~ staging

    // bijective XCD swizzle: hw XCD = bid%8; XCD x gets orig ids x*64..x*64+63
    // = (b,h) pairs 8x..8x+7 complete (8 q-tiles each).
    const int bid  = blockIdx.x;                  // 0..511 flat
    const int orig = (bid & 7) * 64 + (bid >> 3);
    const int qt = orig & 7;
    const int h  = (orig >> 3) & 15;
    const int b  = orig >> 7;

    const int q0   = qt * 128;
    const int tid  = threadIdx.x;
    const int w    = tid >> 6;
    const int lane = tid & 63;
    const int l16  = lane & 15;
    const int quad = lane >> 4;

    const size_t base  = (size_t)b * S_ * DM_ + (size_t)h * DK_;
    const size_t baseT = (size_t)(b * H_ + h) * DK_ * S_;

    // staging lane coords (qkv pattern): row-in-segment + XOR'd col group
    const int srow = lane >> 3;                  // 0..7
    const int sgrp = (lane & 7) ^ srow;          // swizzled source col group

    // issue 6 global_load_lds per wave covering 24 segments of 8 rows:
    // flat seg s = w*6+i; tile t = s/8 (0:krs 1:vrs 2:kts); r8 = (s%8)*8.
#define STAGE_TILES(buf, kn)                                                   \
    {                                                                          \
        _Pragma("unroll")                                                      \
        for (int i = 0; i < 6; ++i) {                                          \
            int s_ = w * 6 + i;                                                \
            int t_ = s_ >> 3;                                                  \
            int r8 = (s_ & 7) * 8;                                             \
            if (t_ == 0)                                                       \
                async_ld16(&kr[base + (size_t)((kn) + r8 + srow) * DM_ +       \
                               sgrp * 8], &krs[buf][r8][0]);                   \
            else if (t_ == 1)                                                  \
                async_ld16(&vr[base + (size_t)((kn) + r8 + srow) * DM_ +       \
                               sgrp * 8], &vrs[buf][r8][0]);                   \
            else                                                               \
                async_ld16(&kpt[baseT + (size_t)(r8 + srow) * S_ + (kn) +      \
                                sgrp * 8], &kts[buf][r8][0]);                  \
        }                                                                      \
    }

    bf16x8 a1[2][2], a2[2][2];
#pragma unroll
    for (int rt = 0; rt < 2; ++rt) {
        const int qrow = q0 + w * 32 + rt * 16 + l16;
#pragma unroll
        for (int kk = 0; kk < 2; ++kk) {
            a1[rt][kk] = *(const bf16x8*)&q1[base + (size_t)qrow * DM_ + kk * 32 + quad * 8];
            a2[rt][kk] = *(const bf16x8*)&q2[base + (size_t)qrow * DM_ + kk * 32 + quad * 8];
        }
    }

    // softmax state: per qt half, this lane owns q = qt*16 + l16
    float m_run[2], l_run[2];
    f32x4 oacc[2][4];
#pragma unroll
    for (int qt2 = 0; qt2 < 2; ++qt2) { m_run[qt2] = -1e30f; l_run[qt2] = 0.f; }
#pragma unroll
    for (int rt = 0; rt < 2; ++rt)
#pragma unroll
        for (int ct = 0; ct < 4; ++ct) oacc[rt][ct] = (f32x4){0.f, 0.f, 0.f, 0.f};

    // ---- prologue: stage tile 0 into buffer 0 (barrier drains vmcnt) ----
    STAGE_TILES(0, 0)
    __syncthreads();

    for (int kt = 0; kt < S_ / 64; ++kt) {
        const int cur = kt & 1;
        const int k0  = kt * 64;
        const bool pf = (kt + 1 < S_ / 64);

        // issue next-tile DMA first — lands during compute, drained by barrier
        if (pf) STAGE_TILES(cur ^ 1, k0 + 64)

        const int tf = tflags[b * 16 + kt];

        // st[qt][kt4] = D[k][q]: row k = kt4*16 + quad*4 + r, col q = qt*16+l16
        f32x4 st1[2][4], st2[2][4];
#pragma unroll
        for (int qt2 = 0; qt2 < 2; ++qt2)
#pragma unroll
            for (int kt4 = 0; kt4 < 4; ++kt4) {
                st1[qt2][kt4] = (f32x4){0.f, 0.f, 0.f, 0.f};
                st2[qt2][kt4] = (f32x4){0.f, 0.f, 0.f, 0.f};
            }
        __builtin_amdgcn_s_setprio(1);
#pragma unroll
        for (int kk = 0; kk < 2; ++kk) {
            const int p = ((kk * 4 + quad) ^ (l16 & 7)) * 8;
            bf16x8 b1[4], b2[4];
#pragma unroll
            for (int kt4 = 0; kt4 < 4; ++kt4) {
                b1[kt4] = *(const bf16x8*)&krs[cur][kt4 * 16 + l16][p];
                b2[kt4] = *(const bf16x8*)&vrs[cur][kt4 * 16 + l16][p];
            }
            // SWAPPED operand order: A=K/V rows (k), B=Q rows (q)
#pragma unroll
            for (int qt2 = 0; qt2 < 2; ++qt2)
#pragma unroll
                for (int kt4 = 0; kt4 < 4; ++kt4) {
                    st1[qt2][kt4] = __builtin_amdgcn_mfma_f32_16x16x32_bf16(
                        b1[kt4], a1[qt2][kk], st1[qt2][kt4], 0, 0, 0);
                    st2[qt2][kt4] = __builtin_amdgcn_mfma_f32_16x16x32_bf16(
                        b2[kt4], a2[qt2][kk], st2[qt2][kt4], 0, 0, 0);
                }
        }
        __builtin_amdgcn_s_setprio(0);

        if (tf) {
#pragma unroll
            for (int qt2 = 0; qt2 < 2; ++qt2)
#pragma unroll
                for (int kt4 = 0; kt4 < 4; ++kt4)
#pragma unroll
                    for (int r = 0; r < 4; ++r) {
                        int qrow = q0 + w * 32 + qt2 * 16 + l16;
                        int kc   = k0 + kt4 * 16 + quad * 4 + r;
                        if (mask[((size_t)b * S_ + qrow) * S_ + kc] == 0)
                            st1[qt2][kt4][r] = -1e9f;
                    }
        }

        // ---- row-local softmax: in-lane fold + 2 shfl_xor per quantity ----
        float alphaq[2], newm[2];
#pragma unroll
        for (int qt2 = 0; qt2 < 2; ++qt2) {
            float m = st1[qt2][0][0];
#pragma unroll
            for (int kt4 = 0; kt4 < 4; ++kt4)
#pragma unroll
                for (int r = 0; r < 4; ++r)
                    m = fmaxf(m, st1[qt2][kt4][r]);
            m = fmaxf(m, __shfl_xor(m, 16, 64));
            m = fmaxf(m, __shfl_xor(m, 32, 64));
            newm[qt2]   = fmaxf(m_run[qt2], m);
            alphaq[qt2] = __expf(m_run[qt2] - newm[qt2]);
            m_run[qt2]  = newm[qt2];
        }

#pragma unroll
        for (int qt2 = 0; qt2 < 2; ++qt2) {
            float s = 0.f;
#pragma unroll
            for (int kt4 = 0; kt4 < 4; ++kt4)
#pragma unroll
                for (int pp = 0; pp < 2; ++pp) {
                    float p0 = __expf(st1[qt2][kt4][2 * pp]     - newm[qt2]);
                    float p1 = __expf(st1[qt2][kt4][2 * pp + 1] - newm[qt2]);
                    s += p0 + p1;
                    unsigned u = (unsigned)f2bf_fast(p0 * st2[qt2][kt4][2 * pp])
                               | ((unsigned)f2bf_fast(p1 * st2[qt2][kt4][2 * pp + 1]) << 16);
                    *(unsigned*)&pts[w][qt2 * 16 + l16][kt4 * 16 + quad * 4 + 2 * pp] = u;
                }
            s += __shfl_xor(s, 16, 64);
            s += __shfl_xor(s, 32, 64);
            l_run[qt2] = l_run[qt2] * alphaq[qt2] + s;
        }

        // oacc rescale: broadcast alpha from softmax layout (q=l16) to
        // C-layout rows (q=quad*4+r); value uniform across source quads.
#pragma unroll
        for (int rt = 0; rt < 2; ++rt)
#pragma unroll
            for (int r = 0; r < 4; ++r) {
                float ao = __shfl(alphaq[rt], quad * 4 + r, 64);
#pragma unroll
                for (int ct = 0; ct < 4; ++ct) oacc[rt][ct][r] *= ao;
            }

        {
            __builtin_amdgcn_s_setprio(1);
            bf16x8 bb[2][4];
#pragma unroll
            for (int kk = 0; kk < 2; ++kk) {
                const int p = ((kk * 4 + quad) ^ (l16 & 7)) * 8;
#pragma unroll
                for (int ct = 0; ct < 4; ++ct)
                    bb[kk][ct] = *(const bf16x8*)&kts[cur][ct * 16 + l16][p];
            }
#pragma unroll
            for (int rt = 0; rt < 2; ++rt)
#pragma unroll
                for (int kk = 0; kk < 2; ++kk) {
                    // per-wave DS in-order: reads see this wave's pts writes
                    bf16x8 a = *(const bf16x8*)&pts[w][rt * 16 + l16][kk * 32 + quad * 8];
#pragma unroll
                    for (int ct = 0; ct < 4; ++ct)
                        oacc[rt][ct] = __builtin_amdgcn_mfma_f32_16x16x32_bf16(
                            a, bb[kk][ct], oacc[rt][ct], 0, 0, 0);
                }
            __builtin_amdgcn_s_setprio(0);
        }

        // barrier releases next buffer (drains the in-flight DMA)
        if (pf) __syncthreads();
    }

#pragma unroll
    for (int rt = 0; rt < 2; ++rt)
#pragma unroll
        for (int r = 0; r < 4; ++r) {
            float lo = __shfl(l_run[rt], quad * 4 + r, 64);
            float inv = 1.f / lo;
#pragma unroll
            for (int ct = 0; ct < 4; ++ct) {
                int row = q0 + w * 32 + rt * 16 + quad * 4 + r;
                int col = ct * 16 + l16;
                om[base + (size_t)row * DM_ + col] = f2bf_fast(oacc[rt][ct][r] * inv);
            }
        }
#undef STAGE_TILES
}

// ---------------------------------------------------------------------------
extern "C" void kernel_launch(void* const* d_in, const int* in_sizes, int n_in,
                              void* d_out, int out_size, void* d_ws, size_t ws_size,
                              hipStream_t stream)
{
    const void* query = d_in[0];
    const void* key   = d_in[1];
    const void* value = d_in[2];
    const int*  mask  = (const int*)d_in[3];
    const void* Wq  = d_in[4];  const void* bq  = d_in[5];
    const void* Wk  = d_in[6];  const void* bk  = d_in[7];
    const void* Wv  = d_in[8];  const void* bv  = d_in[9];
    const void* Wo  = d_in[10]; const void* bo  = d_in[11];
    const void* Wkl = d_in[12]; const void* bkl = d_in[13];
    const void* Wql = d_in[14]; const void* bql = d_in[15];
    const void* Wq2 = d_in[16]; const void* bq2 = d_in[17];
    const void* Wvl = d_in[18]; const void* bvl = d_in[19];
    const void* Wel = d_in[20]; const void* bel = d_in[21];

    int* flag   = (int*)d_ws;
    int* tflags = (int*)d_ws + 4;                     // 64 ints
    u16* ws     = (u16*)((char*)d_ws + 512);
    const size_t BUF = (size_t)(B_ * S_) * DM_;       // 4M elems = 8 MB bf16
    u16* Kp  = ws + 0 * BUF;                          // (unused since R17)
    u16* krb = ws + 1 * BUF;
    u16* q1b = ws + 2 * BUF;
    u16* q2r = ws + 3 * BUF;
    u16* vrb = ws + 4 * BUF;
    u16* Om  = ws + 5 * BUF;
    u16* KpT = ws + 6 * BUF;
    u16* Qc  = ws + 7 * BUF;
    u16* Kc  = ws + 8 * BUF;
    u16* Vc  = ws + 9 * BUF;
    u16* Wbig = ws + 10 * BUF;
    u16* Wqc = Wbig + 0 * (size_t)(DM_ * DM_);
    u16* Wkc = Wbig + 1 * (size_t)(DM_ * DM_);
    u16* Wvc = Wbig + 2 * (size_t)(DM_ * DM_);
    u16* Woc = Wbig + 3 * (size_t)(DM_ * DM_);
    u16* Wsm = Wbig + 4 * (size_t)(DM_ * DM_);
    u16* Wklc = Wsm + 0 * (DK_ * DK_);
    u16* Wqlc = Wsm + 1 * (DK_ * DK_);
    u16* Welc = Wsm + 2 * (DK_ * DK_);
    u16* Wq2c = Wsm + 3 * (DK_ * DK_);
    u16* Wvlc = Wsm + 4 * (DK_ * DK_);
    (void)Kp;

    const int M = B_ * S_;
    dim3 blk(256);

    detect_kernel<<<1, 64, 0, stream>>>((const u16*)query, flag);

    // fused mask-flag scan + dtype conversion
    hipMemsetAsync(tflags, 0, 64 * sizeof(int), stream);
    CvtArgs ca;
    const unsigned VIN = (unsigned)(BUF / 8);
    const unsigned VWB = (unsigned)(DM_ * DM_ / 8);
    const unsigned VWS = (unsigned)(DK_ * DK_ / 8);
    const void* srcs[NSEG] = {query, key, value, Wq, Wk, Wv, Wo, Wkl, Wql, Wel, Wq2, Wvl};
    void* dsts[NSEG] = {Qc, Kc, Vc, Wqc, Wkc, Wvc, Woc, Wklc, Wqlc, Welc, Wq2c, Wvlc};
    unsigned vcn[NSEG] = {VIN, VIN, VIN, VWB, VWB, VWB, VWB, VWS, VWS, VWS, VWS, VWS};
    unsigned off = 0;
    for (int i = 0; i < NSEG; ++i) { ca.src[i] = srcs[i]; ca.dst[i] = dsts[i]; ca.off[i] = off; off += vcn[i]; }
    ca.off[NSEG] = off;
    prep_kernel<<<dim3(512 + (off + 255) / 256), blk, 0, stream>>>(ca, off, flag, mask, tflags);

    // Q/K/V projections + fused per-head refinements (768 blocks)
    // z=1 now writes KpT directly (transpose kernel fused away)
    QKVArgs qa = {};
    qa.A0[0] = (const u16*)query; qa.A1[0] = Qc;
    qa.A0[1] = (const u16*)key;   qa.A1[1] = Kc;
    qa.A0[2] = (const u16*)value; qa.A1[2] = Vc;
    qa.W0[0] = (const u16*)Wq; qa.W1[0] = Wqc;
    qa.W0[1] = (const u16*)Wk; qa.W1[1] = Wkc;
    qa.W0[2] = (const u16*)Wv; qa.W1[2] = Wvc;
    qa.bias[0] = bq; qa.bias[1] = bk; qa.bias[2] = bv;
    qa.R10[0] = (const u16*)Wql; qa.R11[0] = Wqlc; qa.rb1[0] = bql;
    qa.R10[1] = (const u16*)Wkl; qa.R11[1] = Wklc; qa.rb1[1] = bkl;
    qa.R10[2] = (const u16*)Wvl; qa.R11[2] = Wvlc; qa.rb1[2] = bvl;
    qa.R20 = (const u16*)Wel; qa.R21 = Welc; qa.rb2 = bel;
    qa.R30 = (const u16*)Wq2; qa.R31 = Wq2c; qa.rb3 = bq2;
    qa.KpT = KpT; qa.q1b = q1b; qa.q2r = q2r; qa.krb = krb; qa.vrb = vrb;
    dim3 gBig(DM_ / 128, M / 128, 3);
    qkv_fused_kernel<<<gBig, blk, 0, stream>>>(qa, flag);

    // fused attention -> merged (B,S,DM) layout (128 q-rows per block,
    // flat grid + XCD swizzle: one (b,h) pair's 8 q-blocks per XCD)
    attn_kernel<<<dim3(512), blk, 0, stream>>>(q1b, q2r, krb, vrb, KpT, mask, tflags, Om);

    // output projection -> d_out
    dim3 gO(DM_ / 128, M / 128);
    gemm_async_kernel<<<gO, blk, 0, stream>>>(Om, (const u16*)Wo, Woc, bo, d_out, flag);
}